// Round 14
// baseline (1181.784 us; speedup 1.0000x reference)
//
#include <hip/hip_runtime.h>
#include <hip/hip_bf16.h>
#include <math.h>

// Problem constants (match reference)
#define BB 8
#define SS 2048
#define DD 1024
#define DS 64
#define MM (BB*SS)   // 16384

// ---------------- helpers ----------------

__device__ __forceinline__ float4 ld4(const float* p) { return *(const float4*)p; }

template<int CTRL>
__device__ __forceinline__ float dppadd(float x) {
  int v = __builtin_amdgcn_update_dpp(0, __float_as_int(x), CTRL, 0xf, 0xf, true);
  return x + __int_as_float(v);
}

__device__ __forceinline__ float xor16add(float x) {
#if defined(__has_builtin) && __has_builtin(__builtin_amdgcn_permlane16_swap)
  auto r = __builtin_amdgcn_permlane16_swap(__float_as_uint(x), __float_as_uint(x), false, false);
  return __uint_as_float(r[0]) + __uint_as_float(r[1]);
#else
  return x + __shfl_xor(x, 16, 64);
#endif
}
__device__ __forceinline__ float xor32add(float x) {
#if defined(__has_builtin) && __has_builtin(__builtin_amdgcn_permlane32_swap)
  auto r = __builtin_amdgcn_permlane32_swap(__float_as_uint(x), __float_as_uint(x), false, false);
  return __uint_as_float(r[0]) + __uint_as_float(r[1]);
#else
  return x + __shfl_xor(x, 32, 64);
#endif
}

// full 64-lane butterfly sum; result valid in all lanes
__device__ __forceinline__ float wsum(float x) {
  x = dppadd<0xB1>(x);
  x = dppadd<0x4E>(x);
  x = dppadd<0x141>(x);
  x = dppadd<0x140>(x);
  x = xor16add(x);
  x = xor32add(x);
  return x;
}

__device__ __forceinline__ float gelu_exact(float x) {
  return 0.5f * x * (1.f + erff(x * 0.7071067811865476f));
}

// ---------------- k0: pack weights [Wk;Wv;Wq;ir_w1;pw;0-pad] -> Wcat[320][1024]
__global__ __launch_bounds__(256) void pack_w(
    const float* __restrict__ Wk, const float* __restrict__ Wv,
    const float* __restrict__ Wq, const float* __restrict__ ir_w1,
    const float* __restrict__ pw, float* __restrict__ Wcat) {
  int idx = blockIdx.x * 256 + threadIdx.x;   // 320*1024 total
  int r = idx >> 10, c = idx & 1023;
  float val = 0.f;
  if (r < 64)       val = Wk[r*1024 + c];
  else if (r < 128) val = Wv[(r-64)*1024 + c];
  else if (r < 192) val = Wq[(r-128)*1024 + c];
  else if (r < 256) val = ir_w1[(r-192)*1024 + c];
  else if (r < 259) val = pw[(r-256)*1024 + c];
  Wcat[idx] = val;
}

// ---------------- k1: Y[16384][320] = X[16384][1024] @ Wcat[320][1024]^T
__global__ __launch_bounds__(256) void gemm1(
    const float* __restrict__ X, const float* __restrict__ Wcat,
    float* __restrict__ Y) {
  __shared__ float As[32*128];   // [k][m]
  __shared__ float Bs[32*64];    // [k][n]
  const int t  = threadIdx.x;
  const int m0 = blockIdx.x * 128;
  const int n0 = blockIdx.y * 64;
  const int mi = t >> 4, ni = t & 15;
  const int rA = t >> 1, hA = t & 1;
  const int rB = t >> 2, qB = t & 3;
  float acc[8][4];
  #pragma unroll
  for (int i = 0; i < 8; ++i)
    #pragma unroll
    for (int j = 0; j < 4; ++j) acc[i][j] = 0.f;

  for (int k0 = 0; k0 < 1024; k0 += 32) {
    __syncthreads();
    {
      const float* src = X + (size_t)(m0 + rA)*1024 + k0 + hA*16;
      #pragma unroll
      for (int jj = 0; jj < 4; ++jj) {
        float4 xv = ld4(src + jj*4);
        int kk = hA*16 + jj*4;
        As[(kk+0)*128 + rA] = xv.x; As[(kk+1)*128 + rA] = xv.y;
        As[(kk+2)*128 + rA] = xv.z; As[(kk+3)*128 + rA] = xv.w;
      }
      const float* srcB = Wcat + (size_t)(n0 + rB)*1024 + k0 + qB*8;
      #pragma unroll
      for (int jj = 0; jj < 2; ++jj) {
        float4 bv = ld4(srcB + jj*4);
        int kb = qB*8 + jj*4;
        Bs[(kb+0)*64 + rB] = bv.x; Bs[(kb+1)*64 + rB] = bv.y;
        Bs[(kb+2)*64 + rB] = bv.z; Bs[(kb+3)*64 + rB] = bv.w;
      }
    }
    __syncthreads();
    #pragma unroll
    for (int kk = 0; kk < 32; ++kk) {
      float a[8], bv[4];
      float4 a0 = *(const float4*)&As[kk*128 + mi*8];
      float4 a1 = *(const float4*)&As[kk*128 + mi*8 + 4];
      float4 b0 = *(const float4*)&Bs[kk*64 + ni*4];
      a[0]=a0.x; a[1]=a0.y; a[2]=a0.z; a[3]=a0.w;
      a[4]=a1.x; a[5]=a1.y; a[6]=a1.z; a[7]=a1.w;
      bv[0]=b0.x; bv[1]=b0.y; bv[2]=b0.z; bv[3]=b0.w;
      #pragma unroll
      for (int im = 0; im < 8; ++im)
        #pragma unroll
        for (int in = 0; in < 4; ++in)
          acc[im][in] = fmaf(a[im], bv[in], acc[im][in]);
    }
  }
  #pragma unroll
  for (int im = 0; im < 8; ++im) {
    float4 o; o.x = acc[im][0]; o.y = acc[im][1]; o.z = acc[im][2]; o.w = acc[im][3];
    *(float4*)&Y[(size_t)(m0 + mi*8 + im)*320 + n0 + ni*4] = o;
  }
}

// ---------------- k2: per-token postprocess -> K,V,Q,NU,PW, SCL8[0..3]
__global__ __launch_bounds__(256) void post_kernel(
    const float* __restrict__ Y,
    const float* __restrict__ nm_w1, const float* __restrict__ nm_b1,
    const float* __restrict__ nm_w2, const float* __restrict__ nm_b2,
    const float* __restrict__ ir_b1, const float* __restrict__ ir_w2,
    const float* __restrict__ ir_b2, const float* __restrict__ sap,
    float* __restrict__ K, float* __restrict__ V, float* __restrict__ Q,
    float* __restrict__ NU, float* __restrict__ PW,
    float* __restrict__ SCL8) {
  __shared__ float w1s[128*65];
  __shared__ float w2s[64*129];
  __shared__ float vbuf[4][64];
  __shared__ float h1buf[4][128];
  const int tid = threadIdx.x, wid = tid >> 6, l = tid & 63;
  for (int i = tid; i < 128*64; i += 256) w1s[(i>>6)*65 + (i&63)]  = nm_w1[i];
  for (int i = tid; i < 64*128; i += 256) w2s[(i>>7)*129 + (i&127)] = nm_w2[i];
  __syncthreads();
  const float sa   = *sap;
  const float b1a  = nm_b1[l], b1b = nm_b1[64+l], b2l = nm_b2[l];
  const float irb1 = ir_b1[l], irw2 = ir_w2[l],  irb2 = ir_b2[0];
  for (int r = 0; r < 4; ++r) {
    const int tok = blockIdx.x*16 + r*4 + wid;
    const float* yr = Y + (size_t)tok*320;
    float kr = yr[l], vr = yr[64+l], qr = yr[128+l], hr = yr[192+l];
    float rk = 1.f / fmaxf(sqrtf(wsum(kr*kr)), 1e-12f);
    float rq = 1.f / fmaxf(sqrtf(wsum(qr*qr)), 1e-12f);
    float kn = kr*rk, qn = qr*rq;
    float qk = wsum(kn*qn);
    float g  = gelu_exact(hr + irb1);
    float logit = wsum(g*irw2) + irb2;
    float imp = 1.f/(1.f+expf(-logit));
    float bs  = (imp > 0.5f) ? (1.f - sa) : 0.f;   // (1-slow_alpha)*u_slow
    K[(size_t)tok*64+l] = kn; V[(size_t)tok*64+l] = vr; Q[(size_t)tok*64+l] = qn;
    vbuf[wid][l] = vr;
    __syncthreads();
    float h1a = b1a, h1b = b1b;
    #pragma unroll 8
    for (int c = 0; c < 64; ++c) {
      float vv = vbuf[wid][c];
      h1a = fmaf(w1s[l*65 + c], vv, h1a);
      h1b = fmaf(w1s[(64+l)*65 + c], vv, h1b);
    }
    h1buf[wid][l]    = gelu_exact(h1a);
    h1buf[wid][64+l] = gelu_exact(h1b);
    __syncthreads();
    float nu = b2l;
    #pragma unroll 8
    for (int j = 0; j < 128; ++j) nu = fmaf(w2s[l*129 + j], h1buf[wid][j], nu);
    NU[(size_t)tok*64+l] = nu;
    float p0 = yr[256], p1 = yr[257], p2 = yr[258];
    float mx = fmaxf(p0, fmaxf(p1, p2));
    float e0 = expf(p0-mx), e1 = expf(p1-mx), e2 = expf(p2-mx);
    float inv = 1.f/(e0+e1+e2);
    if (l == 0) {
      PW[(size_t)tok*3]   = e0*inv;
      float4 s; s.x = qk; s.y = bs; s.z = e0*inv; s.w = e1*inv;
      *(float4*)&SCL8[(size_t)tok*8] = s;
    }
    else if (l == 1)   PW[(size_t)tok*3+1] = e1*inv;
    else if (l == 2)   PW[(size_t)tok*3+2] = e2*inv;
    __syncthreads();
  }
}

#define STAGE68(dst, srcp) { _Pragma("unroll")                        \
    for (int it_ = 0; it_ < 4; ++it_) {                               \
      int idx4 = (threadIdx.x + it_*256)*4;                           \
      int r_ = idx4 >> 6; int d_ = idx4 & 63;                         \
      *(float4*)&dst[r_*68+d_] = ld4(&(srcp)[r_*64 + d_]); } }

// ---------------- k2c: per-chunk dot matrices for ALL (b,c) in parallel.
__global__ __launch_bounds__(256) void chunkdots(
    const float* __restrict__ K, const float* __restrict__ Q,
    float* __restrict__ AKK, float* __restrict__ AQK) {
  __shared__ float Kl[64*68], Ql[64*68];
  const int tid = threadIdx.x;
  const size_t base = (size_t)blockIdx.x * 4096;
  STAGE68(Kl, K + base)
  STAGE68(Ql, Q + base)
  __syncthreads();
  const int t0 = (tid >> 4) * 4, j0 = (tid & 15) * 4;
  float akk[4][4], aqk[4][4];
  #pragma unroll
  for (int i = 0; i < 4; ++i)
    #pragma unroll
    for (int j = 0; j < 4; ++j) { akk[i][j] = 0.f; aqk[i][j] = 0.f; }
  for (int d = 0; d < 64; ++d) {
    float kt[4], qt[4], kj[4];
    #pragma unroll
    for (int i = 0; i < 4; ++i) {
      kt[i] = Kl[(t0+i)*68 + d];
      qt[i] = Ql[(t0+i)*68 + d];
      kj[i] = Kl[(j0+i)*68 + d];
    }
    #pragma unroll
    for (int i = 0; i < 4; ++i)
      #pragma unroll
      for (int j = 0; j < 4; ++j) {
        akk[i][j] = fmaf(kt[i], kj[j], akk[i][j]);
        aqk[i][j] = fmaf(qt[i], kj[j], aqk[i][j]);
      }
  }
  #pragma unroll
  for (int i = 0; i < 4; ++i) {
    float4 a; a.x=akk[i][0]; a.y=akk[i][1]; a.z=akk[i][2]; a.w=akk[i][3];
    float4 b; b.x=aqk[i][0]; b.y=aqk[i][1]; b.z=aqk[i][2]; b.w=aqk[i][3];
    *(float4*)&AKK[base + (t0+i)*64 + j0] = a;
    *(float4*)&AQK[base + (t0+i)*64 + j0] = b;
  }
}

// ---------------- k3a: per-chunk triangular solves -> P_f, R_f, P_s, R_s
// (I + M_p) X = RHS. Thread owns ONE column; its x history is lane-private
// so x[64] lives in registers. sched_barrier(0) after every step keeps
// live ranges step-local (R13 spill fix: full unroll let the scheduler
// hoist 500+ ds_reads -> 256 VGPR cap -> scratch spill -> 1.6GB traffic).
__global__ __launch_bounds__(256) void pass1_solve(
    const float* __restrict__ K, const float* __restrict__ V,
    const float* __restrict__ SCL8, const float* __restrict__ AKK,
    const float* __restrict__ fap, const float* __restrict__ sap,
    float* __restrict__ Pf, float* __restrict__ Rf,
    float* __restrict__ Ps, float* __restrict__ Rs) {
  __shared__ float Kc[64*68], Vc[64*68], Mf[64*68], Ms[64*68];
  __shared__ float bsv[64];
  __shared__ float fpw[65], spw[65];
  const int tid = threadIdx.x;
  const size_t chunk = blockIdx.x;
  const size_t tok0 = chunk * 64;
  const float fa = *fap, sa = *sap, omfa = 1.f - fa;
  if (tid == 0) {
    float f = 1.f, s = 1.f;
    for (int n = 0; n <= 64; ++n) { fpw[n] = f; spw[n] = s; f *= fa; s *= sa; }
  }
  STAGE68(Kc, K + tok0*64)
  STAGE68(Vc, V + tok0*64)
  STAGE68(Mf, AKK + chunk*4096)   // raw Akk staged into Mf
  if (tid < 64) bsv[tid] = SCL8[(tok0 + tid)*8 + 1];
  __syncthreads();
  // build masked M (read raw from Mf, write Ms then overwrite Mf)
  {
    const int t = tid >> 2, j0 = (tid & 3) * 16;
    const float bst = bsv[t];
    #pragma unroll
    for (int i = 0; i < 16; ++i) {
      int j = j0 + i;
      float a = Mf[t*68 + j];
      bool lt = (j < t);
      int p = lt ? (t-1-j) : 0;
      Ms[t*68 + j] = lt ? bst*spw[p]*a : 0.f;
      Mf[t*68 + j] = lt ? omfa*fpw[p]*a : 0.f;
    }
  }
  __syncthreads();

  const int g  = tid >> 6;     // 0:Pf 1:Rf 2:Ps 3:Rs (wave-uniform)
  const int cc = tid & 63;     // column
  const float* M = (g < 2) ? Mf : Ms;
  float x[64];
  #pragma unroll
  for (int i = 0; i < 64; ++i) x[i] = 0.f;
  #pragma unroll
  for (int t = 0; t < 64; ++t) {
    float rhs;
    if (g == 0)      rhs = omfa    * fpw[t] * Kc[t*68 + cc];
    else if (g == 1) rhs = omfa    * Vc[t*68 + cc];
    else if (g == 2) rhs = bsv[t] * spw[t] * Kc[t*68 + cc];
    else             rhs = bsv[t] * Vc[t*68 + cc];
    float a0 = 0.f, a1 = 0.f, a2 = 0.f, a3 = 0.f;
    #pragma unroll
    for (int j4 = 0; j4 < ((t + 3) >> 2); ++j4) {
      float4 m = *(const float4*)&M[t*68 + j4*4];
      a0 = fmaf(m.x, x[j4*4+0], a0);
      a1 = fmaf(m.y, x[j4*4+1], a1);
      a2 = fmaf(m.z, x[j4*4+2], a2);
      a3 = fmaf(m.w, x[j4*4+3], a3);
    }
    x[t] = rhs - ((a0 + a1) + (a2 + a3));
    __builtin_amdgcn_sched_barrier(0);   // keep live ranges step-local
  }
  float* dst = (g == 0) ? Pf : (g == 1) ? Rf : (g == 2) ? Ps : Rs;
  const size_t base = chunk*4096 + cc;
  #pragma unroll
  for (int t = 0; t < 64; ++t) dst[base + t*64] = x[t];
}

// ---------------- k3b: G = d^64 I - K^T E P, H = K^T E R (per chunk, path)
__global__ __launch_bounds__(256) void pass1b_gh(
    const float* __restrict__ K,
    const float* __restrict__ Pf, const float* __restrict__ Rf,
    const float* __restrict__ Ps, const float* __restrict__ Rs,
    const float* __restrict__ fap, const float* __restrict__ sap,
    float* __restrict__ Gf, float* __restrict__ Hf,
    float* __restrict__ Gs, float* __restrict__ Hs) {
  __shared__ float Kc[64*68], Pl[64*68], Rl[64*68];
  __shared__ float dpw[65];
  const int tid = threadIdx.x;
  const size_t chunk = blockIdx.x >> 1;
  const int path = blockIdx.x & 1;
  const float d = path ? (*sap) : (*fap);
  if (tid == 0) {
    float p = 1.f;
    for (int n = 0; n <= 64; ++n) { dpw[n] = p; p *= d; }
  }
  const float* Pg = path ? Ps : Pf;
  const float* Rg = path ? Rs : Rf;
  float* Gg = path ? Gs : Gf;
  float* Hg = path ? Hs : Hf;
  STAGE68(Kc, K + chunk*4096)
  STAGE68(Pl, Pg + chunk*4096)
  STAGE68(Rl, Rg + chunk*4096)
  __syncthreads();
  const int kd = tid >> 2, c0 = (tid & 3) * 16;
  float accG[16], accH[16];
  #pragma unroll
  for (int i = 0; i < 16; ++i) { accG[i] = 0.f; accH[i] = 0.f; }
  #pragma unroll 8
  for (int j = 0; j < 64; ++j) {
    const float w = Kc[j*68 + kd] * dpw[63 - j];
    #pragma unroll
    for (int i4 = 0; i4 < 4; ++i4) {
      float4 p = *(const float4*)&Pl[j*68 + c0 + i4*4];
      float4 r = *(const float4*)&Rl[j*68 + c0 + i4*4];
      accG[i4*4+0] = fmaf(w, p.x, accG[i4*4+0]);
      accG[i4*4+1] = fmaf(w, p.y, accG[i4*4+1]);
      accG[i4*4+2] = fmaf(w, p.z, accG[i4*4+2]);
      accG[i4*4+3] = fmaf(w, p.w, accG[i4*4+3]);
      accH[i4*4+0] = fmaf(w, r.x, accH[i4*4+0]);
      accH[i4*4+1] = fmaf(w, r.y, accH[i4*4+1]);
      accH[i4*4+2] = fmaf(w, r.z, accH[i4*4+2]);
      accH[i4*4+3] = fmaf(w, r.w, accH[i4*4+3]);
    }
  }
  const float d64 = dpw[64];
  #pragma unroll
  for (int i4 = 0; i4 < 4; ++i4) {
    float4 go, ho;
    float* gp = (float*)&go; float* hp = (float*)&ho;
    #pragma unroll
    for (int i = 0; i < 4; ++i) {
      int col = c0 + i4*4 + i;
      gp[i] = ((col == kd) ? d64 : 0.f) - accG[i4*4+i];
      hp[i] = accH[i4*4+i];
    }
    *(float4*)&Gg[chunk*4096 + (size_t)kd*64 + c0 + i4*4] = go;
    *(float4*)&Hg[chunk*4096 + (size_t)kd*64 + c0 + i4*4] = ho;
  }
}

// ---------------- k3c: sequential state recurrence F' = G F + H.
// Grid 32 = 8b x 2path x 2vhalf, 256 threads. Stores pre-state to Fst.
__global__ __launch_bounds__(256) void pass2_rec(
    const float* __restrict__ Gf, const float* __restrict__ Hf,
    const float* __restrict__ Gs, const float* __restrict__ Hs,
    float* __restrict__ Fstf, float* __restrict__ Fsts) {
  __shared__ float Fl[64*36], Gl[64*68], Hl[64*36];
  const int tid = threadIdx.x;
  const int b = blockIdx.x >> 2;
  const int path = (blockIdx.x >> 1) & 1;
  const int vh = blockIdx.x & 1;
  const float* Gg = path ? Gs : Gf;
  const float* Hg = path ? Hs : Hf;
  float* Fstg = path ? Fsts : Fstf;
  const int kd = tid >> 2, vq = tid & 3;      // 64 x 4(8v)
  #pragma unroll
  for (int i = 0; i < 8; ++i) Fl[kd*36 + vq*8 + i] = 0.f;
  __syncthreads();
  for (int c = 0; c < 32; ++c) {
    const size_t chunk = (size_t)b*32 + c;
    STAGE68(Gl, Gg + chunk*4096)
    *(float4*)&Hl[kd*36 + vq*8]     = ld4(&Hg[chunk*4096 + kd*64 + vh*32 + vq*8]);
    *(float4*)&Hl[kd*36 + vq*8 + 4] = ld4(&Hg[chunk*4096 + kd*64 + vh*32 + vq*8 + 4]);
    // store pre-state (stable since last barrier)
    *(float4*)&Fstg[chunk*4096 + (size_t)kd*64 + vh*32 + vq*8]     = *(float4*)&Fl[kd*36 + vq*8];
    *(float4*)&Fstg[chunk*4096 + (size_t)kd*64 + vh*32 + vq*8 + 4] = *(float4*)&Fl[kd*36 + vq*8 + 4];
    __syncthreads();
    float acc[8];
    #pragma unroll
    for (int i = 0; i < 8; ++i) acc[i] = Hl[kd*36 + vq*8 + i];
    #pragma unroll 8
    for (int j = 0; j < 64; ++j) {
      const float g = Gl[kd*68 + j];
      float4 f0 = *(const float4*)&Fl[j*36 + vq*8];
      float4 f1 = *(const float4*)&Fl[j*36 + vq*8 + 4];
      acc[0]=fmaf(g,f0.x,acc[0]); acc[1]=fmaf(g,f0.y,acc[1]);
      acc[2]=fmaf(g,f0.z,acc[2]); acc[3]=fmaf(g,f0.w,acc[3]);
      acc[4]=fmaf(g,f1.x,acc[4]); acc[5]=fmaf(g,f1.y,acc[5]);
      acc[6]=fmaf(g,f1.z,acc[6]); acc[7]=fmaf(g,f1.w,acc[7]);
    }
    __syncthreads();
    #pragma unroll
    for (int i = 0; i < 8; ++i) Fl[kd*36 + vq*8 + i] = acc[i];
    __syncthreads();
  }
}

// ---------------- k3d: parallel outputs per chunk (needs Fst states).
// Grid 512 = 256 chunks x 2 vhalf, 256 threads.
__global__ __launch_bounds__(256) void pass3_out(
    const float* __restrict__ Q, const float* __restrict__ V,
    const float* __restrict__ SCL8, const float* __restrict__ AQK,
    const float* __restrict__ Pf, const float* __restrict__ Rf,
    const float* __restrict__ Ps, const float* __restrict__ Rs,
    const float* __restrict__ Fstf, const float* __restrict__ Fsts,
    const float* __restrict__ fap, const float* __restrict__ sap,
    float* __restrict__ OBASE, float* __restrict__ E2) {
  __shared__ float Qcl[64*68], AQKl[64*68], Pfl[64*68], Psl[64*68];
  __shared__ float Vl[64*36], Rfl[64*36], Rsl[64*36];
  __shared__ float F0l[64*36], S0l[64*36], Ufl[64*36], Usl[64*36];
  __shared__ float scal[256];
  __shared__ float fpw[65], spw[65];
  const int tid = threadIdx.x;
  const size_t chunk = blockIdx.x >> 1;
  const int vh = blockIdx.x & 1;
  const size_t tok0 = chunk * 64;
  const float fa = *fap, sa = *sap;
  if (tid == 0) {
    float f = 1.f, s = 1.f;
    for (int n = 0; n <= 64; ++n) { fpw[n] = f; spw[n] = s; f *= fa; s *= sa; }
  }
  STAGE68(Qcl,  Q   + tok0*64)
  STAGE68(AQKl, AQK + chunk*4096)
  STAGE68(Pfl,  Pf  + chunk*4096)
  STAGE68(Psl,  Ps  + chunk*4096)
  {
    const int r = tid >> 2, vq = tid & 3;
    const size_t off = chunk*4096 + (size_t)r*64 + vh*32 + vq*8;
    *(float4*)&Vl [r*36 + vq*8]     = ld4(&V   [tok0*64 + (size_t)r*64 + vh*32 + vq*8]);
    *(float4*)&Vl [r*36 + vq*8 + 4] = ld4(&V   [tok0*64 + (size_t)r*64 + vh*32 + vq*8 + 4]);
    *(float4*)&Rfl[r*36 + vq*8]     = ld4(&Rf  [off]);
    *(float4*)&Rfl[r*36 + vq*8 + 4] = ld4(&Rf  [off + 4]);
    *(float4*)&Rsl[r*36 + vq*8]     = ld4(&Rs  [off]);
    *(float4*)&Rsl[r*36 + vq*8 + 4] = ld4(&Rs  [off + 4]);
    *(float4*)&F0l[r*36 + vq*8]     = ld4(&Fstf[off]);
    *(float4*)&F0l[r*36 + vq*8 + 4] = ld4(&Fstf[off + 4]);
    *(float4*)&S0l[r*36 + vq*8]     = ld4(&Fsts[off]);
    *(float4*)&S0l[r*36 + vq*8 + 4] = ld4(&Fsts[off + 4]);
    scal[tid] = SCL8[(tok0 + r)*8 + vq];
  }
  __syncthreads();
  // phase A: U_f = R_f - P_f F0, U_s = R_s - P_s S0
  {
    const int j = tid >> 2, vq = tid & 3;
    float uf[8], us[8];
    #pragma unroll
    for (int i = 0; i < 8; ++i) { uf[i] = 0.f; us[i] = 0.f; }
    #pragma unroll 8
    for (int kd = 0; kd < 64; ++kd) {
      const float pfv = Pfl[j*68 + kd];
      const float psv = Psl[j*68 + kd];
      float4 f0 = *(const float4*)&F0l[kd*36 + vq*8];
      float4 f1 = *(const float4*)&F0l[kd*36 + vq*8 + 4];
      float4 s0 = *(const float4*)&S0l[kd*36 + vq*8];
      float4 s1 = *(const float4*)&S0l[kd*36 + vq*8 + 4];
      uf[0]=fmaf(pfv,f0.x,uf[0]); uf[1]=fmaf(pfv,f0.y,uf[1]);
      uf[2]=fmaf(pfv,f0.z,uf[2]); uf[3]=fmaf(pfv,f0.w,uf[3]);
      uf[4]=fmaf(pfv,f1.x,uf[4]); uf[5]=fmaf(pfv,f1.y,uf[5]);
      uf[6]=fmaf(pfv,f1.z,uf[6]); uf[7]=fmaf(pfv,f1.w,uf[7]);
      us[0]=fmaf(psv,s0.x,us[0]); us[1]=fmaf(psv,s0.y,us[1]);
      us[2]=fmaf(psv,s0.z,us[2]); us[3]=fmaf(psv,s0.w,us[3]);
      us[4]=fmaf(psv,s1.x,us[4]); us[5]=fmaf(psv,s1.y,us[5]);
      us[6]=fmaf(psv,s1.z,us[6]); us[7]=fmaf(psv,s1.w,us[7]);
    }
    #pragma unroll
    for (int i = 0; i < 8; ++i) {
      Ufl[j*36 + vq*8 + i] = Rfl[j*36 + vq*8 + i] - uf[i];
      Usl[j*36 + vq*8 + i] = Rsl[j*36 + vq*8 + i] - us[i];
    }
  }
  __syncthreads();
  // phase B: per-token outputs
  {
    const int t = tid >> 2, vq = tid & 3;
    float af[8], as_[8];
    #pragma unroll
    for (int i = 0; i < 8; ++i) { af[i] = 0.f; as_[i] = 0.f; }
    #pragma unroll 8
    for (int kd = 0; kd < 64; ++kd) {
      const float q = Qcl[t*68 + kd];
      float4 f0 = *(const float4*)&F0l[kd*36 + vq*8];
      float4 f1 = *(const float4*)&F0l[kd*36 + vq*8 + 4];
      float4 s0 = *(const float4*)&S0l[kd*36 + vq*8];
      float4 s1 = *(const float4*)&S0l[kd*36 + vq*8 + 4];
      af[0]=fmaf(q,f0.x,af[0]); af[1]=fmaf(q,f0.y,af[1]);
      af[2]=fmaf(q,f0.z,af[2]); af[3]=fmaf(q,f0.w,af[3]);
      af[4]=fmaf(q,f1.x,af[4]); af[5]=fmaf(q,f1.y,af[5]);
      af[6]=fmaf(q,f1.z,af[6]); af[7]=fmaf(q,f1.w,af[7]);
      as_[0]=fmaf(q,s0.x,as_[0]); as_[1]=fmaf(q,s0.y,as_[1]);
      as_[2]=fmaf(q,s0.z,as_[2]); as_[3]=fmaf(q,s0.w,as_[3]);
      as_[4]=fmaf(q,s1.x,as_[4]); as_[5]=fmaf(q,s1.y,as_[5]);
      as_[6]=fmaf(q,s1.z,as_[6]); as_[7]=fmaf(q,s1.w,as_[7]);
    }
    float pq[8], pqs[8];
    #pragma unroll
    for (int i = 0; i < 8; ++i) { pq[i] = fpw[t]*af[i]; pqs[i] = spw[t]*as_[i]; }
    for (int j = 0; j < 64; ++j) {
      const float aq = AQKl[t*68 + j];
      const bool lt = (j < t);
      const int p = lt ? (t-1-j) : 0;
      const float wf = lt ? fpw[p]*aq : 0.f;
      const float ws = lt ? spw[p]*aq : 0.f;
      float4 u0 = *(const float4*)&Ufl[j*36 + vq*8];
      float4 u1 = *(const float4*)&Ufl[j*36 + vq*8 + 4];
      float4 w0 = *(const float4*)&Usl[j*36 + vq*8];
      float4 w1 = *(const float4*)&Usl[j*36 + vq*8 + 4];
      pq[0]=fmaf(wf,u0.x,pq[0]); pq[1]=fmaf(wf,u0.y,pq[1]);
      pq[2]=fmaf(wf,u0.z,pq[2]); pq[3]=fmaf(wf,u0.w,pq[3]);
      pq[4]=fmaf(wf,u1.x,pq[4]); pq[5]=fmaf(wf,u1.y,pq[5]);
      pq[6]=fmaf(wf,u1.z,pq[6]); pq[7]=fmaf(wf,u1.w,pq[7]);
      pqs[0]=fmaf(ws,w0.x,pqs[0]); pqs[1]=fmaf(ws,w0.y,pqs[1]);
      pqs[2]=fmaf(ws,w0.z,pqs[2]); pqs[3]=fmaf(ws,w0.w,pqs[3]);
      pqs[4]=fmaf(ws,w1.x,pqs[4]); pqs[5]=fmaf(ws,w1.y,pqs[5]);
      pqs[6]=fmaf(ws,w1.z,pqs[6]); pqs[7]=fmaf(ws,w1.w,pqs[7]);
    }
    const float qk = scal[t*4+0], p0 = scal[t*4+2], p1 = scal[t*4+3];
    float ob[8], ee[8];
    #pragma unroll
    for (int i = 0; i < 8; ++i) {
      const float uft = Ufl[t*36 + vq*8 + i];
      const float ust = Usl[t*36 + vq*8 + i];
      const float qfn = fmaf(fa, pq[i],  qk*uft);
      const float qsn = fmaf(sa, pqs[i], qk*ust);
      ob[i] = fmaf(p0, qfn, p1*qsn);
      const float pd = Vl[t*36 + vq*8 + i] - 0.5f*(pq[i] + pqs[i]);
      ee[i] = pd*pd;
    }
    const size_t o = (tok0 + t)*64 + vh*32 + vq*8;
    *(float4*)&OBASE[o]     = *(float4*)&ob[0];
    *(float4*)&OBASE[o + 4] = *(float4*)&ob[4];
    *(float4*)&E2[o]        = *(float4*)&ee[0];
    *(float4*)&E2[o + 4]    = *(float4*)&ee[4];
  }
}

// ---------------- k4: err reduce -> ns-gate coefficient c = 0.1*u_neu
__global__ __launch_bounds__(256) void err_kernel(
    const float* __restrict__ E, float* __restrict__ CNS) {
  int row = blockIdx.x*4 + (threadIdx.x >> 6);
  int l = threadIdx.x & 63;
  float s = wsum(E[(size_t)row*64 + l]);
  if (l == 0) {
    float z = s / (1.0f + 1e-6f);          // TEMP + 1e-6
    float sg = 1.f/(1.f+expf(-z));
    CNS[row] = (sg > 0.7f) ? 0.1f : 0.f;
  }
}

// ---------------- k5: ns scan + o assembly, software-pipelined
#define BW 16
__device__ __forceinline__ void loadw(int b, int t0, int v,
    const float* __restrict__ CNS, const float* __restrict__ NU,
    const float* __restrict__ OBASE, const float* __restrict__ PW,
    float* c, float* nu, float* ob, float* p2) {
  #pragma unroll
  for (int i = 0; i < BW; ++i) {
    size_t bt = (size_t)b*SS + (t0 + i);
    c[i]  = CNS[bt];
    nu[i] = NU[bt*64 + v];
    ob[i] = OBASE[bt*64 + v];
    p2[i] = PW[bt*3 + 2];
  }
}
__device__ __forceinline__ float procw(int b, int t0, int v, float ns,
    const float* c, const float* nu, const float* ob, const float* p2,
    float* __restrict__ OB) {
  #pragma unroll
  for (int i = 0; i < BW; ++i) {
    float cn = c[i]*nu[i];
    float a  = 1.f - c[i];
    ns = fmaf(a, ns, cn);
    float o = fmaf(p2[i], ns, ob[i]);
    OB[((size_t)b*SS + (t0+i))*64 + v] = o;
  }
  return ns;
}
__global__ __launch_bounds__(64) void nsout_kernel(
    const float* __restrict__ CNS, const float* __restrict__ NU,
    const float* __restrict__ OBASE, const float* __restrict__ PW,
    float* __restrict__ OB) {
  const int b = blockIdx.x, v = threadIdx.x;
  float cA[BW],nA[BW],oA[BW],pA[BW], cB[BW],nB[BW],oB[BW],pB[BW];
  loadw(b, 0, v, CNS, NU, OBASE, PW, cA, nA, oA, pA);
  float ns = 0.f;
  for (int t0 = 0; t0 < SS; t0 += 2*BW) {
    int tB = t0 + BW;
    loadw(b, tB, v, CNS, NU, OBASE, PW, cB, nB, oB, pB);
    ns = procw(b, t0, v, ns, cA, nA, oA, pA, OB);
    int tA2 = t0 + 2*BW; if (tA2 > SS - BW) tA2 = SS - BW;
    loadw(b, tA2, v, CNS, NU, OBASE, PW, cA, nA, oA, pA);
    ns = procw(b, tB, v, ns, cB, nB, oB, pB, OB);
  }
}

// ---------------- k6: fused RMSNorm + out = normed @ Wo^T
__global__ __launch_bounds__(256) void out_gemm(
    const float* __restrict__ OB, const float* __restrict__ Wo,
    const float* __restrict__ normw, float* __restrict__ out) {
  __shared__ float As[64*64];    // [k][m]
  __shared__ float Bs[64*128];   // [k][n]
  const int t  = threadIdx.x;
  const int m0 = blockIdx.y * 64;
  const int n0 = blockIdx.x * 128;
  {
    int r = t >> 2, q4 = t & 3;
    const float* src = OB + (size_t)(m0 + r)*64 + q4*16;
    float4 x0 = ld4(src), x1 = ld4(src+4), x2 = ld4(src+8), x3 = ld4(src+12);
    float ss = x0.x*x0.x+x0.y*x0.y+x0.z*x0.z+x0.w*x0.w
             + x1.x*x1.x+x1.y*x1.y+x1.z*x1.z+x1.w*x1.w
             + x2.x*x2.x+x2.y*x2.y+x2.z*x2.z+x2.w*x2.w
             + x3.x*x3.x+x3.y*x3.y+x3.z*x3.z+x3.w*x3.w;
    ss += __shfl_xor(ss, 1, 64);
    ss += __shfl_xor(ss, 2, 64);
    float rms = rsqrtf(ss * (1.f/64.f) + 1e-6f);
    const float* nw = normw + q4*16;
    float4 w0 = ld4(nw), w1 = ld4(nw+4), w2 = ld4(nw+8), w3 = ld4(nw+12);
    int kbase = q4*16;
    As[(kbase+ 0)*64+r]=x0.x*rms*w0.x; As[(kbase+ 1)*64+r]=x0.y*rms*w0.y;
    As[(kbase+ 2)*64+r]=x0.z*rms*w0.z; As[(kbase+ 3)*64+r]=x0.w*rms*w0.w;
    As[(kbase+ 4)*64+r]=x1.x*rms*w1.x; As[(kbase+ 5)*64+r]=x1.y*rms*w1.y;
    As[(kbase+ 6)*64+r]=x1.z*rms*w1.z; As[(kbase+ 7)*64+r]=x1.w*rms*w1.w;
    As[(kbase+ 8)*64+r]=x2.x*rms*w2.x; As[(kbase+ 9)*64+r]=x2.y*rms*w2.y;
    As[(kbase+10)*64+r]=x2.z*rms*w2.z; As[(kbase+11)*64+r]=x2.w*rms*w2.w;
    As[(kbase+12)*64+r]=x3.x*rms*w3.x; As[(kbase+13)*64+r]=x3.y*rms*w3.y;
    As[(kbase+14)*64+r]=x3.z*rms*w3.z; As[(kbase+15)*64+r]=x3.w*rms*w3.w;
  }
  {
    int rw = t >> 1, half = t & 1;
    const float* src = Wo + (size_t)(n0 + rw)*64 + half*32;
    #pragma unroll
    for (int j = 0; j < 8; ++j) {
      float4 w = ld4(src + j*4);
      int k = half*32 + j*4;
      Bs[(k+0)*128+rw] = w.x; Bs[(k+1)*128+rw] = w.y;
      Bs[(k+2)*128+rw] = w.z; Bs[(k+3)*128+rw] = w.w;
    }
  }
  __syncthreads();
  const int mi = t >> 5, ni = t & 31;
  float acc[8][4];
  #pragma unroll
  for (int i = 0; i < 8; ++i)
    #pragma unroll
    for (int j = 0; j < 4; ++j) acc[i][j] = 0.f;
  #pragma unroll 8
  for (int k = 0; k < 64; ++k) {
    float a[8], bv[4];
    float4 a0 = *(const float4*)&As[k*64 + mi*8];
    float4 a1 = *(const float4*)&As[k*64 + mi*8 + 4];
    float4 b0 = *(const float4*)&Bs[k*128 + ni*4];
    a[0]=a0.x; a[1]=a0.y; a[2]=a0.z; a[3]=a0.w;
    a[4]=a1.x; a[5]=a1.y; a[6]=a1.z; a[7]=a1.w;
    bv[0]=b0.x; bv[1]=b0.y; bv[2]=b0.z; bv[3]=b0.w;
    #pragma unroll
    for (int im = 0; im < 8; ++im)
      #pragma unroll
      for (int in = 0; in < 4; ++in)
        acc[im][in] = fmaf(a[im], bv[in], acc[im][in]);
  }
  #pragma unroll
  for (int im = 0; im < 8; ++im) {
    float4 o; o.x=acc[im][0]; o.y=acc[im][1]; o.z=acc[im][2]; o.w=acc[im][3];
    *(float4*)&out[(size_t)(m0 + mi*8 + im)*1024 + n0 + ni*4] = o;
  }
}

// ---------------- launcher ----------------
extern "C" void kernel_launch(void* const* d_in, const int* in_sizes, int n_in,
                              void* d_out, int out_size, void* d_ws, size_t ws_size,
                              hipStream_t stream) {
  const float* x     = (const float*)d_in[0];
  const float* Wk    = (const float*)d_in[1];
  const float* Wv    = (const float*)d_in[2];
  const float* Wq    = (const float*)d_in[3];
  const float* fap   = (const float*)d_in[4];
  const float* sap   = (const float*)d_in[5];
  const float* nm_w1 = (const float*)d_in[6];
  const float* nm_b1 = (const float*)d_in[7];
  const float* nm_w2 = (const float*)d_in[8];
  const float* nm_b2 = (const float*)d_in[9];
  const float* ir_w1 = (const float*)d_in[10];
  const float* ir_b1 = (const float*)d_in[11];
  const float* ir_w2 = (const float*)d_in[12];
  const float* ir_b2 = (const float*)d_in[13];
  const float* pw    = (const float*)d_in[14];
  const float* Wo    = (const float*)d_in[15];
  const float* normw = (const float*)d_in[16];
  float* out = (float*)d_out;
  float* ws  = (float*)d_ws;

  // workspace layout (floats)
  const size_t oW    = 0;                              // 320*1024
  const size_t oY    = oW + (size_t)320*1024;          // MM*320 (reused below)
  const size_t oOBASE = oY;                            // MM*64
  const size_t oE     = oY + (size_t)1*MM*64;          // MM*64
  const size_t oPfA   = oY + (size_t)2*MM*64;          // AKK -> P_f
  const size_t oAQK   = oY + (size_t)3*MM*64;          // AQK (kept for pass3)
  const size_t oPs    = oY + (size_t)4*MM*64;          // P_s
  const size_t oK    = oY + (size_t)MM*320;
  const size_t oV    = oK + (size_t)MM*64;
  const size_t oQ    = oV + (size_t)MM*64;
  const size_t oNU   = oQ + (size_t)MM*64;
  const size_t oPW   = oNU + (size_t)MM*64;
  const size_t oSCL  = oPW + (size_t)MM*3;
  const size_t oCNS  = oSCL + (size_t)MM*8;
  const size_t oOB   = oCNS + MM;
  const size_t oRf   = oOB  + (size_t)MM*64;
  const size_t oRs   = oRf  + (size_t)MM*64;
  const size_t oGf   = oRs  + (size_t)MM*64;
  const size_t oGs   = oGf  + (size_t)MM*64;
  const size_t oHf   = oGs  + (size_t)MM*64;
  const size_t oHs   = oHf  + (size_t)MM*64;
  const size_t oFstf = oHs  + (size_t)MM*64;
  const size_t oFsts = oFstf + (size_t)MM*64;

  pack_w<<<1280, 256, 0, stream>>>(Wk, Wv, Wq, ir_w1, pw, ws + oW);
  gemm1<<<dim3(128, 5), 256, 0, stream>>>(x, ws + oW, ws + oY);
  post_kernel<<<1024, 256, 0, stream>>>(ws + oY, nm_w1, nm_b1, nm_w2, nm_b2,
                                        ir_b1, ir_w2, ir_b2, sap,
                                        ws + oK, ws + oV, ws + oQ, ws + oNU,
                                        ws + oPW, ws + oSCL);
  chunkdots<<<256, 256, 0, stream>>>(ws + oK, ws + oQ, ws + oPfA, ws + oAQK);
  pass1_solve<<<256, 256, 0, stream>>>(ws + oK, ws + oV, ws + oSCL, ws + oPfA,
                                       fap, sap,
                                       ws + oPfA, ws + oRf, ws + oPs, ws + oRs);
  pass1b_gh<<<512, 256, 0, stream>>>(ws + oK,
                                     ws + oPfA, ws + oRf, ws + oPs, ws + oRs,
                                     fap, sap,
                                     ws + oGf, ws + oHf, ws + oGs, ws + oHs);
  pass2_rec<<<32, 256, 0, stream>>>(ws + oGf, ws + oHf, ws + oGs, ws + oHs,
                                    ws + oFstf, ws + oFsts);
  pass3_out<<<512, 256, 0, stream>>>(ws + oQ, ws + oV, ws + oSCL, ws + oAQK,
                                     ws + oPfA, ws + oRf, ws + oPs, ws + oRs,
                                     ws + oFstf, ws + oFsts, fap, sap,
                                     ws + oOBASE, ws + oE);
  err_kernel<<<4096, 256, 0, stream>>>(ws + oE, ws + oCNS);
  nsout_kernel<<<8, 64, 0, stream>>>(ws + oCNS, ws + oNU, ws + oOBASE,
                                     ws + oPW, ws + oOB);
  out_gemm<<<dim3(8, 256), 256, 0, stream>>>(ws + oOB, Wo, normw, out);
}

// Round 15
// 534.918 us; speedup vs baseline: 2.2093x; 2.2093x over previous
//
#include <hip/hip_runtime.h>
#include <hip/hip_bf16.h>
#include <math.h>

// Problem constants (match reference)
#define BB 8
#define SS 2048
#define DD 1024
#define DS 64
#define MM (BB*SS)   // 16384

// ---------------- helpers ----------------

__device__ __forceinline__ float4 ld4(const float* p) { return *(const float4*)p; }

template<int CTRL>
__device__ __forceinline__ float dppadd(float x) {
  int v = __builtin_amdgcn_update_dpp(0, __float_as_int(x), CTRL, 0xf, 0xf, true);
  return x + __int_as_float(v);
}

__device__ __forceinline__ float xor16add(float x) {
#if defined(__has_builtin) && __has_builtin(__builtin_amdgcn_permlane16_swap)
  auto r = __builtin_amdgcn_permlane16_swap(__float_as_uint(x), __float_as_uint(x), false, false);
  return __uint_as_float(r[0]) + __uint_as_float(r[1]);
#else
  return x + __shfl_xor(x, 16, 64);
#endif
}
__device__ __forceinline__ float xor32add(float x) {
#if defined(__has_builtin) && __has_builtin(__builtin_amdgcn_permlane32_swap)
  auto r = __builtin_amdgcn_permlane32_swap(__float_as_uint(x), __float_as_uint(x), false, false);
  return __uint_as_float(r[0]) + __uint_as_float(r[1]);
#else
  return x + __shfl_xor(x, 32, 64);
#endif
}

// full 64-lane butterfly sum; result valid in all lanes
__device__ __forceinline__ float wsum(float x) {
  x = dppadd<0xB1>(x);
  x = dppadd<0x4E>(x);
  x = dppadd<0x141>(x);
  x = dppadd<0x140>(x);
  x = xor16add(x);
  x = xor32add(x);
  return x;
}

__device__ __forceinline__ float gelu_exact(float x) {
  return 0.5f * x * (1.f + erff(x * 0.7071067811865476f));
}

// ---------------- k0: pack weights [Wk;Wv;Wq;ir_w1;pw;0-pad] -> Wcat[320][1024]
__global__ __launch_bounds__(256) void pack_w(
    const float* __restrict__ Wk, const float* __restrict__ Wv,
    const float* __restrict__ Wq, const float* __restrict__ ir_w1,
    const float* __restrict__ pw, float* __restrict__ Wcat) {
  int idx = blockIdx.x * 256 + threadIdx.x;   // 320*1024 total
  int r = idx >> 10, c = idx & 1023;
  float val = 0.f;
  if (r < 64)       val = Wk[r*1024 + c];
  else if (r < 128) val = Wv[(r-64)*1024 + c];
  else if (r < 192) val = Wq[(r-128)*1024 + c];
  else if (r < 256) val = ir_w1[(r-192)*1024 + c];
  else if (r < 259) val = pw[(r-256)*1024 + c];
  Wcat[idx] = val;
}

// ---------------- k1: Y[16384][320] = X[16384][1024] @ Wcat[320][1024]^T
__global__ __launch_bounds__(256) void gemm1(
    const float* __restrict__ X, const float* __restrict__ Wcat,
    float* __restrict__ Y) {
  __shared__ float As[32*128];   // [k][m]
  __shared__ float Bs[32*64];    // [k][n]
  const int t  = threadIdx.x;
  const int m0 = blockIdx.x * 128;
  const int n0 = blockIdx.y * 64;
  const int mi = t >> 4, ni = t & 15;
  const int rA = t >> 1, hA = t & 1;
  const int rB = t >> 2, qB = t & 3;
  float acc[8][4];
  #pragma unroll
  for (int i = 0; i < 8; ++i)
    #pragma unroll
    for (int j = 0; j < 4; ++j) acc[i][j] = 0.f;

  for (int k0 = 0; k0 < 1024; k0 += 32) {
    __syncthreads();
    {
      const float* src = X + (size_t)(m0 + rA)*1024 + k0 + hA*16;
      #pragma unroll
      for (int jj = 0; jj < 4; ++jj) {
        float4 xv = ld4(src + jj*4);
        int kk = hA*16 + jj*4;
        As[(kk+0)*128 + rA] = xv.x; As[(kk+1)*128 + rA] = xv.y;
        As[(kk+2)*128 + rA] = xv.z; As[(kk+3)*128 + rA] = xv.w;
      }
      const float* srcB = Wcat + (size_t)(n0 + rB)*1024 + k0 + qB*8;
      #pragma unroll
      for (int jj = 0; jj < 2; ++jj) {
        float4 bv = ld4(srcB + jj*4);
        int kb = qB*8 + jj*4;
        Bs[(kb+0)*64 + rB] = bv.x; Bs[(kb+1)*64 + rB] = bv.y;
        Bs[(kb+2)*64 + rB] = bv.z; Bs[(kb+3)*64 + rB] = bv.w;
      }
    }
    __syncthreads();
    #pragma unroll
    for (int kk = 0; kk < 32; ++kk) {
      float a[8], bv[4];
      float4 a0 = *(const float4*)&As[kk*128 + mi*8];
      float4 a1 = *(const float4*)&As[kk*128 + mi*8 + 4];
      float4 b0 = *(const float4*)&Bs[kk*64 + ni*4];
      a[0]=a0.x; a[1]=a0.y; a[2]=a0.z; a[3]=a0.w;
      a[4]=a1.x; a[5]=a1.y; a[6]=a1.z; a[7]=a1.w;
      bv[0]=b0.x; bv[1]=b0.y; bv[2]=b0.z; bv[3]=b0.w;
      #pragma unroll
      for (int im = 0; im < 8; ++im)
        #pragma unroll
        for (int in = 0; in < 4; ++in)
          acc[im][in] = fmaf(a[im], bv[in], acc[im][in]);
    }
  }
  #pragma unroll
  for (int im = 0; im < 8; ++im) {
    float4 o; o.x = acc[im][0]; o.y = acc[im][1]; o.z = acc[im][2]; o.w = acc[im][3];
    *(float4*)&Y[(size_t)(m0 + mi*8 + im)*320 + n0 + ni*4] = o;
  }
}

// ---------------- k2: per-token postprocess -> K,V,Q,NU,PW, SCL8[0..3]
__global__ __launch_bounds__(256) void post_kernel(
    const float* __restrict__ Y,
    const float* __restrict__ nm_w1, const float* __restrict__ nm_b1,
    const float* __restrict__ nm_w2, const float* __restrict__ nm_b2,
    const float* __restrict__ ir_b1, const float* __restrict__ ir_w2,
    const float* __restrict__ ir_b2, const float* __restrict__ sap,
    float* __restrict__ K, float* __restrict__ V, float* __restrict__ Q,
    float* __restrict__ NU, float* __restrict__ PW,
    float* __restrict__ SCL8) {
  __shared__ float w1s[128*65];
  __shared__ float w2s[64*129];
  __shared__ float vbuf[4][64];
  __shared__ float h1buf[4][128];
  const int tid = threadIdx.x, wid = tid >> 6, l = tid & 63;
  for (int i = tid; i < 128*64; i += 256) w1s[(i>>6)*65 + (i&63)]  = nm_w1[i];
  for (int i = tid; i < 64*128; i += 256) w2s[(i>>7)*129 + (i&127)] = nm_w2[i];
  __syncthreads();
  const float sa   = *sap;
  const float b1a  = nm_b1[l], b1b = nm_b1[64+l], b2l = nm_b2[l];
  const float irb1 = ir_b1[l], irw2 = ir_w2[l],  irb2 = ir_b2[0];
  for (int r = 0; r < 4; ++r) {
    const int tok = blockIdx.x*16 + r*4 + wid;
    const float* yr = Y + (size_t)tok*320;
    float kr = yr[l], vr = yr[64+l], qr = yr[128+l], hr = yr[192+l];
    float rk = 1.f / fmaxf(sqrtf(wsum(kr*kr)), 1e-12f);
    float rq = 1.f / fmaxf(sqrtf(wsum(qr*qr)), 1e-12f);
    float kn = kr*rk, qn = qr*rq;
    float qk = wsum(kn*qn);
    float g  = gelu_exact(hr + irb1);
    float logit = wsum(g*irw2) + irb2;
    float imp = 1.f/(1.f+expf(-logit));
    float bs  = (imp > 0.5f) ? (1.f - sa) : 0.f;   // (1-slow_alpha)*u_slow
    K[(size_t)tok*64+l] = kn; V[(size_t)tok*64+l] = vr; Q[(size_t)tok*64+l] = qn;
    vbuf[wid][l] = vr;
    __syncthreads();
    float h1a = b1a, h1b = b1b;
    #pragma unroll 8
    for (int c = 0; c < 64; ++c) {
      float vv = vbuf[wid][c];
      h1a = fmaf(w1s[l*65 + c], vv, h1a);
      h1b = fmaf(w1s[(64+l)*65 + c], vv, h1b);
    }
    h1buf[wid][l]    = gelu_exact(h1a);
    h1buf[wid][64+l] = gelu_exact(h1b);
    __syncthreads();
    float nu = b2l;
    #pragma unroll 8
    for (int j = 0; j < 128; ++j) nu = fmaf(w2s[l*129 + j], h1buf[wid][j], nu);
    NU[(size_t)tok*64+l] = nu;
    float p0 = yr[256], p1 = yr[257], p2 = yr[258];
    float mx = fmaxf(p0, fmaxf(p1, p2));
    float e0 = expf(p0-mx), e1 = expf(p1-mx), e2 = expf(p2-mx);
    float inv = 1.f/(e0+e1+e2);
    if (l == 0) {
      PW[(size_t)tok*3]   = e0*inv;
      float4 s; s.x = qk; s.y = bs; s.z = e0*inv; s.w = e1*inv;
      *(float4*)&SCL8[(size_t)tok*8] = s;
    }
    else if (l == 1)   PW[(size_t)tok*3+1] = e1*inv;
    else if (l == 2)   PW[(size_t)tok*3+2] = e2*inv;
    __syncthreads();
  }
}

#define STAGE68(dst, srcp) { _Pragma("unroll")                        \
    for (int it_ = 0; it_ < 4; ++it_) {                               \
      int idx4 = (threadIdx.x + it_*256)*4;                           \
      int r_ = idx4 >> 6; int d_ = idx4 & 63;                         \
      *(float4*)&dst[r_*68+d_] = ld4(&(srcp)[r_*64 + d_]); } }

// ---------------- k2c: per-chunk dot matrices for ALL (b,c) in parallel.
__global__ __launch_bounds__(256) void chunkdots(
    const float* __restrict__ K, const float* __restrict__ Q,
    float* __restrict__ AKK, float* __restrict__ AQK) {
  __shared__ float Kl[64*68], Ql[64*68];
  const int tid = threadIdx.x;
  const size_t base = (size_t)blockIdx.x * 4096;
  STAGE68(Kl, K + base)
  STAGE68(Ql, Q + base)
  __syncthreads();
  const int t0 = (tid >> 4) * 4, j0 = (tid & 15) * 4;
  float akk[4][4], aqk[4][4];
  #pragma unroll
  for (int i = 0; i < 4; ++i)
    #pragma unroll
    for (int j = 0; j < 4; ++j) { akk[i][j] = 0.f; aqk[i][j] = 0.f; }
  for (int d = 0; d < 64; ++d) {
    float kt[4], qt[4], kj[4];
    #pragma unroll
    for (int i = 0; i < 4; ++i) {
      kt[i] = Kl[(t0+i)*68 + d];
      qt[i] = Ql[(t0+i)*68 + d];
      kj[i] = Kl[(j0+i)*68 + d];
    }
    #pragma unroll
    for (int i = 0; i < 4; ++i)
      #pragma unroll
      for (int j = 0; j < 4; ++j) {
        akk[i][j] = fmaf(kt[i], kj[j], akk[i][j]);
        aqk[i][j] = fmaf(qt[i], kj[j], aqk[i][j]);
      }
  }
  #pragma unroll
  for (int i = 0; i < 4; ++i) {
    float4 a; a.x=akk[i][0]; a.y=akk[i][1]; a.z=akk[i][2]; a.w=akk[i][3];
    float4 b; b.x=aqk[i][0]; b.y=aqk[i][1]; b.z=aqk[i][2]; b.w=aqk[i][3];
    *(float4*)&AKK[base + (t0+i)*64 + j0] = a;
    *(float4*)&AQK[base + (t0+i)*64 + j0] = b;
  }
}

// ---------------- k3a: per-chunk triangular solves -> P_f, R_f, P_s, R_s
// (I + M_p) X = RHS. R14 lesson (rule #20): per-thread x[64] with a
// non-unrolled outer loop is runtime-indexed -> scratch -> 1.6GB spill
// traffic. Fix: X lives in LDS. Wave g owns one system; lane = column.
// Left-looking substitution: X[t][c] -= sum_{j<t} M[t][j]*X[j][c].
// M row = LDS broadcast, X column read = conflict-free, no barriers in
// the loop (each wave touches only its own X buffer).
__global__ __launch_bounds__(256) void pass1_solve(
    const float* __restrict__ K, const float* __restrict__ V,
    const float* __restrict__ SCL8, const float* __restrict__ AKK,
    const float* __restrict__ fap, const float* __restrict__ sap,
    float* __restrict__ Pf, float* __restrict__ Rf,
    float* __restrict__ Ps, float* __restrict__ Rs) {
  __shared__ float Mf[64*68], Ms[64*68];
  __shared__ float Xpf[64*68], Xrf[64*68], Xps[64*68], Xrs[64*68];
  __shared__ float bsv[64];
  __shared__ float fpw[65], spw[65];
  const int tid = threadIdx.x;
  const size_t chunk = blockIdx.x;
  const size_t tok0 = chunk * 64;
  const float fa = *fap, sa = *sap, omfa = 1.f - fa;
  if (tid == 0) {
    float f = 1.f, s = 1.f;
    for (int n = 0; n <= 64; ++n) { fpw[n] = f; spw[n] = s; f *= fa; s *= sa; }
  }
  STAGE68(Xpf, K + tok0*64)        // raw K
  STAGE68(Xrf, V + tok0*64)        // raw V
  STAGE68(Mf, AKK + chunk*4096)    // raw Akk
  if (tid < 64) bsv[tid] = SCL8[(tok0 + tid)*8 + 1];
  __syncthreads();
  // build masked M + all four RHS (in place; each (t,j) owned by one thread)
  {
    const int t = tid >> 2, j0 = (tid & 3) * 16;
    const float bst = bsv[t];
    const float cpf = omfa*fpw[t], cps = bst*spw[t];
    #pragma unroll
    for (int i = 0; i < 16; ++i) {
      int j = j0 + i;
      float a    = Mf [t*68 + j];
      float kraw = Xpf[t*68 + j];
      float vraw = Xrf[t*68 + j];
      bool lt = (j < t);
      int p = lt ? (t-1-j) : 0;
      Ms [t*68 + j] = lt ? bst*spw[p]*a  : 0.f;
      Mf [t*68 + j] = lt ? omfa*fpw[p]*a : 0.f;
      Xps[t*68 + j] = cps * kraw;
      Xpf[t*68 + j] = cpf * kraw;
      Xrs[t*68 + j] = bst * vraw;
      Xrf[t*68 + j] = omfa * vraw;
    }
  }
  __syncthreads();

  const int g  = tid >> 6;     // 0:Pf 1:Rf 2:Ps 3:Rs (wave-uniform)
  const int cc = tid & 63;     // column
  const float* M = (g < 2) ? Mf : Ms;
  float* X = (g == 0) ? Xpf : (g == 1) ? Xrf : (g == 2) ? Xps : Xrs;
  for (int t = 1; t < 64; ++t) {
    float a0 = 0.f, a1 = 0.f, a2 = 0.f, a3 = 0.f;
    int j = 0;
    for (; j + 4 <= t; j += 4) {
      float4 m = *(const float4*)&M[t*68 + j];
      a0 = fmaf(m.x, X[(j+0)*68 + cc], a0);
      a1 = fmaf(m.y, X[(j+1)*68 + cc], a1);
      a2 = fmaf(m.z, X[(j+2)*68 + cc], a2);
      a3 = fmaf(m.w, X[(j+3)*68 + cc], a3);
    }
    for (; j < t; ++j) a0 = fmaf(M[t*68 + j], X[j*68 + cc], a0);
    X[t*68 + cc] -= ((a0 + a1) + (a2 + a3));
  }
  float* dst = (g == 0) ? Pf : (g == 1) ? Rf : (g == 2) ? Ps : Rs;
  const size_t base = chunk*4096 + cc;
  for (int t = 0; t < 64; ++t) dst[base + t*64] = X[t*68 + cc];
}

// ---------------- k3b: G = d^64 I - K^T E P, H = K^T E R (per chunk, path)
__global__ __launch_bounds__(256) void pass1b_gh(
    const float* __restrict__ K,
    const float* __restrict__ Pf, const float* __restrict__ Rf,
    const float* __restrict__ Ps, const float* __restrict__ Rs,
    const float* __restrict__ fap, const float* __restrict__ sap,
    float* __restrict__ Gf, float* __restrict__ Hf,
    float* __restrict__ Gs, float* __restrict__ Hs) {
  __shared__ float Kc[64*68], Pl[64*68], Rl[64*68];
  __shared__ float dpw[65];
  const int tid = threadIdx.x;
  const size_t chunk = blockIdx.x >> 1;
  const int path = blockIdx.x & 1;
  const float d = path ? (*sap) : (*fap);
  if (tid == 0) {
    float p = 1.f;
    for (int n = 0; n <= 64; ++n) { dpw[n] = p; p *= d; }
  }
  const float* Pg = path ? Ps : Pf;
  const float* Rg = path ? Rs : Rf;
  float* Gg = path ? Gs : Gf;
  float* Hg = path ? Hs : Hf;
  STAGE68(Kc, K + chunk*4096)
  STAGE68(Pl, Pg + chunk*4096)
  STAGE68(Rl, Rg + chunk*4096)
  __syncthreads();
  const int kd = tid >> 2, c0 = (tid & 3) * 16;
  float accG[16], accH[16];
  #pragma unroll
  for (int i = 0; i < 16; ++i) { accG[i] = 0.f; accH[i] = 0.f; }
  #pragma unroll 8
  for (int j = 0; j < 64; ++j) {
    const float w = Kc[j*68 + kd] * dpw[63 - j];
    #pragma unroll
    for (int i4 = 0; i4 < 4; ++i4) {
      float4 p = *(const float4*)&Pl[j*68 + c0 + i4*4];
      float4 r = *(const float4*)&Rl[j*68 + c0 + i4*4];
      accG[i4*4+0] = fmaf(w, p.x, accG[i4*4+0]);
      accG[i4*4+1] = fmaf(w, p.y, accG[i4*4+1]);
      accG[i4*4+2] = fmaf(w, p.z, accG[i4*4+2]);
      accG[i4*4+3] = fmaf(w, p.w, accG[i4*4+3]);
      accH[i4*4+0] = fmaf(w, r.x, accH[i4*4+0]);
      accH[i4*4+1] = fmaf(w, r.y, accH[i4*4+1]);
      accH[i4*4+2] = fmaf(w, r.z, accH[i4*4+2]);
      accH[i4*4+3] = fmaf(w, r.w, accH[i4*4+3]);
    }
  }
  const float d64 = dpw[64];
  #pragma unroll
  for (int i4 = 0; i4 < 4; ++i4) {
    float4 go, ho;
    float* gp = (float*)&go; float* hp = (float*)&ho;
    #pragma unroll
    for (int i = 0; i < 4; ++i) {
      int col = c0 + i4*4 + i;
      gp[i] = ((col == kd) ? d64 : 0.f) - accG[i4*4+i];
      hp[i] = accH[i4*4+i];
    }
    *(float4*)&Gg[chunk*4096 + (size_t)kd*64 + c0 + i4*4] = go;
    *(float4*)&Hg[chunk*4096 + (size_t)kd*64 + c0 + i4*4] = ho;
  }
}

// ---------------- k3c: sequential state recurrence F' = G F + H.
// Grid 32 = 8b x 2path x 2vhalf, 256 threads. Stores pre-state to Fst.
__global__ __launch_bounds__(256) void pass2_rec(
    const float* __restrict__ Gf, const float* __restrict__ Hf,
    const float* __restrict__ Gs, const float* __restrict__ Hs,
    float* __restrict__ Fstf, float* __restrict__ Fsts) {
  __shared__ float Fl[64*36], Gl[64*68], Hl[64*36];
  const int tid = threadIdx.x;
  const int b = blockIdx.x >> 2;
  const int path = (blockIdx.x >> 1) & 1;
  const int vh = blockIdx.x & 1;
  const float* Gg = path ? Gs : Gf;
  const float* Hg = path ? Hs : Hf;
  float* Fstg = path ? Fsts : Fstf;
  const int kd = tid >> 2, vq = tid & 3;      // 64 x 4(8v)
  #pragma unroll
  for (int i = 0; i < 8; ++i) Fl[kd*36 + vq*8 + i] = 0.f;
  __syncthreads();
  for (int c = 0; c < 32; ++c) {
    const size_t chunk = (size_t)b*32 + c;
    STAGE68(Gl, Gg + chunk*4096)
    *(float4*)&Hl[kd*36 + vq*8]     = ld4(&Hg[chunk*4096 + kd*64 + vh*32 + vq*8]);
    *(float4*)&Hl[kd*36 + vq*8 + 4] = ld4(&Hg[chunk*4096 + kd*64 + vh*32 + vq*8 + 4]);
    // store pre-state (stable since last barrier)
    *(float4*)&Fstg[chunk*4096 + (size_t)kd*64 + vh*32 + vq*8]     = *(float4*)&Fl[kd*36 + vq*8];
    *(float4*)&Fstg[chunk*4096 + (size_t)kd*64 + vh*32 + vq*8 + 4] = *(float4*)&Fl[kd*36 + vq*8 + 4];
    __syncthreads();
    float acc[8];
    #pragma unroll
    for (int i = 0; i < 8; ++i) acc[i] = Hl[kd*36 + vq*8 + i];
    #pragma unroll 8
    for (int j = 0; j < 64; ++j) {
      const float g = Gl[kd*68 + j];
      float4 f0 = *(const float4*)&Fl[j*36 + vq*8];
      float4 f1 = *(const float4*)&Fl[j*36 + vq*8 + 4];
      acc[0]=fmaf(g,f0.x,acc[0]); acc[1]=fmaf(g,f0.y,acc[1]);
      acc[2]=fmaf(g,f0.z,acc[2]); acc[3]=fmaf(g,f0.w,acc[3]);
      acc[4]=fmaf(g,f1.x,acc[4]); acc[5]=fmaf(g,f1.y,acc[5]);
      acc[6]=fmaf(g,f1.z,acc[6]); acc[7]=fmaf(g,f1.w,acc[7]);
    }
    __syncthreads();
    #pragma unroll
    for (int i = 0; i < 8; ++i) Fl[kd*36 + vq*8 + i] = acc[i];
    __syncthreads();
  }
}

// ---------------- k3d: parallel outputs per chunk (needs Fst states).
// Grid 512 = 256 chunks x 2 vhalf, 256 threads.
__global__ __launch_bounds__(256) void pass3_out(
    const float* __restrict__ Q, const float* __restrict__ V,
    const float* __restrict__ SCL8, const float* __restrict__ AQK,
    const float* __restrict__ Pf, const float* __restrict__ Rf,
    const float* __restrict__ Ps, const float* __restrict__ Rs,
    const float* __restrict__ Fstf, const float* __restrict__ Fsts,
    const float* __restrict__ fap, const float* __restrict__ sap,
    float* __restrict__ OBASE, float* __restrict__ E2) {
  __shared__ float Qcl[64*68], AQKl[64*68], Pfl[64*68], Psl[64*68];
  __shared__ float Vl[64*36], Rfl[64*36], Rsl[64*36];
  __shared__ float F0l[64*36], S0l[64*36], Ufl[64*36], Usl[64*36];
  __shared__ float scal[256];
  __shared__ float fpw[65], spw[65];
  const int tid = threadIdx.x;
  const size_t chunk = blockIdx.x >> 1;
  const int vh = blockIdx.x & 1;
  const size_t tok0 = chunk * 64;
  const float fa = *fap, sa = *sap;
  if (tid == 0) {
    float f = 1.f, s = 1.f;
    for (int n = 0; n <= 64; ++n) { fpw[n] = f; spw[n] = s; f *= fa; s *= sa; }
  }
  STAGE68(Qcl,  Q   + tok0*64)
  STAGE68(AQKl, AQK + chunk*4096)
  STAGE68(Pfl,  Pf  + chunk*4096)
  STAGE68(Psl,  Ps  + chunk*4096)
  {
    const int r = tid >> 2, vq = tid & 3;
    const size_t off = chunk*4096 + (size_t)r*64 + vh*32 + vq*8;
    *(float4*)&Vl [r*36 + vq*8]     = ld4(&V   [tok0*64 + (size_t)r*64 + vh*32 + vq*8]);
    *(float4*)&Vl [r*36 + vq*8 + 4] = ld4(&V   [tok0*64 + (size_t)r*64 + vh*32 + vq*8 + 4]);
    *(float4*)&Rfl[r*36 + vq*8]     = ld4(&Rf  [off]);
    *(float4*)&Rfl[r*36 + vq*8 + 4] = ld4(&Rf  [off + 4]);
    *(float4*)&Rsl[r*36 + vq*8]     = ld4(&Rs  [off]);
    *(float4*)&Rsl[r*36 + vq*8 + 4] = ld4(&Rs  [off + 4]);
    *(float4*)&F0l[r*36 + vq*8]     = ld4(&Fstf[off]);
    *(float4*)&F0l[r*36 + vq*8 + 4] = ld4(&Fstf[off + 4]);
    *(float4*)&S0l[r*36 + vq*8]     = ld4(&Fsts[off]);
    *(float4*)&S0l[r*36 + vq*8 + 4] = ld4(&Fsts[off + 4]);
    scal[tid] = SCL8[(tok0 + r)*8 + vq];
  }
  __syncthreads();
  // phase A: U_f = R_f - P_f F0, U_s = R_s - P_s S0
  {
    const int j = tid >> 2, vq = tid & 3;
    float uf[8], us[8];
    #pragma unroll
    for (int i = 0; i < 8; ++i) { uf[i] = 0.f; us[i] = 0.f; }
    #pragma unroll 8
    for (int kd = 0; kd < 64; ++kd) {
      const float pfv = Pfl[j*68 + kd];
      const float psv = Psl[j*68 + kd];
      float4 f0 = *(const float4*)&F0l[kd*36 + vq*8];
      float4 f1 = *(const float4*)&F0l[kd*36 + vq*8 + 4];
      float4 s0 = *(const float4*)&S0l[kd*36 + vq*8];
      float4 s1 = *(const float4*)&S0l[kd*36 + vq*8 + 4];
      uf[0]=fmaf(pfv,f0.x,uf[0]); uf[1]=fmaf(pfv,f0.y,uf[1]);
      uf[2]=fmaf(pfv,f0.z,uf[2]); uf[3]=fmaf(pfv,f0.w,uf[3]);
      uf[4]=fmaf(pfv,f1.x,uf[4]); uf[5]=fmaf(pfv,f1.y,uf[5]);
      uf[6]=fmaf(pfv,f1.z,uf[6]); uf[7]=fmaf(pfv,f1.w,uf[7]);
      us[0]=fmaf(psv,s0.x,us[0]); us[1]=fmaf(psv,s0.y,us[1]);
      us[2]=fmaf(psv,s0.z,us[2]); us[3]=fmaf(psv,s0.w,us[3]);
      us[4]=fmaf(psv,s1.x,us[4]); us[5]=fmaf(psv,s1.y,us[5]);
      us[6]=fmaf(psv,s1.z,us[6]); us[7]=fmaf(psv,s1.w,us[7]);
    }
    #pragma unroll
    for (int i = 0; i < 8; ++i) {
      Ufl[j*36 + vq*8 + i] = Rfl[j*36 + vq*8 + i] - uf[i];
      Usl[j*36 + vq*8 + i] = Rsl[j*36 + vq*8 + i] - us[i];
    }
  }
  __syncthreads();
  // phase B: per-token outputs
  {
    const int t = tid >> 2, vq = tid & 3;
    float af[8], as_[8];
    #pragma unroll
    for (int i = 0; i < 8; ++i) { af[i] = 0.f; as_[i] = 0.f; }
    #pragma unroll 8
    for (int kd = 0; kd < 64; ++kd) {
      const float q = Qcl[t*68 + kd];
      float4 f0 = *(const float4*)&F0l[kd*36 + vq*8];
      float4 f1 = *(const float4*)&F0l[kd*36 + vq*8 + 4];
      float4 s0 = *(const float4*)&S0l[kd*36 + vq*8];
      float4 s1 = *(const float4*)&S0l[kd*36 + vq*8 + 4];
      af[0]=fmaf(q,f0.x,af[0]); af[1]=fmaf(q,f0.y,af[1]);
      af[2]=fmaf(q,f0.z,af[2]); af[3]=fmaf(q,f0.w,af[3]);
      af[4]=fmaf(q,f1.x,af[4]); af[5]=fmaf(q,f1.y,af[5]);
      af[6]=fmaf(q,f1.z,af[6]); af[7]=fmaf(q,f1.w,af[7]);
      as_[0]=fmaf(q,s0.x,as_[0]); as_[1]=fmaf(q,s0.y,as_[1]);
      as_[2]=fmaf(q,s0.z,as_[2]); as_[3]=fmaf(q,s0.w,as_[3]);
      as_[4]=fmaf(q,s1.x,as_[4]); as_[5]=fmaf(q,s1.y,as_[5]);
      as_[6]=fmaf(q,s1.z,as_[6]); as_[7]=fmaf(q,s1.w,as_[7]);
    }
    float pq[8], pqs[8];
    #pragma unroll
    for (int i = 0; i < 8; ++i) { pq[i] = fpw[t]*af[i]; pqs[i] = spw[t]*as_[i]; }
    for (int j = 0; j < 64; ++j) {
      const float aq = AQKl[t*68 + j];
      const bool lt = (j < t);
      const int p = lt ? (t-1-j) : 0;
      const float wf = lt ? fpw[p]*aq : 0.f;
      const float ws = lt ? spw[p]*aq : 0.f;
      float4 u0 = *(const float4*)&Ufl[j*36 + vq*8];
      float4 u1 = *(const float4*)&Ufl[j*36 + vq*8 + 4];
      float4 w0 = *(const float4*)&Usl[j*36 + vq*8];
      float4 w1 = *(const float4*)&Usl[j*36 + vq*8 + 4];
      pq[0]=fmaf(wf,u0.x,pq[0]); pq[1]=fmaf(wf,u0.y,pq[1]);
      pq[2]=fmaf(wf,u0.z,pq[2]); pq[3]=fmaf(wf,u0.w,pq[3]);
      pq[4]=fmaf(wf,u1.x,pq[4]); pq[5]=fmaf(wf,u1.y,pq[5]);
      pq[6]=fmaf(wf,u1.z,pq[6]); pq[7]=fmaf(wf,u1.w,pq[7]);
      pqs[0]=fmaf(ws,w0.x,pqs[0]); pqs[1]=fmaf(ws,w0.y,pqs[1]);
      pqs[2]=fmaf(ws,w0.z,pqs[2]); pqs[3]=fmaf(ws,w0.w,pqs[3]);
      pqs[4]=fmaf(ws,w1.x,pqs[4]); pqs[5]=fmaf(ws,w1.y,pqs[5]);
      pqs[6]=fmaf(ws,w1.z,pqs[6]); pqs[7]=fmaf(ws,w1.w,pqs[7]);
    }
    const float qk = scal[t*4+0], p0 = scal[t*4+2], p1 = scal[t*4+3];
    float ob[8], ee[8];
    #pragma unroll
    for (int i = 0; i < 8; ++i) {
      const float uft = Ufl[t*36 + vq*8 + i];
      const float ust = Usl[t*36 + vq*8 + i];
      const float qfn = fmaf(fa, pq[i],  qk*uft);
      const float qsn = fmaf(sa, pqs[i], qk*ust);
      ob[i] = fmaf(p0, qfn, p1*qsn);
      const float pd = Vl[t*36 + vq*8 + i] - 0.5f*(pq[i] + pqs[i]);
      ee[i] = pd*pd;
    }
    const size_t o = (tok0 + t)*64 + vh*32 + vq*8;
    *(float4*)&OBASE[o]     = *(float4*)&ob[0];
    *(float4*)&OBASE[o + 4] = *(float4*)&ob[4];
    *(float4*)&E2[o]        = *(float4*)&ee[0];
    *(float4*)&E2[o + 4]    = *(float4*)&ee[4];
  }
}

// ---------------- k4: err reduce -> ns-gate coefficient c = 0.1*u_neu
__global__ __launch_bounds__(256) void err_kernel(
    const float* __restrict__ E, float* __restrict__ CNS) {
  int row = blockIdx.x*4 + (threadIdx.x >> 6);
  int l = threadIdx.x & 63;
  float s = wsum(E[(size_t)row*64 + l]);
  if (l == 0) {
    float z = s / (1.0f + 1e-6f);          // TEMP + 1e-6
    float sg = 1.f/(1.f+expf(-z));
    CNS[row] = (sg > 0.7f) ? 0.1f : 0.f;
  }
}

// ---------------- k5: ns scan + o assembly, software-pipelined
#define BW 16
__device__ __forceinline__ void loadw(int b, int t0, int v,
    const float* __restrict__ CNS, const float* __restrict__ NU,
    const float* __restrict__ OBASE, const float* __restrict__ PW,
    float* c, float* nu, float* ob, float* p2) {
  #pragma unroll
  for (int i = 0; i < BW; ++i) {
    size_t bt = (size_t)b*SS + (t0 + i);
    c[i]  = CNS[bt];
    nu[i] = NU[bt*64 + v];
    ob[i] = OBASE[bt*64 + v];
    p2[i] = PW[bt*3 + 2];
  }
}
__device__ __forceinline__ float procw(int b, int t0, int v, float ns,
    const float* c, const float* nu, const float* ob, const float* p2,
    float* __restrict__ OB) {
  #pragma unroll
  for (int i = 0; i < BW; ++i) {
    float cn = c[i]*nu[i];
    float a  = 1.f - c[i];
    ns = fmaf(a, ns, cn);
    float o = fmaf(p2[i], ns, ob[i]);
    OB[((size_t)b*SS + (t0+i))*64 + v] = o;
  }
  return ns;
}
__global__ __launch_bounds__(64) void nsout_kernel(
    const float* __restrict__ CNS, const float* __restrict__ NU,
    const float* __restrict__ OBASE, const float* __restrict__ PW,
    float* __restrict__ OB) {
  const int b = blockIdx.x, v = threadIdx.x;
  float cA[BW],nA[BW],oA[BW],pA[BW], cB[BW],nB[BW],oB[BW],pB[BW];
  loadw(b, 0, v, CNS, NU, OBASE, PW, cA, nA, oA, pA);
  float ns = 0.f;
  for (int t0 = 0; t0 < SS; t0 += 2*BW) {
    int tB = t0 + BW;
    loadw(b, tB, v, CNS, NU, OBASE, PW, cB, nB, oB, pB);
    ns = procw(b, t0, v, ns, cA, nA, oA, pA, OB);
    int tA2 = t0 + 2*BW; if (tA2 > SS - BW) tA2 = SS - BW;
    loadw(b, tA2, v, CNS, NU, OBASE, PW, cA, nA, oA, pA);
    ns = procw(b, tB, v, ns, cB, nB, oB, pB, OB);
  }
}

// ---------------- k6: fused RMSNorm + out = normed @ Wo^T
__global__ __launch_bounds__(256) void out_gemm(
    const float* __restrict__ OB, const float* __restrict__ Wo,
    const float* __restrict__ normw, float* __restrict__ out) {
  __shared__ float As[64*64];    // [k][m]
  __shared__ float Bs[64*128];   // [k][n]
  const int t  = threadIdx.x;
  const int m0 = blockIdx.y * 64;
  const int n0 = blockIdx.x * 128;
  {
    int r = t >> 2, q4 = t & 3;
    const float* src = OB + (size_t)(m0 + r)*64 + q4*16;
    float4 x0 = ld4(src), x1 = ld4(src+4), x2 = ld4(src+8), x3 = ld4(src+12);
    float ss = x0.x*x0.x+x0.y*x0.y+x0.z*x0.z+x0.w*x0.w
             + x1.x*x1.x+x1.y*x1.y+x1.z*x1.z+x1.w*x1.w
             + x2.x*x2.x+x2.y*x2.y+x2.z*x2.z+x2.w*x2.w
             + x3.x*x3.x+x3.y*x3.y+x3.z*x3.z+x3.w*x3.w;
    ss += __shfl_xor(ss, 1, 64);
    ss += __shfl_xor(ss, 2, 64);
    float rms = rsqrtf(ss * (1.f/64.f) + 1e-6f);
    const float* nw = normw + q4*16;
    float4 w0 = ld4(nw), w1 = ld4(nw+4), w2 = ld4(nw+8), w3 = ld4(nw+12);
    int kbase = q4*16;
    As[(kbase+ 0)*64+r]=x0.x*rms*w0.x; As[(kbase+ 1)*64+r]=x0.y*rms*w0.y;
    As[(kbase+ 2)*64+r]=x0.z*rms*w0.z; As[(kbase+ 3)*64+r]=x0.w*rms*w0.w;
    As[(kbase+ 4)*64+r]=x1.x*rms*w1.x; As[(kbase+ 5)*64+r]=x1.y*rms*w1.y;
    As[(kbase+ 6)*64+r]=x1.z*rms*w1.z; As[(kbase+ 7)*64+r]=x1.w*rms*w1.w;
    As[(kbase+ 8)*64+r]=x2.x*rms*w2.x; As[(kbase+ 9)*64+r]=x2.y*rms*w2.y;
    As[(kbase+10)*64+r]=x2.z*rms*w2.z; As[(kbase+11)*64+r]=x2.w*rms*w2.w;
    As[(kbase+12)*64+r]=x3.x*rms*w3.x; As[(kbase+13)*64+r]=x3.y*rms*w3.y;
    As[(kbase+14)*64+r]=x3.z*rms*w3.z; As[(kbase+15)*64+r]=x3.w*rms*w3.w;
  }
  {
    int rw = t >> 1, half = t & 1;
    const float* src = Wo + (size_t)(n0 + rw)*64 + half*32;
    #pragma unroll
    for (int j = 0; j < 8; ++j) {
      float4 w = ld4(src + j*4);
      int k = half*32 + j*4;
      Bs[(k+0)*128+rw] = w.x; Bs[(k+1)*128+rw] = w.y;
      Bs[(k+2)*128+rw] = w.z; Bs[(k+3)*128+rw] = w.w;
    }
  }
  __syncthreads();
  const int mi = t >> 5, ni = t & 31;
  float acc[8][4];
  #pragma unroll
  for (int i = 0; i < 8; ++i)
    #pragma unroll
    for (int j = 0; j < 4; ++j) acc[i][j] = 0.f;
  #pragma unroll 8
  for (int k = 0; k < 64; ++k) {
    float a[8], bv[4];
    float4 a0 = *(const float4*)&As[k*64 + mi*8];
    float4 a1 = *(const float4*)&As[k*64 + mi*8 + 4];
    float4 b0 = *(const float4*)&Bs[k*128 + ni*4];
    a[0]=a0.x; a[1]=a0.y; a[2]=a0.z; a[3]=a0.w;
    a[4]=a1.x; a[5]=a1.y; a[6]=a1.z; a[7]=a1.w;
    bv[0]=b0.x; bv[1]=b0.y; bv[2]=b0.z; bv[3]=b0.w;
    #pragma unroll
    for (int im = 0; im < 8; ++im)
      #pragma unroll
      for (int in = 0; in < 4; ++in)
        acc[im][in] = fmaf(a[im], bv[in], acc[im][in]);
  }
  #pragma unroll
  for (int im = 0; im < 8; ++im) {
    float4 o; o.x=acc[im][0]; o.y=acc[im][1]; o.z=acc[im][2]; o.w=acc[im][3];
    *(float4*)&out[(size_t)(m0 + mi*8 + im)*1024 + n0 + ni*4] = o;
  }
}

// ---------------- launcher ----------------
extern "C" void kernel_launch(void* const* d_in, const int* in_sizes, int n_in,
                              void* d_out, int out_size, void* d_ws, size_t ws_size,
                              hipStream_t stream) {
  const float* x     = (const float*)d_in[0];
  const float* Wk    = (const float*)d_in[1];
  const float* Wv    = (const float*)d_in[2];
  const float* Wq    = (const float*)d_in[3];
  const float* fap   = (const float*)d_in[4];
  const float* sap   = (const float*)d_in[5];
  const float* nm_w1 = (const float*)d_in[6];
  const float* nm_b1 = (const float*)d_in[7];
  const float* nm_w2 = (const float*)d_in[8];
  const float* nm_b2 = (const float*)d_in[9];
  const float* ir_w1 = (const float*)d_in[10];
  const float* ir_b1 = (const float*)d_in[11];
  const float* ir_w2 = (const float*)d_in[12];
  const float* ir_b2 = (const float*)d_in[13];
  const float* pw    = (const float*)d_in[14];
  const float* Wo    = (const float*)d_in[15];
  const float* normw = (const float*)d_in[16];
  float* out = (float*)d_out;
  float* ws  = (float*)d_ws;

  // workspace layout (floats)
  const size_t oW    = 0;                              // 320*1024
  const size_t oY    = oW + (size_t)320*1024;          // MM*320 (reused below)
  const size_t oOBASE = oY;                            // MM*64
  const size_t oE     = oY + (size_t)1*MM*64;          // MM*64
  const size_t oPfA   = oY + (size_t)2*MM*64;          // AKK -> P_f
  const size_t oAQK   = oY + (size_t)3*MM*64;          // AQK (kept for pass3)
  const size_t oPs    = oY + (size_t)4*MM*64;          // P_s
  const size_t oK    = oY + (size_t)MM*320;
  const size_t oV    = oK + (size_t)MM*64;
  const size_t oQ    = oV + (size_t)MM*64;
  const size_t oNU   = oQ + (size_t)MM*64;
  const size_t oPW   = oNU + (size_t)MM*64;
  const size_t oSCL  = oPW + (size_t)MM*3;
  const size_t oCNS  = oSCL + (size_t)MM*8;
  const size_t oOB   = oCNS + MM;
  const size_t oRf   = oOB  + (size_t)MM*64;
  const size_t oRs   = oRf  + (size_t)MM*64;
  const size_t oGf   = oRs  + (size_t)MM*64;
  const size_t oGs   = oGf  + (size_t)MM*64;
  const size_t oHf   = oGs  + (size_t)MM*64;
  const size_t oHs   = oHf  + (size_t)MM*64;
  const size_t oFstf = oHs  + (size_t)MM*64;
  const size_t oFsts = oFstf + (size_t)MM*64;

  pack_w<<<1280, 256, 0, stream>>>(Wk, Wv, Wq, ir_w1, pw, ws + oW);
  gemm1<<<dim3(128, 5), 256, 0, stream>>>(x, ws + oW, ws + oY);
  post_kernel<<<1024, 256, 0, stream>>>(ws + oY, nm_w1, nm_b1, nm_w2, nm_b2,
                                        ir_b1, ir_w2, ir_b2, sap,
                                        ws + oK, ws + oV, ws + oQ, ws + oNU,
                                        ws + oPW, ws + oSCL);
  chunkdots<<<256, 256, 0, stream>>>(ws + oK, ws + oQ, ws + oPfA, ws + oAQK);
  pass1_solve<<<256, 256, 0, stream>>>(ws + oK, ws + oV, ws + oSCL, ws + oPfA,
                                       fap, sap,
                                       ws + oPfA, ws + oRf, ws + oPs, ws + oRs);
  pass1b_gh<<<512, 256, 0, stream>>>(ws + oK,
                                     ws + oPfA, ws + oRf, ws + oPs, ws + oRs,
                                     fap, sap,
                                     ws + oGf, ws + oHf, ws + oGs, ws + oHs);
  pass2_rec<<<32, 256, 0, stream>>>(ws + oGf, ws + oHf, ws + oGs, ws + oHs,
                                    ws + oFstf, ws + oFsts);
  pass3_out<<<512, 256, 0, stream>>>(ws + oQ, ws + oV, ws + oSCL, ws + oAQK,
                                     ws + oPfA, ws + oRf, ws + oPs, ws + oRs,
                                     ws + oFstf, ws + oFsts, fap, sap,
                                     ws + oOBASE, ws + oE);
  err_kernel<<<4096, 256, 0, stream>>>(ws + oE, ws + oCNS);
  nsout_kernel<<<8, 64, 0, stream>>>(ws + oCNS, ws + oNU, ws + oOBASE,
                                     ws + oPW, ws + oOB);
  out_gemm<<<dim3(8, 256), 256, 0, stream>>>(ws + oOB, Wo, normw, out);
}

// Round 16
// 510.006 us; speedup vs baseline: 2.3172x; 1.0488x over previous
//
#include <hip/hip_runtime.h>
#include <hip/hip_bf16.h>
#include <math.h>

// Problem constants (match reference)
#define BB 8
#define SS 2048
#define DD 1024
#define DS 64
#define MM (BB*SS)   // 16384

// ---------------- helpers ----------------

__device__ __forceinline__ float4 ld4(const float* p) { return *(const float4*)p; }

template<int CTRL>
__device__ __forceinline__ float dppadd(float x) {
  int v = __builtin_amdgcn_update_dpp(0, __float_as_int(x), CTRL, 0xf, 0xf, true);
  return x + __int_as_float(v);
}

__device__ __forceinline__ float xor16add(float x) {
#if defined(__has_builtin) && __has_builtin(__builtin_amdgcn_permlane16_swap)
  auto r = __builtin_amdgcn_permlane16_swap(__float_as_uint(x), __float_as_uint(x), false, false);
  return __uint_as_float(r[0]) + __uint_as_float(r[1]);
#else
  return x + __shfl_xor(x, 16, 64);
#endif
}
__device__ __forceinline__ float xor32add(float x) {
#if defined(__has_builtin) && __has_builtin(__builtin_amdgcn_permlane32_swap)
  auto r = __builtin_amdgcn_permlane32_swap(__float_as_uint(x), __float_as_uint(x), false, false);
  return __uint_as_float(r[0]) + __uint_as_float(r[1]);
#else
  return x + __shfl_xor(x, 32, 64);
#endif
}

// full 64-lane butterfly sum; result valid in all lanes
__device__ __forceinline__ float wsum(float x) {
  x = dppadd<0xB1>(x);
  x = dppadd<0x4E>(x);
  x = dppadd<0x141>(x);
  x = dppadd<0x140>(x);
  x = xor16add(x);
  x = xor32add(x);
  return x;
}

__device__ __forceinline__ float gelu_exact(float x) {
  return 0.5f * x * (1.f + erff(x * 0.7071067811865476f));
}

// ---------------- k0: pack weights [Wk;Wv;Wq;ir_w1;pw;0-pad] -> Wcat[320][1024]
__global__ __launch_bounds__(256) void pack_w(
    const float* __restrict__ Wk, const float* __restrict__ Wv,
    const float* __restrict__ Wq, const float* __restrict__ ir_w1,
    const float* __restrict__ pw, float* __restrict__ Wcat) {
  int idx = blockIdx.x * 256 + threadIdx.x;   // 320*1024 total
  int r = idx >> 10, c = idx & 1023;
  float val = 0.f;
  if (r < 64)       val = Wk[r*1024 + c];
  else if (r < 128) val = Wv[(r-64)*1024 + c];
  else if (r < 192) val = Wq[(r-128)*1024 + c];
  else if (r < 256) val = ir_w1[(r-192)*1024 + c];
  else if (r < 259) val = pw[(r-256)*1024 + c];
  Wcat[idx] = val;
}

// ---------------- k1: YP[z][16384][320] = X[.][k-half z] @ Wcat[.][z]^T
// Split-K=2: grid (128,5,2); z picks K-half. 1280 blocks -> 5 blocks/CU.
// Bs staged lane=column (store addr = const + lane) -> bank-conflict-free.
__global__ __launch_bounds__(256) void gemm1(
    const float* __restrict__ X, const float* __restrict__ Wcat,
    float* __restrict__ YP0, float* __restrict__ YP1) {
  __shared__ float As[32*128];   // [k][m]
  __shared__ float Bs[32*68];    // [k][n], stride 68
  const int t  = threadIdx.x;
  const int m0 = blockIdx.x * 128;
  const int n0 = blockIdx.y * 64;
  const int kh = blockIdx.z;          // K-half
  const int kbase = kh * 512;
  const int mi = t >> 4, ni = t & 15;
  const int rA = t >> 1, hA = t & 1;
  const int rB = t & 63, qB = t >> 6; // lane=column mapping (conflict-free store)
  float acc[8][4];
  #pragma unroll
  for (int i = 0; i < 8; ++i)
    #pragma unroll
    for (int j = 0; j < 4; ++j) acc[i][j] = 0.f;

  for (int k0 = kbase; k0 < kbase + 512; k0 += 32) {
    __syncthreads();
    {
      const float* src = X + (size_t)(m0 + rA)*1024 + k0 + hA*16;
      #pragma unroll
      for (int jj = 0; jj < 4; ++jj) {
        float4 xv = ld4(src + jj*4);
        int kk = hA*16 + jj*4;
        As[(kk+0)*128 + rA] = xv.x; As[(kk+1)*128 + rA] = xv.y;
        As[(kk+2)*128 + rA] = xv.z; As[(kk+3)*128 + rA] = xv.w;
      }
      const float* srcB = Wcat + (size_t)(n0 + rB)*1024 + k0 + qB*8;
      #pragma unroll
      for (int jj = 0; jj < 2; ++jj) {
        float4 bv = ld4(srcB + jj*4);
        int kb = qB*8 + jj*4;
        Bs[(kb+0)*68 + rB] = bv.x; Bs[(kb+1)*68 + rB] = bv.y;
        Bs[(kb+2)*68 + rB] = bv.z; Bs[(kb+3)*68 + rB] = bv.w;
      }
    }
    __syncthreads();
    #pragma unroll
    for (int kk = 0; kk < 32; ++kk) {
      float a[8], bv[4];
      float4 a0 = *(const float4*)&As[kk*128 + mi*8];
      float4 a1 = *(const float4*)&As[kk*128 + mi*8 + 4];
      float4 b0 = *(const float4*)&Bs[kk*68 + ni*4];
      a[0]=a0.x; a[1]=a0.y; a[2]=a0.z; a[3]=a0.w;
      a[4]=a1.x; a[5]=a1.y; a[6]=a1.z; a[7]=a1.w;
      bv[0]=b0.x; bv[1]=b0.y; bv[2]=b0.z; bv[3]=b0.w;
      #pragma unroll
      for (int im = 0; im < 8; ++im)
        #pragma unroll
        for (int in = 0; in < 4; ++in)
          acc[im][in] = fmaf(a[im], bv[in], acc[im][in]);
    }
  }
  float* Y = kh ? YP1 : YP0;
  #pragma unroll
  for (int im = 0; im < 8; ++im) {
    float4 o; o.x = acc[im][0]; o.y = acc[im][1]; o.z = acc[im][2]; o.w = acc[im][3];
    *(float4*)&Y[(size_t)(m0 + mi*8 + im)*320 + n0 + ni*4] = o;
  }
}

// ---------------- k2: per-token postprocess -> K,V,Q,NU,PW, SCL8[0..3]
// Reads Y = YP0 + YP1 (split-K partial sums).
__global__ __launch_bounds__(256) void post_kernel(
    const float* __restrict__ YP0, const float* __restrict__ YP1,
    const float* __restrict__ nm_w1, const float* __restrict__ nm_b1,
    const float* __restrict__ nm_w2, const float* __restrict__ nm_b2,
    const float* __restrict__ ir_b1, const float* __restrict__ ir_w2,
    const float* __restrict__ ir_b2, const float* __restrict__ sap,
    float* __restrict__ K, float* __restrict__ V, float* __restrict__ Q,
    float* __restrict__ NU, float* __restrict__ PW,
    float* __restrict__ SCL8) {
  __shared__ float w1s[128*65];
  __shared__ float w2s[64*129];
  __shared__ float vbuf[4][64];
  __shared__ float h1buf[4][128];
  const int tid = threadIdx.x, wid = tid >> 6, l = tid & 63;
  for (int i = tid; i < 128*64; i += 256) w1s[(i>>6)*65 + (i&63)]  = nm_w1[i];
  for (int i = tid; i < 64*128; i += 256) w2s[(i>>7)*129 + (i&127)] = nm_w2[i];
  __syncthreads();
  const float sa   = *sap;
  const float b1a  = nm_b1[l], b1b = nm_b1[64+l], b2l = nm_b2[l];
  const float irb1 = ir_b1[l], irw2 = ir_w2[l],  irb2 = ir_b2[0];
  for (int r = 0; r < 4; ++r) {
    const int tok = blockIdx.x*16 + r*4 + wid;
    const float* yr0 = YP0 + (size_t)tok*320;
    const float* yr1 = YP1 + (size_t)tok*320;
    float kr = yr0[l]     + yr1[l];
    float vr = yr0[64+l]  + yr1[64+l];
    float qr = yr0[128+l] + yr1[128+l];
    float hr = yr0[192+l] + yr1[192+l];
    float rk = 1.f / fmaxf(sqrtf(wsum(kr*kr)), 1e-12f);
    float rq = 1.f / fmaxf(sqrtf(wsum(qr*qr)), 1e-12f);
    float kn = kr*rk, qn = qr*rq;
    float qk = wsum(kn*qn);
    float g  = gelu_exact(hr + irb1);
    float logit = wsum(g*irw2) + irb2;
    float imp = 1.f/(1.f+expf(-logit));
    float bs  = (imp > 0.5f) ? (1.f - sa) : 0.f;   // (1-slow_alpha)*u_slow
    K[(size_t)tok*64+l] = kn; V[(size_t)tok*64+l] = vr; Q[(size_t)tok*64+l] = qn;
    vbuf[wid][l] = vr;
    __syncthreads();
    float h1a = b1a, h1b = b1b;
    #pragma unroll 8
    for (int c = 0; c < 64; ++c) {
      float vv = vbuf[wid][c];
      h1a = fmaf(w1s[l*65 + c], vv, h1a);
      h1b = fmaf(w1s[(64+l)*65 + c], vv, h1b);
    }
    h1buf[wid][l]    = gelu_exact(h1a);
    h1buf[wid][64+l] = gelu_exact(h1b);
    __syncthreads();
    float nu = b2l;
    #pragma unroll 8
    for (int j = 0; j < 128; ++j) nu = fmaf(w2s[l*129 + j], h1buf[wid][j], nu);
    NU[(size_t)tok*64+l] = nu;
    float p0 = yr0[256] + yr1[256];
    float p1 = yr0[257] + yr1[257];
    float p2 = yr0[258] + yr1[258];
    float mx = fmaxf(p0, fmaxf(p1, p2));
    float e0 = expf(p0-mx), e1 = expf(p1-mx), e2 = expf(p2-mx);
    float inv = 1.f/(e0+e1+e2);
    if (l == 0) {
      PW[(size_t)tok*3]   = e0*inv;
      float4 s; s.x = qk; s.y = bs; s.z = e0*inv; s.w = e1*inv;
      *(float4*)&SCL8[(size_t)tok*8] = s;
    }
    else if (l == 1)   PW[(size_t)tok*3+1] = e1*inv;
    else if (l == 2)   PW[(size_t)tok*3+2] = e2*inv;
    __syncthreads();
  }
}

#define STAGE68(dst, srcp) { _Pragma("unroll")                        \
    for (int it_ = 0; it_ < 4; ++it_) {                               \
      int idx4 = (threadIdx.x + it_*256)*4;                           \
      int r_ = idx4 >> 6; int d_ = idx4 & 63;                         \
      *(float4*)&dst[r_*68+d_] = ld4(&(srcp)[r_*64 + d_]); } }

// ---------------- k2c: per-chunk dot matrices for ALL (b,c) in parallel.
__global__ __launch_bounds__(256) void chunkdots(
    const float* __restrict__ K, const float* __restrict__ Q,
    float* __restrict__ AKK, float* __restrict__ AQK) {
  __shared__ float Kl[64*68], Ql[64*68];
  const int tid = threadIdx.x;
  const size_t base = (size_t)blockIdx.x * 4096;
  STAGE68(Kl, K + base)
  STAGE68(Ql, Q + base)
  __syncthreads();
  const int t0 = (tid >> 4) * 4, j0 = (tid & 15) * 4;
  float akk[4][4], aqk[4][4];
  #pragma unroll
  for (int i = 0; i < 4; ++i)
    #pragma unroll
    for (int j = 0; j < 4; ++j) { akk[i][j] = 0.f; aqk[i][j] = 0.f; }
  for (int d = 0; d < 64; ++d) {
    float kt[4], qt[4], kj[4];
    #pragma unroll
    for (int i = 0; i < 4; ++i) {
      kt[i] = Kl[(t0+i)*68 + d];
      qt[i] = Ql[(t0+i)*68 + d];
      kj[i] = Kl[(j0+i)*68 + d];
    }
    #pragma unroll
    for (int i = 0; i < 4; ++i)
      #pragma unroll
      for (int j = 0; j < 4; ++j) {
        akk[i][j] = fmaf(kt[i], kj[j], akk[i][j]);
        aqk[i][j] = fmaf(qt[i], kj[j], aqk[i][j]);
      }
  }
  #pragma unroll
  for (int i = 0; i < 4; ++i) {
    float4 a; a.x=akk[i][0]; a.y=akk[i][1]; a.z=akk[i][2]; a.w=akk[i][3];
    float4 b; b.x=aqk[i][0]; b.y=aqk[i][1]; b.z=aqk[i][2]; b.w=aqk[i][3];
    *(float4*)&AKK[base + (t0+i)*64 + j0] = a;
    *(float4*)&AQK[base + (t0+i)*64 + j0] = b;
  }
}

// ---------------- k3a: per-chunk triangular solves -> P_f, R_f, P_s, R_s
// (I + M_p) X = RHS. X lives in LDS (R14 fix). Wave g owns one system;
// lane = column. No barriers in the loop.
__global__ __launch_bounds__(256) void pass1_solve(
    const float* __restrict__ K, const float* __restrict__ V,
    const float* __restrict__ SCL8, const float* __restrict__ AKK,
    const float* __restrict__ fap, const float* __restrict__ sap,
    float* __restrict__ Pf, float* __restrict__ Rf,
    float* __restrict__ Ps, float* __restrict__ Rs) {
  __shared__ float Mf[64*68], Ms[64*68];
  __shared__ float Xpf[64*68], Xrf[64*68], Xps[64*68], Xrs[64*68];
  __shared__ float bsv[64];
  __shared__ float fpw[65], spw[65];
  const int tid = threadIdx.x;
  const size_t chunk = blockIdx.x;
  const size_t tok0 = chunk * 64;
  const float fa = *fap, sa = *sap, omfa = 1.f - fa;
  if (tid == 0) {
    float f = 1.f, s = 1.f;
    for (int n = 0; n <= 64; ++n) { fpw[n] = f; spw[n] = s; f *= fa; s *= sa; }
  }
  STAGE68(Xpf, K + tok0*64)        // raw K
  STAGE68(Xrf, V + tok0*64)        // raw V
  STAGE68(Mf, AKK + chunk*4096)    // raw Akk
  if (tid < 64) bsv[tid] = SCL8[(tok0 + tid)*8 + 1];
  __syncthreads();
  // build masked M + all four RHS (in place; each (t,j) owned by one thread)
  {
    const int t = tid >> 2, j0 = (tid & 3) * 16;
    const float bst = bsv[t];
    const float cpf = omfa*fpw[t], cps = bst*spw[t];
    #pragma unroll
    for (int i = 0; i < 16; ++i) {
      int j = j0 + i;
      float a    = Mf [t*68 + j];
      float kraw = Xpf[t*68 + j];
      float vraw = Xrf[t*68 + j];
      bool lt = (j < t);
      int p = lt ? (t-1-j) : 0;
      Ms [t*68 + j] = lt ? bst*spw[p]*a  : 0.f;
      Mf [t*68 + j] = lt ? omfa*fpw[p]*a : 0.f;
      Xps[t*68 + j] = cps * kraw;
      Xpf[t*68 + j] = cpf * kraw;
      Xrs[t*68 + j] = bst * vraw;
      Xrf[t*68 + j] = omfa * vraw;
    }
  }
  __syncthreads();

  const int g  = tid >> 6;     // 0:Pf 1:Rf 2:Ps 3:Rs (wave-uniform)
  const int cc = tid & 63;     // column
  const float* M = (g < 2) ? Mf : Ms;
  float* X = (g == 0) ? Xpf : (g == 1) ? Xrf : (g == 2) ? Xps : Xrs;
  for (int t = 1; t < 64; ++t) {
    float a0 = 0.f, a1 = 0.f, a2 = 0.f, a3 = 0.f;
    int j = 0;
    for (; j + 4 <= t; j += 4) {
      float4 m = *(const float4*)&M[t*68 + j];
      a0 = fmaf(m.x, X[(j+0)*68 + cc], a0);
      a1 = fmaf(m.y, X[(j+1)*68 + cc], a1);
      a2 = fmaf(m.z, X[(j+2)*68 + cc], a2);
      a3 = fmaf(m.w, X[(j+3)*68 + cc], a3);
    }
    for (; j < t; ++j) a0 = fmaf(M[t*68 + j], X[j*68 + cc], a0);
    X[t*68 + cc] -= ((a0 + a1) + (a2 + a3));
  }
  float* dst = (g == 0) ? Pf : (g == 1) ? Rf : (g == 2) ? Ps : Rs;
  const size_t base = chunk*4096 + cc;
  for (int t = 0; t < 64; ++t) dst[base + t*64] = X[t*68 + cc];
}

// ---------------- k3b: G = d^64 I - K^T E P, H = K^T E R (per chunk, path)
__global__ __launch_bounds__(256) void pass1b_gh(
    const float* __restrict__ K,
    const float* __restrict__ Pf, const float* __restrict__ Rf,
    const float* __restrict__ Ps, const float* __restrict__ Rs,
    const float* __restrict__ fap, const float* __restrict__ sap,
    float* __restrict__ Gf, float* __restrict__ Hf,
    float* __restrict__ Gs, float* __restrict__ Hs) {
  __shared__ float Kc[64*68], Pl[64*68], Rl[64*68];
  __shared__ float dpw[65];
  const int tid = threadIdx.x;
  const size_t chunk = blockIdx.x >> 1;
  const int path = blockIdx.x & 1;
  const float d = path ? (*sap) : (*fap);
  if (tid == 0) {
    float p = 1.f;
    for (int n = 0; n <= 64; ++n) { dpw[n] = p; p *= d; }
  }
  const float* Pg = path ? Ps : Pf;
  const float* Rg = path ? Rs : Rf;
  float* Gg = path ? Gs : Gf;
  float* Hg = path ? Hs : Hf;
  STAGE68(Kc, K + chunk*4096)
  STAGE68(Pl, Pg + chunk*4096)
  STAGE68(Rl, Rg + chunk*4096)
  __syncthreads();
  const int kd = tid >> 2, c0 = (tid & 3) * 16;
  float accG[16], accH[16];
  #pragma unroll
  for (int i = 0; i < 16; ++i) { accG[i] = 0.f; accH[i] = 0.f; }
  #pragma unroll 8
  for (int j = 0; j < 64; ++j) {
    const float w = Kc[j*68 + kd] * dpw[63 - j];
    #pragma unroll
    for (int i4 = 0; i4 < 4; ++i4) {
      float4 p = *(const float4*)&Pl[j*68 + c0 + i4*4];
      float4 r = *(const float4*)&Rl[j*68 + c0 + i4*4];
      accG[i4*4+0] = fmaf(w, p.x, accG[i4*4+0]);
      accG[i4*4+1] = fmaf(w, p.y, accG[i4*4+1]);
      accG[i4*4+2] = fmaf(w, p.z, accG[i4*4+2]);
      accG[i4*4+3] = fmaf(w, p.w, accG[i4*4+3]);
      accH[i4*4+0] = fmaf(w, r.x, accH[i4*4+0]);
      accH[i4*4+1] = fmaf(w, r.y, accH[i4*4+1]);
      accH[i4*4+2] = fmaf(w, r.z, accH[i4*4+2]);
      accH[i4*4+3] = fmaf(w, r.w, accH[i4*4+3]);
    }
  }
  const float d64 = dpw[64];
  #pragma unroll
  for (int i4 = 0; i4 < 4; ++i4) {
    float4 go, ho;
    float* gp = (float*)&go; float* hp = (float*)&ho;
    #pragma unroll
    for (int i = 0; i < 4; ++i) {
      int col = c0 + i4*4 + i;
      gp[i] = ((col == kd) ? d64 : 0.f) - accG[i4*4+i];
      hp[i] = accH[i4*4+i];
    }
    *(float4*)&Gg[chunk*4096 + (size_t)kd*64 + c0 + i4*4] = go;
    *(float4*)&Hg[chunk*4096 + (size_t)kd*64 + c0 + i4*4] = ho;
  }
}

// ---------------- k3c: sequential state recurrence F' = G F + H.
// Grid 32 = 8b x 2path x 2vhalf, 256 threads. Stores pre-state to Fst.
__global__ __launch_bounds__(256) void pass2_rec(
    const float* __restrict__ Gf, const float* __restrict__ Hf,
    const float* __restrict__ Gs, const float* __restrict__ Hs,
    float* __restrict__ Fstf, float* __restrict__ Fsts) {
  __shared__ float Fl[64*36], Gl[64*68], Hl[64*36];
  const int tid = threadIdx.x;
  const int b = blockIdx.x >> 2;
  const int path = (blockIdx.x >> 1) & 1;
  const int vh = blockIdx.x & 1;
  const float* Gg = path ? Gs : Gf;
  const float* Hg = path ? Hs : Hf;
  float* Fstg = path ? Fsts : Fstf;
  const int kd = tid >> 2, vq = tid & 3;      // 64 x 4(8v)
  #pragma unroll
  for (int i = 0; i < 8; ++i) Fl[kd*36 + vq*8 + i] = 0.f;
  __syncthreads();
  for (int c = 0; c < 32; ++c) {
    const size_t chunk = (size_t)b*32 + c;
    STAGE68(Gl, Gg + chunk*4096)
    *(float4*)&Hl[kd*36 + vq*8]     = ld4(&Hg[chunk*4096 + kd*64 + vh*32 + vq*8]);
    *(float4*)&Hl[kd*36 + vq*8 + 4] = ld4(&Hg[chunk*4096 + kd*64 + vh*32 + vq*8 + 4]);
    // store pre-state (stable since last barrier)
    *(float4*)&Fstg[chunk*4096 + (size_t)kd*64 + vh*32 + vq*8]     = *(float4*)&Fl[kd*36 + vq*8];
    *(float4*)&Fstg[chunk*4096 + (size_t)kd*64 + vh*32 + vq*8 + 4] = *(float4*)&Fl[kd*36 + vq*8 + 4];
    __syncthreads();
    float acc[8];
    #pragma unroll
    for (int i = 0; i < 8; ++i) acc[i] = Hl[kd*36 + vq*8 + i];
    #pragma unroll 8
    for (int j = 0; j < 64; ++j) {
      const float g = Gl[kd*68 + j];
      float4 f0 = *(const float4*)&Fl[j*36 + vq*8];
      float4 f1 = *(const float4*)&Fl[j*36 + vq*8 + 4];
      acc[0]=fmaf(g,f0.x,acc[0]); acc[1]=fmaf(g,f0.y,acc[1]);
      acc[2]=fmaf(g,f0.z,acc[2]); acc[3]=fmaf(g,f0.w,acc[3]);
      acc[4]=fmaf(g,f1.x,acc[4]); acc[5]=fmaf(g,f1.y,acc[5]);
      acc[6]=fmaf(g,f1.z,acc[6]); acc[7]=fmaf(g,f1.w,acc[7]);
    }
    __syncthreads();
    #pragma unroll
    for (int i = 0; i < 8; ++i) Fl[kd*36 + vq*8 + i] = acc[i];
    __syncthreads();
  }
}

// ---------------- k3d: parallel outputs per chunk (needs Fst states).
// Grid 512 = 256 chunks x 2 vhalf, 256 threads.
__global__ __launch_bounds__(256) void pass3_out(
    const float* __restrict__ Q, const float* __restrict__ V,
    const float* __restrict__ SCL8, const float* __restrict__ AQK,
    const float* __restrict__ Pf, const float* __restrict__ Rf,
    const float* __restrict__ Ps, const float* __restrict__ Rs,
    const float* __restrict__ Fstf, const float* __restrict__ Fsts,
    const float* __restrict__ fap, const float* __restrict__ sap,
    float* __restrict__ OBASE, float* __restrict__ E2) {
  __shared__ float Qcl[64*68], AQKl[64*68], Pfl[64*68], Psl[64*68];
  __shared__ float Vl[64*36], Rfl[64*36], Rsl[64*36];
  __shared__ float F0l[64*36], S0l[64*36], Ufl[64*36], Usl[64*36];
  __shared__ float scal[256];
  __shared__ float fpw[65], spw[65];
  const int tid = threadIdx.x;
  const size_t chunk = blockIdx.x >> 1;
  const int vh = blockIdx.x & 1;
  const size_t tok0 = chunk * 64;
  const float fa = *fap, sa = *sap;
  if (tid == 0) {
    float f = 1.f, s = 1.f;
    for (int n = 0; n <= 64; ++n) { fpw[n] = f; spw[n] = s; f *= fa; s *= sa; }
  }
  STAGE68(Qcl,  Q   + tok0*64)
  STAGE68(AQKl, AQK + chunk*4096)
  STAGE68(Pfl,  Pf  + chunk*4096)
  STAGE68(Psl,  Ps  + chunk*4096)
  {
    const int r = tid >> 2, vq = tid & 3;
    const size_t off = chunk*4096 + (size_t)r*64 + vh*32 + vq*8;
    *(float4*)&Vl [r*36 + vq*8]     = ld4(&V   [tok0*64 + (size_t)r*64 + vh*32 + vq*8]);
    *(float4*)&Vl [r*36 + vq*8 + 4] = ld4(&V   [tok0*64 + (size_t)r*64 + vh*32 + vq*8 + 4]);
    *(float4*)&Rfl[r*36 + vq*8]     = ld4(&Rf  [off]);
    *(float4*)&Rfl[r*36 + vq*8 + 4] = ld4(&Rf  [off + 4]);
    *(float4*)&Rsl[r*36 + vq*8]     = ld4(&Rs  [off]);
    *(float4*)&Rsl[r*36 + vq*8 + 4] = ld4(&Rs  [off + 4]);
    *(float4*)&F0l[r*36 + vq*8]     = ld4(&Fstf[off]);
    *(float4*)&F0l[r*36 + vq*8 + 4] = ld4(&Fstf[off + 4]);
    *(float4*)&S0l[r*36 + vq*8]     = ld4(&Fsts[off]);
    *(float4*)&S0l[r*36 + vq*8 + 4] = ld4(&Fsts[off + 4]);
    scal[tid] = SCL8[(tok0 + r)*8 + vq];
  }
  __syncthreads();
  // phase A: U_f = R_f - P_f F0, U_s = R_s - P_s S0
  {
    const int j = tid >> 2, vq = tid & 3;
    float uf[8], us[8];
    #pragma unroll
    for (int i = 0; i < 8; ++i) { uf[i] = 0.f; us[i] = 0.f; }
    #pragma unroll 8
    for (int kd = 0; kd < 64; ++kd) {
      const float pfv = Pfl[j*68 + kd];
      const float psv = Psl[j*68 + kd];
      float4 f0 = *(const float4*)&F0l[kd*36 + vq*8];
      float4 f1 = *(const float4*)&F0l[kd*36 + vq*8 + 4];
      float4 s0 = *(const float4*)&S0l[kd*36 + vq*8];
      float4 s1 = *(const float4*)&S0l[kd*36 + vq*8 + 4];
      uf[0]=fmaf(pfv,f0.x,uf[0]); uf[1]=fmaf(pfv,f0.y,uf[1]);
      uf[2]=fmaf(pfv,f0.z,uf[2]); uf[3]=fmaf(pfv,f0.w,uf[3]);
      uf[4]=fmaf(pfv,f1.x,uf[4]); uf[5]=fmaf(pfv,f1.y,uf[5]);
      uf[6]=fmaf(pfv,f1.z,uf[6]); uf[7]=fmaf(pfv,f1.w,uf[7]);
      us[0]=fmaf(psv,s0.x,us[0]); us[1]=fmaf(psv,s0.y,us[1]);
      us[2]=fmaf(psv,s0.z,us[2]); us[3]=fmaf(psv,s0.w,us[3]);
      us[4]=fmaf(psv,s1.x,us[4]); us[5]=fmaf(psv,s1.y,us[5]);
      us[6]=fmaf(psv,s1.z,us[6]); us[7]=fmaf(psv,s1.w,us[7]);
    }
    #pragma unroll
    for (int i = 0; i < 8; ++i) {
      Ufl[j*36 + vq*8 + i] = Rfl[j*36 + vq*8 + i] - uf[i];
      Usl[j*36 + vq*8 + i] = Rsl[j*36 + vq*8 + i] - us[i];
    }
  }
  __syncthreads();
  // phase B: per-token outputs
  {
    const int t = tid >> 2, vq = tid & 3;
    float af[8], as_[8];
    #pragma unroll
    for (int i = 0; i < 8; ++i) { af[i] = 0.f; as_[i] = 0.f; }
    #pragma unroll 8
    for (int kd = 0; kd < 64; ++kd) {
      const float q = Qcl[t*68 + kd];
      float4 f0 = *(const float4*)&F0l[kd*36 + vq*8];
      float4 f1 = *(const float4*)&F0l[kd*36 + vq*8 + 4];
      float4 s0 = *(const float4*)&S0l[kd*36 + vq*8];
      float4 s1 = *(const float4*)&S0l[kd*36 + vq*8 + 4];
      af[0]=fmaf(q,f0.x,af[0]); af[1]=fmaf(q,f0.y,af[1]);
      af[2]=fmaf(q,f0.z,af[2]); af[3]=fmaf(q,f0.w,af[3]);
      af[4]=fmaf(q,f1.x,af[4]); af[5]=fmaf(q,f1.y,af[5]);
      af[6]=fmaf(q,f1.z,af[6]); af[7]=fmaf(q,f1.w,af[7]);
      as_[0]=fmaf(q,s0.x,as_[0]); as_[1]=fmaf(q,s0.y,as_[1]);
      as_[2]=fmaf(q,s0.z,as_[2]); as_[3]=fmaf(q,s0.w,as_[3]);
      as_[4]=fmaf(q,s1.x,as_[4]); as_[5]=fmaf(q,s1.y,as_[5]);
      as_[6]=fmaf(q,s1.z,as_[6]); as_[7]=fmaf(q,s1.w,as_[7]);
    }
    float pq[8], pqs[8];
    #pragma unroll
    for (int i = 0; i < 8; ++i) { pq[i] = fpw[t]*af[i]; pqs[i] = spw[t]*as_[i]; }
    for (int j = 0; j < 64; ++j) {
      const float aq = AQKl[t*68 + j];
      const bool lt = (j < t);
      const int p = lt ? (t-1-j) : 0;
      const float wf = lt ? fpw[p]*aq : 0.f;
      const float ws = lt ? spw[p]*aq : 0.f;
      float4 u0 = *(const float4*)&Ufl[j*36 + vq*8];
      float4 u1 = *(const float4*)&Ufl[j*36 + vq*8 + 4];
      float4 w0 = *(const float4*)&Usl[j*36 + vq*8];
      float4 w1 = *(const float4*)&Usl[j*36 + vq*8 + 4];
      pq[0]=fmaf(wf,u0.x,pq[0]); pq[1]=fmaf(wf,u0.y,pq[1]);
      pq[2]=fmaf(wf,u0.z,pq[2]); pq[3]=fmaf(wf,u0.w,pq[3]);
      pq[4]=fmaf(wf,u1.x,pq[4]); pq[5]=fmaf(wf,u1.y,pq[5]);
      pq[6]=fmaf(wf,u1.z,pq[6]); pq[7]=fmaf(wf,u1.w,pq[7]);
      pqs[0]=fmaf(ws,w0.x,pqs[0]); pqs[1]=fmaf(ws,w0.y,pqs[1]);
      pqs[2]=fmaf(ws,w0.z,pqs[2]); pqs[3]=fmaf(ws,w0.w,pqs[3]);
      pqs[4]=fmaf(ws,w1.x,pqs[4]); pqs[5]=fmaf(ws,w1.y,pqs[5]);
      pqs[6]=fmaf(ws,w1.z,pqs[6]); pqs[7]=fmaf(ws,w1.w,pqs[7]);
    }
    const float qk = scal[t*4+0], p0 = scal[t*4+2], p1 = scal[t*4+3];
    float ob[8], ee[8];
    #pragma unroll
    for (int i = 0; i < 8; ++i) {
      const float uft = Ufl[t*36 + vq*8 + i];
      const float ust = Usl[t*36 + vq*8 + i];
      const float qfn = fmaf(fa, pq[i],  qk*uft);
      const float qsn = fmaf(sa, pqs[i], qk*ust);
      ob[i] = fmaf(p0, qfn, p1*qsn);
      const float pd = Vl[t*36 + vq*8 + i] - 0.5f*(pq[i] + pqs[i]);
      ee[i] = pd*pd;
    }
    const size_t o = (tok0 + t)*64 + vh*32 + vq*8;
    *(float4*)&OBASE[o]     = *(float4*)&ob[0];
    *(float4*)&OBASE[o + 4] = *(float4*)&ob[4];
    *(float4*)&E2[o]        = *(float4*)&ee[0];
    *(float4*)&E2[o + 4]    = *(float4*)&ee[4];
  }
}

// ---------------- k4: err reduce -> ns-gate coefficient c = 0.1*u_neu
__global__ __launch_bounds__(256) void err_kernel(
    const float* __restrict__ E, float* __restrict__ CNS) {
  int row = blockIdx.x*4 + (threadIdx.x >> 6);
  int l = threadIdx.x & 63;
  float s = wsum(E[(size_t)row*64 + l]);
  if (l == 0) {
    float z = s / (1.0f + 1e-6f);          // TEMP + 1e-6
    float sg = 1.f/(1.f+expf(-z));
    CNS[row] = (sg > 0.7f) ? 0.1f : 0.f;
  }
}

// ---------------- k5: ns scan + o assembly, software-pipelined
#define BW 16
__device__ __forceinline__ void loadw(int b, int t0, int v,
    const float* __restrict__ CNS, const float* __restrict__ NU,
    const float* __restrict__ OBASE, const float* __restrict__ PW,
    float* c, float* nu, float* ob, float* p2) {
  #pragma unroll
  for (int i = 0; i < BW; ++i) {
    size_t bt = (size_t)b*SS + (t0 + i);
    c[i]  = CNS[bt];
    nu[i] = NU[bt*64 + v];
    ob[i] = OBASE[bt*64 + v];
    p2[i] = PW[bt*3 + 2];
  }
}
__device__ __forceinline__ float procw(int b, int t0, int v, float ns,
    const float* c, const float* nu, const float* ob, const float* p2,
    float* __restrict__ OB) {
  #pragma unroll
  for (int i = 0; i < BW; ++i) {
    float cn = c[i]*nu[i];
    float a  = 1.f - c[i];
    ns = fmaf(a, ns, cn);
    float o = fmaf(p2[i], ns, ob[i]);
    OB[((size_t)b*SS + (t0+i))*64 + v] = o;
  }
  return ns;
}
__global__ __launch_bounds__(64) void nsout_kernel(
    const float* __restrict__ CNS, const float* __restrict__ NU,
    const float* __restrict__ OBASE, const float* __restrict__ PW,
    float* __restrict__ OB) {
  const int b = blockIdx.x, v = threadIdx.x;
  float cA[BW],nA[BW],oA[BW],pA[BW], cB[BW],nB[BW],oB[BW],pB[BW];
  loadw(b, 0, v, CNS, NU, OBASE, PW, cA, nA, oA, pA);
  float ns = 0.f;
  for (int t0 = 0; t0 < SS; t0 += 2*BW) {
    int tB = t0 + BW;
    loadw(b, tB, v, CNS, NU, OBASE, PW, cB, nB, oB, pB);
    ns = procw(b, t0, v, ns, cA, nA, oA, pA, OB);
    int tA2 = t0 + 2*BW; if (tA2 > SS - BW) tA2 = SS - BW;
    loadw(b, tA2, v, CNS, NU, OBASE, PW, cA, nA, oA, pA);
    ns = procw(b, tB, v, ns, cB, nB, oB, pB, OB);
  }
}

// ---------------- k6: fused RMSNorm + out = normed @ Wo^T
__global__ __launch_bounds__(256) void out_gemm(
    const float* __restrict__ OB, const float* __restrict__ Wo,
    const float* __restrict__ normw, float* __restrict__ out) {
  __shared__ float As[64*64];    // [k][m]
  __shared__ float Bs[64*128];   // [k][n]
  const int t  = threadIdx.x;
  const int m0 = blockIdx.y * 64;
  const int n0 = blockIdx.x * 128;
  {
    int r = t >> 2, q4 = t & 3;
    const float* src = OB + (size_t)(m0 + r)*64 + q4*16;
    float4 x0 = ld4(src), x1 = ld4(src+4), x2 = ld4(src+8), x3 = ld4(src+12);
    float ss = x0.x*x0.x+x0.y*x0.y+x0.z*x0.z+x0.w*x0.w
             + x1.x*x1.x+x1.y*x1.y+x1.z*x1.z+x1.w*x1.w
             + x2.x*x2.x+x2.y*x2.y+x2.z*x2.z+x2.w*x2.w
             + x3.x*x3.x+x3.y*x3.y+x3.z*x3.z+x3.w*x3.w;
    ss += __shfl_xor(ss, 1, 64);
    ss += __shfl_xor(ss, 2, 64);
    float rms = rsqrtf(ss * (1.f/64.f) + 1e-6f);
    const float* nw = normw + q4*16;
    float4 w0 = ld4(nw), w1 = ld4(nw+4), w2 = ld4(nw+8), w3 = ld4(nw+12);
    int kbase = q4*16;
    As[(kbase+ 0)*64+r]=x0.x*rms*w0.x; As[(kbase+ 1)*64+r]=x0.y*rms*w0.y;
    As[(kbase+ 2)*64+r]=x0.z*rms*w0.z; As[(kbase+ 3)*64+r]=x0.w*rms*w0.w;
    As[(kbase+ 4)*64+r]=x1.x*rms*w1.x; As[(kbase+ 5)*64+r]=x1.y*rms*w1.y;
    As[(kbase+ 6)*64+r]=x1.z*rms*w1.z; As[(kbase+ 7)*64+r]=x1.w*rms*w1.w;
    As[(kbase+ 8)*64+r]=x2.x*rms*w2.x; As[(kbase+ 9)*64+r]=x2.y*rms*w2.y;
    As[(kbase+10)*64+r]=x2.z*rms*w2.z; As[(kbase+11)*64+r]=x2.w*rms*w2.w;
    As[(kbase+12)*64+r]=x3.x*rms*w3.x; As[(kbase+13)*64+r]=x3.y*rms*w3.y;
    As[(kbase+14)*64+r]=x3.z*rms*w3.z; As[(kbase+15)*64+r]=x3.w*rms*w3.w;
  }
  {
    int rw = t >> 1, half = t & 1;
    const float* src = Wo + (size_t)(n0 + rw)*64 + half*32;
    #pragma unroll
    for (int j = 0; j < 8; ++j) {
      float4 w = ld4(src + j*4);
      int k = half*32 + j*4;
      Bs[(k+0)*128+rw] = w.x; Bs[(k+1)*128+rw] = w.y;
      Bs[(k+2)*128+rw] = w.z; Bs[(k+3)*128+rw] = w.w;
    }
  }
  __syncthreads();
  const int mi = t >> 5, ni = t & 31;
  float acc[8][4];
  #pragma unroll
  for (int i = 0; i < 8; ++i)
    #pragma unroll
    for (int j = 0; j < 4; ++j) acc[i][j] = 0.f;
  #pragma unroll 8
  for (int k = 0; k < 64; ++k) {
    float a[8], bv[4];
    float4 a0 = *(const float4*)&As[k*64 + mi*8];
    float4 a1 = *(const float4*)&As[k*64 + mi*8 + 4];
    float4 b0 = *(const float4*)&Bs[k*128 + ni*4];
    a[0]=a0.x; a[1]=a0.y; a[2]=a0.z; a[3]=a0.w;
    a[4]=a1.x; a[5]=a1.y; a[6]=a1.z; a[7]=a1.w;
    bv[0]=b0.x; bv[1]=b0.y; bv[2]=b0.z; bv[3]=b0.w;
    #pragma unroll
    for (int im = 0; im < 8; ++im)
      #pragma unroll
      for (int in = 0; in < 4; ++in)
        acc[im][in] = fmaf(a[im], bv[in], acc[im][in]);
  }
  #pragma unroll
  for (int im = 0; im < 8; ++im) {
    float4 o; o.x=acc[im][0]; o.y=acc[im][1]; o.z=acc[im][2]; o.w=acc[im][3];
    *(float4*)&out[(size_t)(m0 + mi*8 + im)*1024 + n0 + ni*4] = o;
  }
}

// ---------------- launcher ----------------
extern "C" void kernel_launch(void* const* d_in, const int* in_sizes, int n_in,
                              void* d_out, int out_size, void* d_ws, size_t ws_size,
                              hipStream_t stream) {
  const float* x     = (const float*)d_in[0];
  const float* Wk    = (const float*)d_in[1];
  const float* Wv    = (const float*)d_in[2];
  const float* Wq    = (const float*)d_in[3];
  const float* fap   = (const float*)d_in[4];
  const float* sap   = (const float*)d_in[5];
  const float* nm_w1 = (const float*)d_in[6];
  const float* nm_b1 = (const float*)d_in[7];
  const float* nm_w2 = (const float*)d_in[8];
  const float* nm_b2 = (const float*)d_in[9];
  const float* ir_w1 = (const float*)d_in[10];
  const float* ir_b1 = (const float*)d_in[11];
  const float* ir_w2 = (const float*)d_in[12];
  const float* ir_b2 = (const float*)d_in[13];
  const float* pw    = (const float*)d_in[14];
  const float* Wo    = (const float*)d_in[15];
  const float* normw = (const float*)d_in[16];
  float* out = (float*)d_out;
  float* ws  = (float*)d_ws;

  // workspace layout (floats)
  const size_t oW    = 0;                              // 320*1024
  const size_t oY    = oW + (size_t)320*1024;          // MM*320 (reused below)
  const size_t oOBASE = oY;                            // MM*64
  const size_t oE     = oY + (size_t)1*MM*64;          // MM*64
  const size_t oPfA   = oY + (size_t)2*MM*64;          // AKK -> P_f
  const size_t oAQK   = oY + (size_t)3*MM*64;          // AQK (kept for pass3)
  const size_t oPs    = oY + (size_t)4*MM*64;          // P_s
  const size_t oK    = oY + (size_t)MM*320;
  const size_t oV    = oK + (size_t)MM*64;
  const size_t oQ    = oV + (size_t)MM*64;
  const size_t oNU   = oQ + (size_t)MM*64;
  const size_t oPW   = oNU + (size_t)MM*64;
  const size_t oSCL  = oPW + (size_t)MM*3;
  const size_t oCNS  = oSCL + (size_t)MM*8;
  const size_t oOB   = oCNS + MM;
  const size_t oRf   = oOB  + (size_t)MM*64;
  const size_t oRs   = oRf  + (size_t)MM*64;
  const size_t oGf   = oRs  + (size_t)MM*64;
  const size_t oGs   = oGf  + (size_t)MM*64;
  const size_t oHf   = oGs  + (size_t)MM*64;
  const size_t oHs   = oHf  + (size_t)MM*64;
  const size_t oFstf = oHs  + (size_t)MM*64;
  const size_t oFsts = oFstf + (size_t)MM*64;
  // split-K partial: YP0 = oY (MM*320), YP1 overlays oRf.. (5*MM*64 = MM*320;
  // Rf..Fsts are written later by pass1+, post reads YP1 before that).
  const size_t oYP1 = oRf;

  pack_w<<<1280, 256, 0, stream>>>(Wk, Wv, Wq, ir_w1, pw, ws + oW);
  gemm1<<<dim3(128, 5, 2), 256, 0, stream>>>(x, ws + oW, ws + oY, ws + oYP1);
  post_kernel<<<1024, 256, 0, stream>>>(ws + oY, ws + oYP1,
                                        nm_w1, nm_b1, nm_w2, nm_b2,
                                        ir_b1, ir_w2, ir_b2, sap,
                                        ws + oK, ws + oV, ws + oQ, ws + oNU,
                                        ws + oPW, ws + oSCL);
  chunkdots<<<256, 256, 0, stream>>>(ws + oK, ws + oQ, ws + oPfA, ws + oAQK);
  pass1_solve<<<256, 256, 0, stream>>>(ws + oK, ws + oV, ws + oSCL, ws + oPfA,
                                       fap, sap,
                                       ws + oPfA, ws + oRf, ws + oPs, ws + oRs);
  pass1b_gh<<<512, 256, 0, stream>>>(ws + oK,
                                     ws + oPfA, ws + oRf, ws + oPs, ws + oRs,
                                     fap, sap,
                                     ws + oGf, ws + oHf, ws + oGs, ws + oHs);
  pass2_rec<<<32, 256, 0, stream>>>(ws + oGf, ws + oHf, ws + oGs, ws + oHs,
                                    ws + oFstf, ws + oFsts);
  pass3_out<<<512, 256, 0, stream>>>(ws + oQ, ws + oV, ws + oSCL, ws + oAQK,
                                     ws + oPfA, ws + oRf, ws + oPs, ws + oRs,
                                     ws + oFstf, ws + oFsts, fap, sap,
                                     ws + oOBASE, ws + oE);
  err_kernel<<<4096, 256, 0, stream>>>(ws + oE, ws + oCNS);
  nsout_kernel<<<8, 64, 0, stream>>>(ws + oCNS, ws + oNU, ws + oOBASE,
                                     ws + oPW, ws + oOB);
  out_gemm<<<dim3(8, 256), 256, 0, stream>>>(ws + oOB, Wo, normw, out);
}

// Round 17
// 366.843 us; speedup vs baseline: 3.2215x; 1.3903x over previous
//
#include <hip/hip_runtime.h>
#include <hip/hip_bf16.h>
#include <math.h>

// Problem constants (match reference)
#define BB 8
#define SS 2048
#define DD 1024
#define DS 64
#define MM (BB*SS)   // 16384

typedef __attribute__((ext_vector_type(8))) short short8b;   // 8 bf16 (4 VGPRs)
typedef __attribute__((ext_vector_type(4))) float f32x4;

// ---------------- helpers ----------------

__device__ __forceinline__ float4 ld4(const float* p) { return *(const float4*)p; }

template<int CTRL>
__device__ __forceinline__ float dppadd(float x) {
  int v = __builtin_amdgcn_update_dpp(0, __float_as_int(x), CTRL, 0xf, 0xf, true);
  return x + __int_as_float(v);
}

__device__ __forceinline__ float xor16add(float x) {
#if defined(__has_builtin) && __has_builtin(__builtin_amdgcn_permlane16_swap)
  auto r = __builtin_amdgcn_permlane16_swap(__float_as_uint(x), __float_as_uint(x), false, false);
  return __uint_as_float(r[0]) + __uint_as_float(r[1]);
#else
  return x + __shfl_xor(x, 16, 64);
#endif
}
__device__ __forceinline__ float xor32add(float x) {
#if defined(__has_builtin) && __has_builtin(__builtin_amdgcn_permlane32_swap)
  auto r = __builtin_amdgcn_permlane32_swap(__float_as_uint(x), __float_as_uint(x), false, false);
  return __uint_as_float(r[0]) + __uint_as_float(r[1]);
#else
  return x + __shfl_xor(x, 32, 64);
#endif
}

// full 64-lane butterfly sum; result valid in all lanes
__device__ __forceinline__ float wsum(float x) {
  x = dppadd<0xB1>(x);
  x = dppadd<0x4E>(x);
  x = dppadd<0x141>(x);
  x = dppadd<0x140>(x);
  x = xor16add(x);
  x = xor32add(x);
  return x;
}

__device__ __forceinline__ float gelu_exact(float x) {
  return 0.5f * x * (1.f + erff(x * 0.7071067811865476f));
}

// split fp32 -> (hi, lo) bf16 pairs, packed 2-per-u32 (k ascending = low half)
__device__ __forceinline__ void cvt8(const float* f, uint* hi, uint* lo) {
  #pragma unroll
  for (int i = 0; i < 4; ++i) {
    uint u0 = __float_as_uint(f[2*i]);
    uint u1 = __float_as_uint(f[2*i+1]);
    uint h0 = u0 & 0xFFFF0000u, h1 = u1 & 0xFFFF0000u;
    float l0 = f[2*i]   - __uint_as_float(h0);
    float l1 = f[2*i+1] - __uint_as_float(h1);
    hi[i] = (h0 >> 16) | h1;
    lo[i] = (__float_as_uint(l0) >> 16) | (__float_as_uint(l1) & 0xFFFF0000u);
  }
}

// ---------------- k0: pack weights [Wk;Wv;Wq;ir_w1;pw;0-pad] -> Wcat[320][1024]
__global__ __launch_bounds__(256) void pack_w(
    const float* __restrict__ Wk, const float* __restrict__ Wv,
    const float* __restrict__ Wq, const float* __restrict__ ir_w1,
    const float* __restrict__ pw, float* __restrict__ Wcat) {
  int idx = blockIdx.x * 256 + threadIdx.x;   // 320*1024 total
  int r = idx >> 10, c = idx & 1023;
  float val = 0.f;
  if (r < 64)       val = Wk[r*1024 + c];
  else if (r < 128) val = Wv[(r-64)*1024 + c];
  else if (r < 192) val = Wq[(r-128)*1024 + c];
  else if (r < 256) val = ir_w1[(r-192)*1024 + c];
  else if (r < 259) val = pw[(r-256)*1024 + c];
  Wcat[idx] = val;
}

// ---------------- k1: Y[16384][320] = X @ Wcat^T via bf16 MFMA, hi/lo split.
// Tile 128m x 64n, K-step 64, 4 waves (2m x 2n), per wave 4x2 16x16 tiles.
// LDS rows 128B (64 bf16), T2 XOR swizzle kbyte ^ ((row&7)<<4) on BOTH
// store and read (rule #21). Products hh + hl + lh (lo*lo ~2^-16, dropped).
__global__ __launch_bounds__(256) void gemm1(
    const float* __restrict__ X, const float* __restrict__ Wcat,
    float* __restrict__ Y) {
  __shared__ unsigned short Ah[128*64], Al[128*64];   // 16KB each
  __shared__ unsigned short Bh[64*64],  Bl[64*64];    // 8KB each
  const int t  = threadIdx.x;
  const int m0 = blockIdx.x * 128;
  const int n0 = blockIdx.y * 64;
  const int l  = t & 63, w = t >> 6;
  const int wm = (w >> 1) * 64, wn = (w & 1) * 32;
  const int fr = l & 15;           // frag row-in-tile
  const int fkb = (l >> 4) * 16;   // frag k byte base within 32-k half
  const int mA = t >> 1, khA = (t & 1) * 32;   // A staging: row, k-half
  const int nB = t >> 2, kqB = (t & 3) * 16;   // B staging: row, k-quarter
  f32x4 acc[4][2];
  #pragma unroll
  for (int i = 0; i < 4; ++i)
    #pragma unroll
    for (int j = 0; j < 2; ++j) acc[i][j] = (f32x4){0.f,0.f,0.f,0.f};

  for (int k0 = 0; k0 < 1024; k0 += 64) {
    __syncthreads();
    {   // stage A (128x64 fp32 -> bf16 hi/lo)
      const float* src = X + (size_t)(m0 + mA)*1024 + k0 + khA;
      float f[32];
      #pragma unroll
      for (int j = 0; j < 8; ++j) *(float4*)&f[j*4] = ld4(src + j*4);
      #pragma unroll
      for (int g = 0; g < 4; ++g) {
        uint hi[4], lo[4];
        cvt8(&f[g*8], hi, lo);
        int off = mA*128 + ((khA*2 + g*16) ^ ((mA & 7) << 4));
        *(uint4*)((char*)Ah + off) = make_uint4(hi[0],hi[1],hi[2],hi[3]);
        *(uint4*)((char*)Al + off) = make_uint4(lo[0],lo[1],lo[2],lo[3]);
      }
    }
    {   // stage B (64x64 fp32 -> bf16 hi/lo)
      const float* src = Wcat + (size_t)(n0 + nB)*1024 + k0 + kqB;
      float f[16];
      #pragma unroll
      for (int j = 0; j < 4; ++j) *(float4*)&f[j*4] = ld4(src + j*4);
      #pragma unroll
      for (int g = 0; g < 2; ++g) {
        uint hi[4], lo[4];
        cvt8(&f[g*8], hi, lo);
        int off = nB*128 + ((kqB*2 + g*16) ^ ((nB & 7) << 4));
        *(uint4*)((char*)Bh + off) = make_uint4(hi[0],hi[1],hi[2],hi[3]);
        *(uint4*)((char*)Bl + off) = make_uint4(lo[0],lo[1],lo[2],lo[3]);
      }
    }
    __syncthreads();
    #pragma unroll
    for (int h = 0; h < 2; ++h) {
      const int kb = h*64 + fkb;
      short8b ah[4], al[4], bh[2], bl[2];
      #pragma unroll
      for (int i = 0; i < 4; ++i) {
        int row = wm + i*16 + fr;
        int off = row*128 + (kb ^ ((row & 7) << 4));
        ah[i] = *(const short8b*)((const char*)Ah + off);
        al[i] = *(const short8b*)((const char*)Al + off);
      }
      #pragma unroll
      for (int j = 0; j < 2; ++j) {
        int row = wn + j*16 + fr;
        int off = row*128 + (kb ^ ((row & 7) << 4));
        bh[j] = *(const short8b*)((const char*)Bh + off);
        bl[j] = *(const short8b*)((const char*)Bl + off);
      }
      #pragma unroll
      for (int i = 0; i < 4; ++i)
        #pragma unroll
        for (int j = 0; j < 2; ++j) {
          acc[i][j] = __builtin_amdgcn_mfma_f32_16x16x32_bf16(ah[i], bh[j], acc[i][j], 0, 0, 0);
          acc[i][j] = __builtin_amdgcn_mfma_f32_16x16x32_bf16(ah[i], bl[j], acc[i][j], 0, 0, 0);
          acc[i][j] = __builtin_amdgcn_mfma_f32_16x16x32_bf16(al[i], bh[j], acc[i][j], 0, 0, 0);
        }
    }
  }
  // epilogue: C/D layout col=lane&15, row=(lane>>4)*4+reg
  #pragma unroll
  for (int i = 0; i < 4; ++i)
    #pragma unroll
    for (int j = 0; j < 2; ++j)
      #pragma unroll
      for (int r = 0; r < 4; ++r) {
        int row = m0 + wm + i*16 + (l >> 4)*4 + r;
        int col = n0 + wn + j*16 + (l & 15);
        Y[(size_t)row*320 + col] = acc[i][j][r];
      }
}

// ---------------- k2: per-token postprocess -> K,V,Q,NU,PW, SCL8[0..3]
__global__ __launch_bounds__(256) void post_kernel(
    const float* __restrict__ Y,
    const float* __restrict__ nm_w1, const float* __restrict__ nm_b1,
    const float* __restrict__ nm_w2, const float* __restrict__ nm_b2,
    const float* __restrict__ ir_b1, const float* __restrict__ ir_w2,
    const float* __restrict__ ir_b2, const float* __restrict__ sap,
    float* __restrict__ K, float* __restrict__ V, float* __restrict__ Q,
    float* __restrict__ NU, float* __restrict__ PW,
    float* __restrict__ SCL8) {
  __shared__ float w1s[128*65];
  __shared__ float w2s[64*129];
  __shared__ float vbuf[4][64];
  __shared__ float h1buf[4][128];
  const int tid = threadIdx.x, wid = tid >> 6, l = tid & 63;
  for (int i = tid; i < 128*64; i += 256) w1s[(i>>6)*65 + (i&63)]  = nm_w1[i];
  for (int i = tid; i < 64*128; i += 256) w2s[(i>>7)*129 + (i&127)] = nm_w2[i];
  __syncthreads();
  const float sa   = *sap;
  const float b1a  = nm_b1[l], b1b = nm_b1[64+l], b2l = nm_b2[l];
  const float irb1 = ir_b1[l], irw2 = ir_w2[l],  irb2 = ir_b2[0];
  for (int r = 0; r < 4; ++r) {
    const int tok = blockIdx.x*16 + r*4 + wid;
    const float* yr = Y + (size_t)tok*320;
    float kr = yr[l], vr = yr[64+l], qr = yr[128+l], hr = yr[192+l];
    float rk = 1.f / fmaxf(sqrtf(wsum(kr*kr)), 1e-12f);
    float rq = 1.f / fmaxf(sqrtf(wsum(qr*qr)), 1e-12f);
    float kn = kr*rk, qn = qr*rq;
    float qk = wsum(kn*qn);
    float g  = gelu_exact(hr + irb1);
    float logit = wsum(g*irw2) + irb2;
    float imp = 1.f/(1.f+expf(-logit));
    float bs  = (imp > 0.5f) ? (1.f - sa) : 0.f;   // (1-slow_alpha)*u_slow
    K[(size_t)tok*64+l] = kn; V[(size_t)tok*64+l] = vr; Q[(size_t)tok*64+l] = qn;
    vbuf[wid][l] = vr;
    __syncthreads();
    float h1a = b1a, h1b = b1b;
    #pragma unroll 8
    for (int c = 0; c < 64; ++c) {
      float vv = vbuf[wid][c];
      h1a = fmaf(w1s[l*65 + c], vv, h1a);
      h1b = fmaf(w1s[(64+l)*65 + c], vv, h1b);
    }
    h1buf[wid][l]    = gelu_exact(h1a);
    h1buf[wid][64+l] = gelu_exact(h1b);
    __syncthreads();
    float nu = b2l;
    #pragma unroll 8
    for (int j = 0; j < 128; ++j) nu = fmaf(w2s[l*129 + j], h1buf[wid][j], nu);
    NU[(size_t)tok*64+l] = nu;
    float p0 = yr[256], p1 = yr[257], p2 = yr[258];
    float mx = fmaxf(p0, fmaxf(p1, p2));
    float e0 = expf(p0-mx), e1 = expf(p1-mx), e2 = expf(p2-mx);
    float inv = 1.f/(e0+e1+e2);
    if (l == 0) {
      PW[(size_t)tok*3]   = e0*inv;
      float4 s; s.x = qk; s.y = bs; s.z = e0*inv; s.w = e1*inv;
      *(float4*)&SCL8[(size_t)tok*8] = s;
    }
    else if (l == 1)   PW[(size_t)tok*3+1] = e1*inv;
    else if (l == 2)   PW[(size_t)tok*3+2] = e2*inv;
    __syncthreads();
  }
}

#define STAGE68(dst, srcp) { _Pragma("unroll")                        \
    for (int it_ = 0; it_ < 4; ++it_) {                               \
      int idx4 = (threadIdx.x + it_*256)*4;                           \
      int r_ = idx4 >> 6; int d_ = idx4 & 63;                         \
      *(float4*)&dst[r_*68+d_] = ld4(&(srcp)[r_*64 + d_]); } }

// ---------------- k2c: per-chunk dot matrices for ALL (b,c) in parallel.
__global__ __launch_bounds__(256) void chunkdots(
    const float* __restrict__ K, const float* __restrict__ Q,
    float* __restrict__ AKK, float* __restrict__ AQK) {
  __shared__ float Kl[64*68], Ql[64*68];
  const int tid = threadIdx.x;
  const size_t base = (size_t)blockIdx.x * 4096;
  STAGE68(Kl, K + base)
  STAGE68(Ql, Q + base)
  __syncthreads();
  const int t0 = (tid >> 4) * 4, j0 = (tid & 15) * 4;
  float akk[4][4], aqk[4][4];
  #pragma unroll
  for (int i = 0; i < 4; ++i)
    #pragma unroll
    for (int j = 0; j < 4; ++j) { akk[i][j] = 0.f; aqk[i][j] = 0.f; }
  for (int d = 0; d < 64; ++d) {
    float kt[4], qt[4], kj[4];
    #pragma unroll
    for (int i = 0; i < 4; ++i) {
      kt[i] = Kl[(t0+i)*68 + d];
      qt[i] = Ql[(t0+i)*68 + d];
      kj[i] = Kl[(j0+i)*68 + d];
    }
    #pragma unroll
    for (int i = 0; i < 4; ++i)
      #pragma unroll
      for (int j = 0; j < 4; ++j) {
        akk[i][j] = fmaf(kt[i], kj[j], akk[i][j]);
        aqk[i][j] = fmaf(qt[i], kj[j], aqk[i][j]);
      }
  }
  #pragma unroll
  for (int i = 0; i < 4; ++i) {
    float4 a; a.x=akk[i][0]; a.y=akk[i][1]; a.z=akk[i][2]; a.w=akk[i][3];
    float4 b; b.x=aqk[i][0]; b.y=aqk[i][1]; b.z=aqk[i][2]; b.w=aqk[i][3];
    *(float4*)&AKK[base + (t0+i)*64 + j0] = a;
    *(float4*)&AQK[base + (t0+i)*64 + j0] = b;
  }
}

// ---------------- k3a: per-chunk triangular solves -> P_f, R_f, P_s, R_s
__global__ __launch_bounds__(256) void pass1_solve(
    const float* __restrict__ K, const float* __restrict__ V,
    const float* __restrict__ SCL8, const float* __restrict__ AKK,
    const float* __restrict__ fap, const float* __restrict__ sap,
    float* __restrict__ Pf, float* __restrict__ Rf,
    float* __restrict__ Ps, float* __restrict__ Rs) {
  __shared__ float Mf[64*68], Ms[64*68];
  __shared__ float Xpf[64*68], Xrf[64*68], Xps[64*68], Xrs[64*68];
  __shared__ float bsv[64];
  __shared__ float fpw[65], spw[65];
  const int tid = threadIdx.x;
  const size_t chunk = blockIdx.x;
  const size_t tok0 = chunk * 64;
  const float fa = *fap, sa = *sap, omfa = 1.f - fa;
  if (tid == 0) {
    float f = 1.f, s = 1.f;
    for (int n = 0; n <= 64; ++n) { fpw[n] = f; spw[n] = s; f *= fa; s *= sa; }
  }
  STAGE68(Xpf, K + tok0*64)        // raw K
  STAGE68(Xrf, V + tok0*64)        // raw V
  STAGE68(Mf, AKK + chunk*4096)    // raw Akk
  if (tid < 64) bsv[tid] = SCL8[(tok0 + tid)*8 + 1];
  __syncthreads();
  {
    const int t = tid >> 2, j0 = (tid & 3) * 16;
    const float bst = bsv[t];
    const float cpf = omfa*fpw[t], cps = bst*spw[t];
    #pragma unroll
    for (int i = 0; i < 16; ++i) {
      int j = j0 + i;
      float a    = Mf [t*68 + j];
      float kraw = Xpf[t*68 + j];
      float vraw = Xrf[t*68 + j];
      bool lt = (j < t);
      int p = lt ? (t-1-j) : 0;
      Ms [t*68 + j] = lt ? bst*spw[p]*a  : 0.f;
      Mf [t*68 + j] = lt ? omfa*fpw[p]*a : 0.f;
      Xps[t*68 + j] = cps * kraw;
      Xpf[t*68 + j] = cpf * kraw;
      Xrs[t*68 + j] = bst * vraw;
      Xrf[t*68 + j] = omfa * vraw;
    }
  }
  __syncthreads();

  const int g  = tid >> 6;     // 0:Pf 1:Rf 2:Ps 3:Rs (wave-uniform)
  const int cc = tid & 63;     // column
  const float* M = (g < 2) ? Mf : Ms;
  float* X = (g == 0) ? Xpf : (g == 1) ? Xrf : (g == 2) ? Xps : Xrs;
  for (int t = 1; t < 64; ++t) {
    float a0 = 0.f, a1 = 0.f, a2 = 0.f, a3 = 0.f;
    int j = 0;
    for (; j + 4 <= t; j += 4) {
      float4 m = *(const float4*)&M[t*68 + j];
      a0 = fmaf(m.x, X[(j+0)*68 + cc], a0);
      a1 = fmaf(m.y, X[(j+1)*68 + cc], a1);
      a2 = fmaf(m.z, X[(j+2)*68 + cc], a2);
      a3 = fmaf(m.w, X[(j+3)*68 + cc], a3);
    }
    for (; j < t; ++j) a0 = fmaf(M[t*68 + j], X[j*68 + cc], a0);
    X[t*68 + cc] -= ((a0 + a1) + (a2 + a3));
  }
  float* dst = (g == 0) ? Pf : (g == 1) ? Rf : (g == 2) ? Ps : Rs;
  const size_t base = chunk*4096 + cc;
  for (int t = 0; t < 64; ++t) dst[base + t*64] = X[t*68 + cc];
}

// ---------------- k3b: G = d^64 I - K^T E P, H = K^T E R (per chunk, path)
__global__ __launch_bounds__(256) void pass1b_gh(
    const float* __restrict__ K,
    const float* __restrict__ Pf, const float* __restrict__ Rf,
    const float* __restrict__ Ps, const float* __restrict__ Rs,
    const float* __restrict__ fap, const float* __restrict__ sap,
    float* __restrict__ Gf, float* __restrict__ Hf,
    float* __restrict__ Gs, float* __restrict__ Hs) {
  __shared__ float Kc[64*68], Pl[64*68], Rl[64*68];
  __shared__ float dpw[65];
  const int tid = threadIdx.x;
  const size_t chunk = blockIdx.x >> 1;
  const int path = blockIdx.x & 1;
  const float d = path ? (*sap) : (*fap);
  if (tid == 0) {
    float p = 1.f;
    for (int n = 0; n <= 64; ++n) { dpw[n] = p; p *= d; }
  }
  const float* Pg = path ? Ps : Pf;
  const float* Rg = path ? Rs : Rf;
  float* Gg = path ? Gs : Gf;
  float* Hg = path ? Hs : Hf;
  STAGE68(Kc, K + chunk*4096)
  STAGE68(Pl, Pg + chunk*4096)
  STAGE68(Rl, Rg + chunk*4096)
  __syncthreads();
  const int kd = tid >> 2, c0 = (tid & 3) * 16;
  float accG[16], accH[16];
  #pragma unroll
  for (int i = 0; i < 16; ++i) { accG[i] = 0.f; accH[i] = 0.f; }
  #pragma unroll 8
  for (int j = 0; j < 64; ++j) {
    const float w = Kc[j*68 + kd] * dpw[63 - j];
    #pragma unroll
    for (int i4 = 0; i4 < 4; ++i4) {
      float4 p = *(const float4*)&Pl[j*68 + c0 + i4*4];
      float4 r = *(const float4*)&Rl[j*68 + c0 + i4*4];
      accG[i4*4+0] = fmaf(w, p.x, accG[i4*4+0]);
      accG[i4*4+1] = fmaf(w, p.y, accG[i4*4+1]);
      accG[i4*4+2] = fmaf(w, p.z, accG[i4*4+2]);
      accG[i4*4+3] = fmaf(w, p.w, accG[i4*4+3]);
      accH[i4*4+0] = fmaf(w, r.x, accH[i4*4+0]);
      accH[i4*4+1] = fmaf(w, r.y, accH[i4*4+1]);
      accH[i4*4+2] = fmaf(w, r.z, accH[i4*4+2]);
      accH[i4*4+3] = fmaf(w, r.w, accH[i4*4+3]);
    }
  }
  const float d64 = dpw[64];
  #pragma unroll
  for (int i4 = 0; i4 < 4; ++i4) {
    float4 go, ho;
    float* gp = (float*)&go; float* hp = (float*)&ho;
    #pragma unroll
    for (int i = 0; i < 4; ++i) {
      int col = c0 + i4*4 + i;
      gp[i] = ((col == kd) ? d64 : 0.f) - accG[i4*4+i];
      hp[i] = accH[i4*4+i];
    }
    *(float4*)&Gg[chunk*4096 + (size_t)kd*64 + c0 + i4*4] = go;
    *(float4*)&Hg[chunk*4096 + (size_t)kd*64 + c0 + i4*4] = ho;
  }
}

// ---------------- k3c: sequential state recurrence F' = G F + H.
__global__ __launch_bounds__(256) void pass2_rec(
    const float* __restrict__ Gf, const float* __restrict__ Hf,
    const float* __restrict__ Gs, const float* __restrict__ Hs,
    float* __restrict__ Fstf, float* __restrict__ Fsts) {
  __shared__ float Fl[64*36], Gl[64*68], Hl[64*36];
  const int tid = threadIdx.x;
  const int b = blockIdx.x >> 2;
  const int path = (blockIdx.x >> 1) & 1;
  const int vh = blockIdx.x & 1;
  const float* Gg = path ? Gs : Gf;
  const float* Hg = path ? Hs : Hf;
  float* Fstg = path ? Fsts : Fstf;
  const int kd = tid >> 2, vq = tid & 3;      // 64 x 4(8v)
  #pragma unroll
  for (int i = 0; i < 8; ++i) Fl[kd*36 + vq*8 + i] = 0.f;
  __syncthreads();
  for (int c = 0; c < 32; ++c) {
    const size_t chunk = (size_t)b*32 + c;
    STAGE68(Gl, Gg + chunk*4096)
    *(float4*)&Hl[kd*36 + vq*8]     = ld4(&Hg[chunk*4096 + kd*64 + vh*32 + vq*8]);
    *(float4*)&Hl[kd*36 + vq*8 + 4] = ld4(&Hg[chunk*4096 + kd*64 + vh*32 + vq*8 + 4]);
    *(float4*)&Fstg[chunk*4096 + (size_t)kd*64 + vh*32 + vq*8]     = *(float4*)&Fl[kd*36 + vq*8];
    *(float4*)&Fstg[chunk*4096 + (size_t)kd*64 + vh*32 + vq*8 + 4] = *(float4*)&Fl[kd*36 + vq*8 + 4];
    __syncthreads();
    float acc[8];
    #pragma unroll
    for (int i = 0; i < 8; ++i) acc[i] = Hl[kd*36 + vq*8 + i];
    #pragma unroll 8
    for (int j = 0; j < 64; ++j) {
      const float g = Gl[kd*68 + j];
      float4 f0 = *(const float4*)&Fl[j*36 + vq*8];
      float4 f1 = *(const float4*)&Fl[j*36 + vq*8 + 4];
      acc[0]=fmaf(g,f0.x,acc[0]); acc[1]=fmaf(g,f0.y,acc[1]);
      acc[2]=fmaf(g,f0.z,acc[2]); acc[3]=fmaf(g,f0.w,acc[3]);
      acc[4]=fmaf(g,f1.x,acc[4]); acc[5]=fmaf(g,f1.y,acc[5]);
      acc[6]=fmaf(g,f1.z,acc[6]); acc[7]=fmaf(g,f1.w,acc[7]);
    }
    __syncthreads();
    #pragma unroll
    for (int i = 0; i < 8; ++i) Fl[kd*36 + vq*8 + i] = acc[i];
    __syncthreads();
  }
}

// ---------------- k3d: parallel outputs per chunk (needs Fst states).
__global__ __launch_bounds__(256) void pass3_out(
    const float* __restrict__ Q, const float* __restrict__ V,
    const float* __restrict__ SCL8, const float* __restrict__ AQK,
    const float* __restrict__ Pf, const float* __restrict__ Rf,
    const float* __restrict__ Ps, const float* __restrict__ Rs,
    const float* __restrict__ Fstf, const float* __restrict__ Fsts,
    const float* __restrict__ fap, const float* __restrict__ sap,
    float* __restrict__ OBASE, float* __restrict__ E2) {
  __shared__ float Qcl[64*68], AQKl[64*68], Pfl[64*68], Psl[64*68];
  __shared__ float Vl[64*36], Rfl[64*36], Rsl[64*36];
  __shared__ float F0l[64*36], S0l[64*36], Ufl[64*36], Usl[64*36];
  __shared__ float scal[256];
  __shared__ float fpw[65], spw[65];
  const int tid = threadIdx.x;
  const size_t chunk = blockIdx.x >> 1;
  const int vh = blockIdx.x & 1;
  const size_t tok0 = chunk * 64;
  const float fa = *fap, sa = *sap;
  if (tid == 0) {
    float f = 1.f, s = 1.f;
    for (int n = 0; n <= 64; ++n) { fpw[n] = f; spw[n] = s; f *= fa; s *= sa; }
  }
  STAGE68(Qcl,  Q   + tok0*64)
  STAGE68(AQKl, AQK + chunk*4096)
  STAGE68(Pfl,  Pf  + chunk*4096)
  STAGE68(Psl,  Ps  + chunk*4096)
  {
    const int r = tid >> 2, vq = tid & 3;
    const size_t off = chunk*4096 + (size_t)r*64 + vh*32 + vq*8;
    *(float4*)&Vl [r*36 + vq*8]     = ld4(&V   [tok0*64 + (size_t)r*64 + vh*32 + vq*8]);
    *(float4*)&Vl [r*36 + vq*8 + 4] = ld4(&V   [tok0*64 + (size_t)r*64 + vh*32 + vq*8 + 4]);
    *(float4*)&Rfl[r*36 + vq*8]     = ld4(&Rf  [off]);
    *(float4*)&Rfl[r*36 + vq*8 + 4] = ld4(&Rf  [off + 4]);
    *(float4*)&Rsl[r*36 + vq*8]     = ld4(&Rs  [off]);
    *(float4*)&Rsl[r*36 + vq*8 + 4] = ld4(&Rs  [off + 4]);
    *(float4*)&F0l[r*36 + vq*8]     = ld4(&Fstf[off]);
    *(float4*)&F0l[r*36 + vq*8 + 4] = ld4(&Fstf[off + 4]);
    *(float4*)&S0l[r*36 + vq*8]     = ld4(&Fsts[off]);
    *(float4*)&S0l[r*36 + vq*8 + 4] = ld4(&Fsts[off + 4]);
    scal[tid] = SCL8[(tok0 + r)*8 + vq];
  }
  __syncthreads();
  {
    const int j = tid >> 2, vq = tid & 3;
    float uf[8], us[8];
    #pragma unroll
    for (int i = 0; i < 8; ++i) { uf[i] = 0.f; us[i] = 0.f; }
    #pragma unroll 8
    for (int kd = 0; kd < 64; ++kd) {
      const float pfv = Pfl[j*68 + kd];
      const float psv = Psl[j*68 + kd];
      float4 f0 = *(const float4*)&F0l[kd*36 + vq*8];
      float4 f1 = *(const float4*)&F0l[kd*36 + vq*8 + 4];
      float4 s0 = *(const float4*)&S0l[kd*36 + vq*8];
      float4 s1 = *(const float4*)&S0l[kd*36 + vq*8 + 4];
      uf[0]=fmaf(pfv,f0.x,uf[0]); uf[1]=fmaf(pfv,f0.y,uf[1]);
      uf[2]=fmaf(pfv,f0.z,uf[2]); uf[3]=fmaf(pfv,f0.w,uf[3]);
      uf[4]=fmaf(pfv,f1.x,uf[4]); uf[5]=fmaf(pfv,f1.y,uf[5]);
      uf[6]=fmaf(pfv,f1.z,uf[6]); uf[7]=fmaf(pfv,f1.w,uf[7]);
      us[0]=fmaf(psv,s0.x,us[0]); us[1]=fmaf(psv,s0.y,us[1]);
      us[2]=fmaf(psv,s0.z,us[2]); us[3]=fmaf(psv,s0.w,us[3]);
      us[4]=fmaf(psv,s1.x,us[4]); us[5]=fmaf(psv,s1.y,us[5]);
      us[6]=fmaf(psv,s1.z,us[6]); us[7]=fmaf(psv,s1.w,us[7]);
    }
    #pragma unroll
    for (int i = 0; i < 8; ++i) {
      Ufl[j*36 + vq*8 + i] = Rfl[j*36 + vq*8 + i] - uf[i];
      Usl[j*36 + vq*8 + i] = Rsl[j*36 + vq*8 + i] - us[i];
    }
  }
  __syncthreads();
  {
    const int t = tid >> 2, vq = tid & 3;
    float af[8], as_[8];
    #pragma unroll
    for (int i = 0; i < 8; ++i) { af[i] = 0.f; as_[i] = 0.f; }
    #pragma unroll 8
    for (int kd = 0; kd < 64; ++kd) {
      const float q = Qcl[t*68 + kd];
      float4 f0 = *(const float4*)&F0l[kd*36 + vq*8];
      float4 f1 = *(const float4*)&F0l[kd*36 + vq*8 + 4];
      float4 s0 = *(const float4*)&S0l[kd*36 + vq*8];
      float4 s1 = *(const float4*)&S0l[kd*36 + vq*8 + 4];
      af[0]=fmaf(q,f0.x,af[0]); af[1]=fmaf(q,f0.y,af[1]);
      af[2]=fmaf(q,f0.z,af[2]); af[3]=fmaf(q,f0.w,af[3]);
      af[4]=fmaf(q,f1.x,af[4]); af[5]=fmaf(q,f1.y,af[5]);
      af[6]=fmaf(q,f1.z,af[6]); af[7]=fmaf(q,f1.w,af[7]);
      as_[0]=fmaf(q,s0.x,as_[0]); as_[1]=fmaf(q,s0.y,as_[1]);
      as_[2]=fmaf(q,s0.z,as_[2]); as_[3]=fmaf(q,s0.w,as_[3]);
      as_[4]=fmaf(q,s1.x,as_[4]); as_[5]=fmaf(q,s1.y,as_[5]);
      as_[6]=fmaf(q,s1.z,as_[6]); as_[7]=fmaf(q,s1.w,as_[7]);
    }
    float pq[8], pqs[8];
    #pragma unroll
    for (int i = 0; i < 8; ++i) { pq[i] = fpw[t]*af[i]; pqs[i] = spw[t]*as_[i]; }
    for (int j = 0; j < 64; ++j) {
      const float aq = AQKl[t*68 + j];
      const bool lt = (j < t);
      const int p = lt ? (t-1-j) : 0;
      const float wf = lt ? fpw[p]*aq : 0.f;
      const float ws = lt ? spw[p]*aq : 0.f;
      float4 u0 = *(const float4*)&Ufl[j*36 + vq*8];
      float4 u1 = *(const float4*)&Ufl[j*36 + vq*8 + 4];
      float4 w0 = *(const float4*)&Usl[j*36 + vq*8];
      float4 w1 = *(const float4*)&Usl[j*36 + vq*8 + 4];
      pq[0]=fmaf(wf,u0.x,pq[0]); pq[1]=fmaf(wf,u0.y,pq[1]);
      pq[2]=fmaf(wf,u0.z,pq[2]); pq[3]=fmaf(wf,u0.w,pq[3]);
      pq[4]=fmaf(wf,u1.x,pq[4]); pq[5]=fmaf(wf,u1.y,pq[5]);
      pq[6]=fmaf(wf,u1.z,pq[6]); pq[7]=fmaf(wf,u1.w,pq[7]);
      pqs[0]=fmaf(ws,w0.x,pqs[0]); pqs[1]=fmaf(ws,w0.y,pqs[1]);
      pqs[2]=fmaf(ws,w0.z,pqs[2]); pqs[3]=fmaf(ws,w0.w,pqs[3]);
      pqs[4]=fmaf(ws,w1.x,pqs[4]); pqs[5]=fmaf(ws,w1.y,pqs[5]);
      pqs[6]=fmaf(ws,w1.z,pqs[6]); pqs[7]=fmaf(ws,w1.w,pqs[7]);
    }
    const float qk = scal[t*4+0], p0 = scal[t*4+2], p1 = scal[t*4+3];
    float ob[8], ee[8];
    #pragma unroll
    for (int i = 0; i < 8; ++i) {
      const float uft = Ufl[t*36 + vq*8 + i];
      const float ust = Usl[t*36 + vq*8 + i];
      const float qfn = fmaf(fa, pq[i],  qk*uft);
      const float qsn = fmaf(sa, pqs[i], qk*ust);
      ob[i] = fmaf(p0, qfn, p1*qsn);
      const float pd = Vl[t*36 + vq*8 + i] - 0.5f*(pq[i] + pqs[i]);
      ee[i] = pd*pd;
    }
    const size_t o = (tok0 + t)*64 + vh*32 + vq*8;
    *(float4*)&OBASE[o]     = *(float4*)&ob[0];
    *(float4*)&OBASE[o + 4] = *(float4*)&ob[4];
    *(float4*)&E2[o]        = *(float4*)&ee[0];
    *(float4*)&E2[o + 4]    = *(float4*)&ee[4];
  }
}

// ---------------- k4: err reduce -> ns-gate coefficient c = 0.1*u_neu
__global__ __launch_bounds__(256) void err_kernel(
    const float* __restrict__ E, float* __restrict__ CNS) {
  int row = blockIdx.x*4 + (threadIdx.x >> 6);
  int l = threadIdx.x & 63;
  float s = wsum(E[(size_t)row*64 + l]);
  if (l == 0) {
    float z = s / (1.0f + 1e-6f);          // TEMP + 1e-6
    float sg = 1.f/(1.f+expf(-z));
    CNS[row] = (sg > 0.7f) ? 0.1f : 0.f;
  }
}

// ---------------- k5a: per-segment summaries A = prod(1-c), Bv = seg-recur(0)
__global__ __launch_bounds__(64) void nsseg(
    const float* __restrict__ CNS, const float* __restrict__ NU,
    float* __restrict__ ASEG, float* __restrict__ BSEG) {
  const int bseg = blockIdx.x;            // b*32 + seg
  const int v = threadIdx.x;
  const size_t t0 = (size_t)(bseg) * 64;  // token index (b*2048 + seg*64)
  float a = 1.f, bv = 0.f;
  for (int i = 0; i < 64; ++i) {
    float c  = CNS[t0 + i];
    float nu = NU[(t0 + i)*64 + v];
    bv = fmaf(1.f - c, bv, c*nu);
    a *= (1.f - c);
  }
  BSEG[(size_t)bseg*64 + v] = bv;
  if (v == 0) ASEG[bseg] = a;
}

// ---------------- k5b: serial prefix over 32 segments per batch (tiny)
__global__ __launch_bounds__(64) void nspre(
    const float* __restrict__ ASEG, const float* __restrict__ BSEG,
    float* __restrict__ NSST) {
  const int b = blockIdx.x, v = threadIdx.x;
  float ns = 0.f;
  for (int s = 0; s < 32; ++s) {
    const int bs = b*32 + s;
    NSST[(size_t)bs*64 + v] = ns;
    ns = fmaf(ASEG[bs], ns, BSEG[(size_t)bs*64 + v]);
  }
}

// ---------------- k5c: parallel replay + output
__global__ __launch_bounds__(64) void nsout2(
    const float* __restrict__ CNS, const float* __restrict__ NU,
    const float* __restrict__ OBASE, const float* __restrict__ PW,
    const float* __restrict__ NSST, float* __restrict__ OB) {
  const int bseg = blockIdx.x;
  const int v = threadIdx.x;
  const size_t t0 = (size_t)bseg * 64;
  float ns = NSST[(size_t)bseg*64 + v];
  for (int i = 0; i < 64; ++i) {
    float c  = CNS[t0 + i];
    float nu = NU[(t0 + i)*64 + v];
    ns = fmaf(1.f - c, ns, c*nu);
    OB[(t0 + i)*64 + v] = fmaf(PW[(t0 + i)*3 + 2], ns, OBASE[(t0 + i)*64 + v]);
  }
}

// ---------------- k6: fused RMSNorm + out = normed @ Wo^T
__global__ __launch_bounds__(256) void out_gemm(
    const float* __restrict__ OB, const float* __restrict__ Wo,
    const float* __restrict__ normw, float* __restrict__ out) {
  __shared__ float As[64*64];    // [k][m]
  __shared__ float Bs[64*128];   // [k][n]
  const int t  = threadIdx.x;
  const int m0 = blockIdx.y * 64;
  const int n0 = blockIdx.x * 128;
  {
    int r = t >> 2, q4 = t & 3;
    const float* src = OB + (size_t)(m0 + r)*64 + q4*16;
    float4 x0 = ld4(src), x1 = ld4(src+4), x2 = ld4(src+8), x3 = ld4(src+12);
    float ss = x0.x*x0.x+x0.y*x0.y+x0.z*x0.z+x0.w*x0.w
             + x1.x*x1.x+x1.y*x1.y+x1.z*x1.z+x1.w*x1.w
             + x2.x*x2.x+x2.y*x2.y+x2.z*x2.z+x2.w*x2.w
             + x3.x*x3.x+x3.y*x3.y+x3.z*x3.z+x3.w*x3.w;
    ss += __shfl_xor(ss, 1, 64);
    ss += __shfl_xor(ss, 2, 64);
    float rms = rsqrtf(ss * (1.f/64.f) + 1e-6f);
    const float* nw = normw + q4*16;
    float4 w0 = ld4(nw), w1 = ld4(nw+4), w2 = ld4(nw+8), w3 = ld4(nw+12);
    int kbase = q4*16;
    As[(kbase+ 0)*64+r]=x0.x*rms*w0.x; As[(kbase+ 1)*64+r]=x0.y*rms*w0.y;
    As[(kbase+ 2)*64+r]=x0.z*rms*w0.z; As[(kbase+ 3)*64+r]=x0.w*rms*w0.w;
    As[(kbase+ 4)*64+r]=x1.x*rms*w1.x; As[(kbase+ 5)*64+r]=x1.y*rms*w1.y;
    As[(kbase+ 6)*64+r]=x1.z*rms*w1.z; As[(kbase+ 7)*64+r]=x1.w*rms*w1.w;
    As[(kbase+ 8)*64+r]=x2.x*rms*w2.x; As[(kbase+ 9)*64+r]=x2.y*rms*w2.y;
    As[(kbase+10)*64+r]=x2.z*rms*w2.z; As[(kbase+11)*64+r]=x2.w*rms*w2.w;
    As[(kbase+12)*64+r]=x3.x*rms*w3.x; As[(kbase+13)*64+r]=x3.y*rms*w3.y;
    As[(kbase+14)*64+r]=x3.z*rms*w3.z; As[(kbase+15)*64+r]=x3.w*rms*w3.w;
  }
  {
    int rw = t >> 1, half = t & 1;
    const float* src = Wo + (size_t)(n0 + rw)*64 + half*32;
    #pragma unroll
    for (int j = 0; j < 8; ++j) {
      float4 w = ld4(src + j*4);
      int k = half*32 + j*4;
      Bs[(k+0)*128+rw] = w.x; Bs[(k+1)*128+rw] = w.y;
      Bs[(k+2)*128+rw] = w.z; Bs[(k+3)*128+rw] = w.w;
    }
  }
  __syncthreads();
  const int mi = t >> 5, ni = t & 31;
  float acc[8][4];
  #pragma unroll
  for (int i = 0; i < 8; ++i)
    #pragma unroll
    for (int j = 0; j < 4; ++j) acc[i][j] = 0.f;
  #pragma unroll 8
  for (int k = 0; k < 64; ++k) {
    float a[8], bv[4];
    float4 a0 = *(const float4*)&As[k*64 + mi*8];
    float4 a1 = *(const float4*)&As[k*64 + mi*8 + 4];
    float4 b0 = *(const float4*)&Bs[k*128 + ni*4];
    a[0]=a0.x; a[1]=a0.y; a[2]=a0.z; a[3]=a0.w;
    a[4]=a1.x; a[5]=a1.y; a[6]=a1.z; a[7]=a1.w;
    bv[0]=b0.x; bv[1]=b0.y; bv[2]=b0.z; bv[3]=b0.w;
    #pragma unroll
    for (int im = 0; im < 8; ++im)
      #pragma unroll
      for (int in = 0; in < 4; ++in)
        acc[im][in] = fmaf(a[im], bv[in], acc[im][in]);
  }
  #pragma unroll
  for (int im = 0; im < 8; ++im) {
    float4 o; o.x=acc[im][0]; o.y=acc[im][1]; o.z=acc[im][2]; o.w=acc[im][3];
    *(float4*)&out[(size_t)(m0 + mi*8 + im)*1024 + n0 + ni*4] = o;
  }
}

// ---------------- launcher ----------------
extern "C" void kernel_launch(void* const* d_in, const int* in_sizes, int n_in,
                              void* d_out, int out_size, void* d_ws, size_t ws_size,
                              hipStream_t stream) {
  const float* x     = (const float*)d_in[0];
  const float* Wk    = (const float*)d_in[1];
  const float* Wv    = (const float*)d_in[2];
  const float* Wq    = (const float*)d_in[3];
  const float* fap   = (const float*)d_in[4];
  const float* sap   = (const float*)d_in[5];
  const float* nm_w1 = (const float*)d_in[6];
  const float* nm_b1 = (const float*)d_in[7];
  const float* nm_w2 = (const float*)d_in[8];
  const float* nm_b2 = (const float*)d_in[9];
  const float* ir_w1 = (const float*)d_in[10];
  const float* ir_b1 = (const float*)d_in[11];
  const float* ir_w2 = (const float*)d_in[12];
  const float* ir_b2 = (const float*)d_in[13];
  const float* pw    = (const float*)d_in[14];
  const float* Wo    = (const float*)d_in[15];
  const float* normw = (const float*)d_in[16];
  float* out = (float*)d_out;
  float* ws  = (float*)d_ws;

  // workspace layout (floats)
  const size_t oW    = 0;                              // 320*1024
  const size_t oY    = oW + (size_t)320*1024;          // MM*320 (reused below)
  const size_t oOBASE = oY;                            // MM*64
  const size_t oE     = oY + (size_t)1*MM*64;          // MM*64
  const size_t oPfA   = oY + (size_t)2*MM*64;          // AKK -> P_f
  const size_t oAQK   = oY + (size_t)3*MM*64;          // AQK (kept for pass3)
  const size_t oPs    = oY + (size_t)4*MM*64;          // P_s
  const size_t oK    = oY + (size_t)MM*320;
  const size_t oV    = oK + (size_t)MM*64;
  const size_t oQ    = oV + (size_t)MM*64;
  const size_t oNU   = oQ + (size_t)MM*64;
  const size_t oPW   = oNU + (size_t)MM*64;
  const size_t oSCL  = oPW + (size_t)MM*3;
  const size_t oCNS  = oSCL + (size_t)MM*8;
  const size_t oOB   = oCNS + MM;
  const size_t oRf   = oOB  + (size_t)MM*64;
  const size_t oRs   = oRf  + (size_t)MM*64;
  const size_t oGf   = oRs  + (size_t)MM*64;
  const size_t oGs   = oGf  + (size_t)MM*64;
  const size_t oHf   = oGs  + (size_t)MM*64;
  const size_t oHs   = oHf  + (size_t)MM*64;
  const size_t oFstf = oHs  + (size_t)MM*64;
  const size_t oFsts = oFstf + (size_t)MM*64;
  const size_t oASEG = oFsts + (size_t)MM*64;          // 256
  const size_t oBSEG = oASEG + 256;                    // 16384
  const size_t oNSST = oBSEG + 16384;                  // 16384

  pack_w<<<1280, 256, 0, stream>>>(Wk, Wv, Wq, ir_w1, pw, ws + oW);
  gemm1<<<dim3(128, 5), 256, 0, stream>>>(x, ws + oW, ws + oY);
  post_kernel<<<1024, 256, 0, stream>>>(ws + oY,
                                        nm_w1, nm_b1, nm_w2, nm_b2,
                                        ir_b1, ir_w2, ir_b2, sap,
                                        ws + oK, ws + oV, ws + oQ, ws + oNU,
                                        ws + oPW, ws + oSCL);
  chunkdots<<<256, 256, 0, stream>>>(ws + oK, ws + oQ, ws + oPfA, ws + oAQK);
  pass1_solve<<<256, 256, 0, stream>>>(ws + oK, ws + oV, ws + oSCL, ws + oPfA,
                                       fap, sap,
                                       ws + oPfA, ws + oRf, ws + oPs, ws + oRs);
  pass1b_gh<<<512, 256, 0, stream>>>(ws + oK,
                                     ws + oPfA, ws + oRf, ws + oPs, ws + oRs,
                                     fap, sap,
                                     ws + oGf, ws + oHf, ws + oGs, ws + oHs);
  pass2_rec<<<32, 256, 0, stream>>>(ws + oGf, ws + oHf, ws + oGs, ws + oHs,
                                    ws + oFstf, ws + oFsts);
  pass3_out<<<512, 256, 0, stream>>>(ws + oQ, ws + oV, ws + oSCL, ws + oAQK,
                                     ws + oPfA, ws + oRf, ws + oPs, ws + oRs,
                                     ws + oFstf, ws + oFsts, fap, sap,
                                     ws + oOBASE, ws + oE);
  err_kernel<<<4096, 256, 0, stream>>>(ws + oE, ws + oCNS);
  nsseg<<<256, 64, 0, stream>>>(ws + oCNS, ws + oNU, ws + oASEG, ws + oBSEG);
  nspre<<<8, 64, 0, stream>>>(ws + oASEG, ws + oBSEG, ws + oNSST);
  nsout2<<<256, 64, 0, stream>>>(ws + oCNS, ws + oNU, ws + oOBASE, ws + oPW,
                                 ws + oNSST, ws + oOB);
  out_gemm<<<dim3(8, 256), 256, 0, stream>>>(ws + oOB, Wo, normw, out);
}

// Round 18
// 341.848 us; speedup vs baseline: 3.4570x; 1.0731x over previous
//
#include <hip/hip_runtime.h>
#include <hip/hip_bf16.h>
#include <math.h>

// Problem constants (match reference)
#define BB 8
#define SS 2048
#define DD 1024
#define DS 64
#define MM (BB*SS)   // 16384

typedef __attribute__((ext_vector_type(8))) short short8b;   // 8 bf16 (4 VGPRs)
typedef __attribute__((ext_vector_type(4))) float f32x4;

// ---------------- helpers ----------------

__device__ __forceinline__ float4 ld4(const float* p) { return *(const float4*)p; }

template<int CTRL>
__device__ __forceinline__ float dppadd(float x) {
  int v = __builtin_amdgcn_update_dpp(0, __float_as_int(x), CTRL, 0xf, 0xf, true);
  return x + __int_as_float(v);
}

__device__ __forceinline__ float xor16add(float x) {
#if defined(__has_builtin) && __has_builtin(__builtin_amdgcn_permlane16_swap)
  auto r = __builtin_amdgcn_permlane16_swap(__float_as_uint(x), __float_as_uint(x), false, false);
  return __uint_as_float(r[0]) + __uint_as_float(r[1]);
#else
  return x + __shfl_xor(x, 16, 64);
#endif
}
__device__ __forceinline__ float xor32add(float x) {
#if defined(__has_builtin) && __has_builtin(__builtin_amdgcn_permlane32_swap)
  auto r = __builtin_amdgcn_permlane32_swap(__float_as_uint(x), __float_as_uint(x), false, false);
  return __uint_as_float(r[0]) + __uint_as_float(r[1]);
#else
  return x + __shfl_xor(x, 32, 64);
#endif
}

// full 64-lane butterfly sum; result valid in all lanes
__device__ __forceinline__ float wsum(float x) {
  x = dppadd<0xB1>(x);
  x = dppadd<0x4E>(x);
  x = dppadd<0x141>(x);
  x = dppadd<0x140>(x);
  x = xor16add(x);
  x = xor32add(x);
  return x;
}

__device__ __forceinline__ float gelu_exact(float x) {
  return 0.5f * x * (1.f + erff(x * 0.7071067811865476f));
}

// split fp32 -> (hi, lo) bf16 pairs, packed 2-per-u32 (k ascending = low half)
__device__ __forceinline__ void cvt8(const float* f, uint* hi, uint* lo) {
  #pragma unroll
  for (int i = 0; i < 4; ++i) {
    uint u0 = __float_as_uint(f[2*i]);
    uint u1 = __float_as_uint(f[2*i+1]);
    uint h0 = u0 & 0xFFFF0000u, h1 = u1 & 0xFFFF0000u;
    float l0 = f[2*i]   - __uint_as_float(h0);
    float l1 = f[2*i+1] - __uint_as_float(h1);
    hi[i] = (h0 >> 16) | h1;
    lo[i] = (__float_as_uint(l0) >> 16) | (__float_as_uint(l1) & 0xFFFF0000u);
  }
}

// ---------------- k0: pack weights [Wk;Wv;Wq;ir_w1;pw;0-pad] -> Wcat[320][1024]
__global__ __launch_bounds__(256) void pack_w(
    const float* __restrict__ Wk, const float* __restrict__ Wv,
    const float* __restrict__ Wq, const float* __restrict__ ir_w1,
    const float* __restrict__ pw, float* __restrict__ Wcat) {
  int idx = blockIdx.x * 256 + threadIdx.x;   // 320*1024 total
  int r = idx >> 10, c = idx & 1023;
  float val = 0.f;
  if (r < 64)       val = Wk[r*1024 + c];
  else if (r < 128) val = Wv[(r-64)*1024 + c];
  else if (r < 192) val = Wq[(r-128)*1024 + c];
  else if (r < 256) val = ir_w1[(r-192)*1024 + c];
  else if (r < 259) val = pw[(r-256)*1024 + c];
  Wcat[idx] = val;
}

// ---------------- k1: YP[z] = X[k-half z] @ Wcat[k-half z]^T via bf16 MFMA.
// Split-K=2 (grid 128x5x2 = 1280 blocks -> 5 blocks/CU). hi/lo split:
// products hh + hl + lh. LDS rows 128B, T2 XOR swizzle on store AND read.
__global__ __launch_bounds__(256) void gemm1(
    const float* __restrict__ X, const float* __restrict__ Wcat,
    float* __restrict__ YP0, float* __restrict__ YP1) {
  __shared__ unsigned short Ah[128*64], Al[128*64];   // 16KB each
  __shared__ unsigned short Bh[64*64],  Bl[64*64];    // 8KB each
  const int t  = threadIdx.x;
  const int m0 = blockIdx.x * 128;
  const int n0 = blockIdx.y * 64;
  const int kh0 = blockIdx.z * 512;
  const int l  = t & 63, w = t >> 6;
  const int wm = (w >> 1) * 64, wn = (w & 1) * 32;
  const int fr = l & 15;           // frag row-in-tile
  const int fkb = (l >> 4) * 16;   // frag k byte base within 32-k half
  const int mA = t >> 1, khA = (t & 1) * 32;   // A staging: row, k-half
  const int nB = t >> 2, kqB = (t & 3) * 16;   // B staging: row, k-quarter
  f32x4 acc[4][2];
  #pragma unroll
  for (int i = 0; i < 4; ++i)
    #pragma unroll
    for (int j = 0; j < 2; ++j) acc[i][j] = (f32x4){0.f,0.f,0.f,0.f};

  for (int k0 = kh0; k0 < kh0 + 512; k0 += 64) {
    __syncthreads();
    {   // stage A (128x64 fp32 -> bf16 hi/lo)
      const float* src = X + (size_t)(m0 + mA)*1024 + k0 + khA;
      float f[32];
      #pragma unroll
      for (int j = 0; j < 8; ++j) *(float4*)&f[j*4] = ld4(src + j*4);
      #pragma unroll
      for (int g = 0; g < 4; ++g) {
        uint hi[4], lo[4];
        cvt8(&f[g*8], hi, lo);
        int off = mA*128 + ((khA*2 + g*16) ^ ((mA & 7) << 4));
        *(uint4*)((char*)Ah + off) = make_uint4(hi[0],hi[1],hi[2],hi[3]);
        *(uint4*)((char*)Al + off) = make_uint4(lo[0],lo[1],lo[2],lo[3]);
      }
    }
    {   // stage B (64x64 fp32 -> bf16 hi/lo)
      const float* src = Wcat + (size_t)(n0 + nB)*1024 + k0 + kqB;
      float f[16];
      #pragma unroll
      for (int j = 0; j < 4; ++j) *(float4*)&f[j*4] = ld4(src + j*4);
      #pragma unroll
      for (int g = 0; g < 2; ++g) {
        uint hi[4], lo[4];
        cvt8(&f[g*8], hi, lo);
        int off = nB*128 + ((kqB*2 + g*16) ^ ((nB & 7) << 4));
        *(uint4*)((char*)Bh + off) = make_uint4(hi[0],hi[1],hi[2],hi[3]);
        *(uint4*)((char*)Bl + off) = make_uint4(lo[0],lo[1],lo[2],lo[3]);
      }
    }
    __syncthreads();
    #pragma unroll
    for (int h = 0; h < 2; ++h) {
      const int kb = h*64 + fkb;
      short8b ah[4], al[4], bh[2], bl[2];
      #pragma unroll
      for (int i = 0; i < 4; ++i) {
        int row = wm + i*16 + fr;
        int off = row*128 + (kb ^ ((row & 7) << 4));
        ah[i] = *(const short8b*)((const char*)Ah + off);
        al[i] = *(const short8b*)((const char*)Al + off);
      }
      #pragma unroll
      for (int j = 0; j < 2; ++j) {
        int row = wn + j*16 + fr;
        int off = row*128 + (kb ^ ((row & 7) << 4));
        bh[j] = *(const short8b*)((const char*)Bh + off);
        bl[j] = *(const short8b*)((const char*)Bl + off);
      }
      #pragma unroll
      for (int i = 0; i < 4; ++i)
        #pragma unroll
        for (int j = 0; j < 2; ++j) {
          acc[i][j] = __builtin_amdgcn_mfma_f32_16x16x32_bf16(ah[i], bh[j], acc[i][j], 0, 0, 0);
          acc[i][j] = __builtin_amdgcn_mfma_f32_16x16x32_bf16(ah[i], bl[j], acc[i][j], 0, 0, 0);
          acc[i][j] = __builtin_amdgcn_mfma_f32_16x16x32_bf16(al[i], bh[j], acc[i][j], 0, 0, 0);
        }
    }
  }
  float* Y = blockIdx.z ? YP1 : YP0;
  // epilogue: C/D layout col=lane&15, row=(lane>>4)*4+reg
  #pragma unroll
  for (int i = 0; i < 4; ++i)
    #pragma unroll
    for (int j = 0; j < 2; ++j)
      #pragma unroll
      for (int r = 0; r < 4; ++r) {
        int row = m0 + wm + i*16 + (l >> 4)*4 + r;
        int col = n0 + wn + j*16 + (l & 15);
        Y[(size_t)row*320 + col] = acc[i][j][r];
      }
}

// ---------------- k2: per-token postprocess (Y = YP0 + YP1)
__global__ __launch_bounds__(256) void post_kernel(
    const float* __restrict__ YP0, const float* __restrict__ YP1,
    const float* __restrict__ nm_w1, const float* __restrict__ nm_b1,
    const float* __restrict__ nm_w2, const float* __restrict__ nm_b2,
    const float* __restrict__ ir_b1, const float* __restrict__ ir_w2,
    const float* __restrict__ ir_b2, const float* __restrict__ sap,
    float* __restrict__ K, float* __restrict__ V, float* __restrict__ Q,
    float* __restrict__ NU, float* __restrict__ PW,
    float* __restrict__ SCL8) {
  __shared__ float w1s[128*65];
  __shared__ float w2s[64*129];
  __shared__ float vbuf[4][64];
  __shared__ float h1buf[4][128];
  const int tid = threadIdx.x, wid = tid >> 6, l = tid & 63;
  for (int i = tid; i < 128*64; i += 256) w1s[(i>>6)*65 + (i&63)]  = nm_w1[i];
  for (int i = tid; i < 64*128; i += 256) w2s[(i>>7)*129 + (i&127)] = nm_w2[i];
  __syncthreads();
  const float sa   = *sap;
  const float b1a  = nm_b1[l], b1b = nm_b1[64+l], b2l = nm_b2[l];
  const float irb1 = ir_b1[l], irw2 = ir_w2[l],  irb2 = ir_b2[0];
  for (int r = 0; r < 4; ++r) {
    const int tok = blockIdx.x*16 + r*4 + wid;
    const float* yr0 = YP0 + (size_t)tok*320;
    const float* yr1 = YP1 + (size_t)tok*320;
    float kr = yr0[l]     + yr1[l];
    float vr = yr0[64+l]  + yr1[64+l];
    float qr = yr0[128+l] + yr1[128+l];
    float hr = yr0[192+l] + yr1[192+l];
    float rk = 1.f / fmaxf(sqrtf(wsum(kr*kr)), 1e-12f);
    float rq = 1.f / fmaxf(sqrtf(wsum(qr*qr)), 1e-12f);
    float kn = kr*rk, qn = qr*rq;
    float qk = wsum(kn*qn);
    float g  = gelu_exact(hr + irb1);
    float logit = wsum(g*irw2) + irb2;
    float imp = 1.f/(1.f+expf(-logit));
    float bs  = (imp > 0.5f) ? (1.f - sa) : 0.f;   // (1-slow_alpha)*u_slow
    K[(size_t)tok*64+l] = kn; V[(size_t)tok*64+l] = vr; Q[(size_t)tok*64+l] = qn;
    vbuf[wid][l] = vr;
    __syncthreads();
    float h1a = b1a, h1b = b1b;
    #pragma unroll 8
    for (int c = 0; c < 64; ++c) {
      float vv = vbuf[wid][c];
      h1a = fmaf(w1s[l*65 + c], vv, h1a);
      h1b = fmaf(w1s[(64+l)*65 + c], vv, h1b);
    }
    h1buf[wid][l]    = gelu_exact(h1a);
    h1buf[wid][64+l] = gelu_exact(h1b);
    __syncthreads();
    float nu = b2l;
    #pragma unroll 8
    for (int j = 0; j < 128; ++j) nu = fmaf(w2s[l*129 + j], h1buf[wid][j], nu);
    NU[(size_t)tok*64+l] = nu;
    float p0 = yr0[256] + yr1[256];
    float p1 = yr0[257] + yr1[257];
    float p2 = yr0[258] + yr1[258];
    float mx = fmaxf(p0, fmaxf(p1, p2));
    float e0 = expf(p0-mx), e1 = expf(p1-mx), e2 = expf(p2-mx);
    float inv = 1.f/(e0+e1+e2);
    if (l == 0) {
      PW[(size_t)tok*3]   = e0*inv;
      float4 s; s.x = qk; s.y = bs; s.z = e0*inv; s.w = e1*inv;
      *(float4*)&SCL8[(size_t)tok*8] = s;
    }
    else if (l == 1)   PW[(size_t)tok*3+1] = e1*inv;
    else if (l == 2)   PW[(size_t)tok*3+2] = e2*inv;
    __syncthreads();
  }
}

#define STAGE68(dst, srcp) { _Pragma("unroll")                        \
    for (int it_ = 0; it_ < 4; ++it_) {                               \
      int idx4 = (threadIdx.x + it_*256)*4;                           \
      int r_ = idx4 >> 6; int d_ = idx4 & 63;                         \
      *(float4*)&dst[r_*68+d_] = ld4(&(srcp)[r_*64 + d_]); } }

// ---------------- k2c: per-chunk dot matrices for ALL (b,c) in parallel.
__global__ __launch_bounds__(256) void chunkdots(
    const float* __restrict__ K, const float* __restrict__ Q,
    float* __restrict__ AKK, float* __restrict__ AQK) {
  __shared__ float Kl[64*68], Ql[64*68];
  const int tid = threadIdx.x;
  const size_t base = (size_t)blockIdx.x * 4096;
  STAGE68(Kl, K + base)
  STAGE68(Ql, Q + base)
  __syncthreads();
  const int t0 = (tid >> 4) * 4, j0 = (tid & 15) * 4;
  float akk[4][4], aqk[4][4];
  #pragma unroll
  for (int i = 0; i < 4; ++i)
    #pragma unroll
    for (int j = 0; j < 4; ++j) { akk[i][j] = 0.f; aqk[i][j] = 0.f; }
  for (int d = 0; d < 64; ++d) {
    float kt[4], qt[4], kj[4];
    #pragma unroll
    for (int i = 0; i < 4; ++i) {
      kt[i] = Kl[(t0+i)*68 + d];
      qt[i] = Ql[(t0+i)*68 + d];
      kj[i] = Kl[(j0+i)*68 + d];
    }
    #pragma unroll
    for (int i = 0; i < 4; ++i)
      #pragma unroll
      for (int j = 0; j < 4; ++j) {
        akk[i][j] = fmaf(kt[i], kj[j], akk[i][j]);
        aqk[i][j] = fmaf(qt[i], kj[j], aqk[i][j]);
      }
  }
  #pragma unroll
  for (int i = 0; i < 4; ++i) {
    float4 a; a.x=akk[i][0]; a.y=akk[i][1]; a.z=akk[i][2]; a.w=akk[i][3];
    float4 b; b.x=aqk[i][0]; b.y=aqk[i][1]; b.z=aqk[i][2]; b.w=aqk[i][3];
    *(float4*)&AKK[base + (t0+i)*64 + j0] = a;
    *(float4*)&AQK[base + (t0+i)*64 + j0] = b;
  }
}

// ---------------- k3a: per-chunk triangular solves -> P_f, R_f, P_s, R_s
__global__ __launch_bounds__(256) void pass1_solve(
    const float* __restrict__ K, const float* __restrict__ V,
    const float* __restrict__ SCL8, const float* __restrict__ AKK,
    const float* __restrict__ fap, const float* __restrict__ sap,
    float* __restrict__ Pf, float* __restrict__ Rf,
    float* __restrict__ Ps, float* __restrict__ Rs) {
  __shared__ float Mf[64*68], Ms[64*68];
  __shared__ float Xpf[64*68], Xrf[64*68], Xps[64*68], Xrs[64*68];
  __shared__ float bsv[64];
  __shared__ float fpw[65], spw[65];
  const int tid = threadIdx.x;
  const size_t chunk = blockIdx.x;
  const size_t tok0 = chunk * 64;
  const float fa = *fap, sa = *sap, omfa = 1.f - fa;
  if (tid == 0) {
    float f = 1.f, s = 1.f;
    for (int n = 0; n <= 64; ++n) { fpw[n] = f; spw[n] = s; f *= fa; s *= sa; }
  }
  STAGE68(Xpf, K + tok0*64)        // raw K
  STAGE68(Xrf, V + tok0*64)        // raw V
  STAGE68(Mf, AKK + chunk*4096)    // raw Akk
  if (tid < 64) bsv[tid] = SCL8[(tok0 + tid)*8 + 1];
  __syncthreads();
  {
    const int t = tid >> 2, j0 = (tid & 3) * 16;
    const float bst = bsv[t];
    const float cpf = omfa*fpw[t], cps = bst*spw[t];
    #pragma unroll
    for (int i = 0; i < 16; ++i) {
      int j = j0 + i;
      float a    = Mf [t*68 + j];
      float kraw = Xpf[t*68 + j];
      float vraw = Xrf[t*68 + j];
      bool lt = (j < t);
      int p = lt ? (t-1-j) : 0;
      Ms [t*68 + j] = lt ? bst*spw[p]*a  : 0.f;
      Mf [t*68 + j] = lt ? omfa*fpw[p]*a : 0.f;
      Xps[t*68 + j] = cps * kraw;
      Xpf[t*68 + j] = cpf * kraw;
      Xrs[t*68 + j] = bst * vraw;
      Xrf[t*68 + j] = omfa * vraw;
    }
  }
  __syncthreads();

  const int g  = tid >> 6;     // 0:Pf 1:Rf 2:Ps 3:Rs (wave-uniform)
  const int cc = tid & 63;     // column
  const float* M = (g < 2) ? Mf : Ms;
  float* X = (g == 0) ? Xpf : (g == 1) ? Xrf : (g == 2) ? Xps : Xrs;
  for (int t = 1; t < 64; ++t) {
    float a0 = 0.f, a1 = 0.f, a2 = 0.f, a3 = 0.f;
    int j = 0;
    for (; j + 4 <= t; j += 4) {
      float4 m = *(const float4*)&M[t*68 + j];
      a0 = fmaf(m.x, X[(j+0)*68 + cc], a0);
      a1 = fmaf(m.y, X[(j+1)*68 + cc], a1);
      a2 = fmaf(m.z, X[(j+2)*68 + cc], a2);
      a3 = fmaf(m.w, X[(j+3)*68 + cc], a3);
    }
    for (; j < t; ++j) a0 = fmaf(M[t*68 + j], X[j*68 + cc], a0);
    X[t*68 + cc] -= ((a0 + a1) + (a2 + a3));
  }
  float* dst = (g == 0) ? Pf : (g == 1) ? Rf : (g == 2) ? Ps : Rs;
  const size_t base = chunk*4096 + cc;
  for (int t = 0; t < 64; ++t) dst[base + t*64] = X[t*68 + cc];
}

// ---------------- k3b: G = d^64 I - K^T E P, H = K^T E R (per chunk, path)
__global__ __launch_bounds__(256) void pass1b_gh(
    const float* __restrict__ K,
    const float* __restrict__ Pf, const float* __restrict__ Rf,
    const float* __restrict__ Ps, const float* __restrict__ Rs,
    const float* __restrict__ fap, const float* __restrict__ sap,
    float* __restrict__ Gf, float* __restrict__ Hf,
    float* __restrict__ Gs, float* __restrict__ Hs) {
  __shared__ float Kc[64*68], Pl[64*68], Rl[64*68];
  __shared__ float dpw[65];
  const int tid = threadIdx.x;
  const size_t chunk = blockIdx.x >> 1;
  const int path = blockIdx.x & 1;
  const float d = path ? (*sap) : (*fap);
  if (tid == 0) {
    float p = 1.f;
    for (int n = 0; n <= 64; ++n) { dpw[n] = p; p *= d; }
  }
  const float* Pg = path ? Ps : Pf;
  const float* Rg = path ? Rs : Rf;
  float* Gg = path ? Gs : Gf;
  float* Hg = path ? Hs : Hf;
  STAGE68(Kc, K + chunk*4096)
  STAGE68(Pl, Pg + chunk*4096)
  STAGE68(Rl, Rg + chunk*4096)
  __syncthreads();
  const int kd = tid >> 2, c0 = (tid & 3) * 16;
  float accG[16], accH[16];
  #pragma unroll
  for (int i = 0; i < 16; ++i) { accG[i] = 0.f; accH[i] = 0.f; }
  #pragma unroll 8
  for (int j = 0; j < 64; ++j) {
    const float w = Kc[j*68 + kd] * dpw[63 - j];
    #pragma unroll
    for (int i4 = 0; i4 < 4; ++i4) {
      float4 p = *(const float4*)&Pl[j*68 + c0 + i4*4];
      float4 r = *(const float4*)&Rl[j*68 + c0 + i4*4];
      accG[i4*4+0] = fmaf(w, p.x, accG[i4*4+0]);
      accG[i4*4+1] = fmaf(w, p.y, accG[i4*4+1]);
      accG[i4*4+2] = fmaf(w, p.z, accG[i4*4+2]);
      accG[i4*4+3] = fmaf(w, p.w, accG[i4*4+3]);
      accH[i4*4+0] = fmaf(w, r.x, accH[i4*4+0]);
      accH[i4*4+1] = fmaf(w, r.y, accH[i4*4+1]);
      accH[i4*4+2] = fmaf(w, r.z, accH[i4*4+2]);
      accH[i4*4+3] = fmaf(w, r.w, accH[i4*4+3]);
    }
  }
  const float d64 = dpw[64];
  #pragma unroll
  for (int i4 = 0; i4 < 4; ++i4) {
    float4 go, ho;
    float* gp = (float*)&go; float* hp = (float*)&ho;
    #pragma unroll
    for (int i = 0; i < 4; ++i) {
      int col = c0 + i4*4 + i;
      gp[i] = ((col == kd) ? d64 : 0.f) - accG[i4*4+i];
      hp[i] = accH[i4*4+i];
    }
    *(float4*)&Gg[chunk*4096 + (size_t)kd*64 + c0 + i4*4] = go;
    *(float4*)&Hg[chunk*4096 + (size_t)kd*64 + c0 + i4*4] = ho;
  }
}

// ---------------- k3c: sequential state recurrence F' = G F + H.
// Grid 64 = 8b x 2path x 4vq (16 v-cols each), 256 threads.
__global__ __launch_bounds__(256) void pass2_rec(
    const float* __restrict__ Gf, const float* __restrict__ Hf,
    const float* __restrict__ Gs, const float* __restrict__ Hs,
    float* __restrict__ Fstf, float* __restrict__ Fsts) {
  __shared__ float Fl[64*20], Gl[64*68], Hl[64*20];
  const int tid = threadIdx.x;
  const int b = blockIdx.x >> 3;
  const int path = (blockIdx.x >> 2) & 1;
  const int vq4 = blockIdx.x & 3;             // v quarter (16 cols)
  const float* Gg = path ? Gs : Gf;
  const float* Hg = path ? Hs : Hf;
  float* Fstg = path ? Fsts : Fstf;
  const int kd = tid >> 2, vi = tid & 3;      // 64 x 4(4v)
  #pragma unroll
  for (int i = 0; i < 4; ++i) Fl[kd*20 + vi*4 + i] = 0.f;
  __syncthreads();
  for (int c = 0; c < 32; ++c) {
    const size_t chunk = (size_t)b*32 + c;
    STAGE68(Gl, Gg + chunk*4096)
    *(float4*)&Hl[kd*20 + vi*4] = ld4(&Hg[chunk*4096 + kd*64 + vq4*16 + vi*4]);
    *(float4*)&Fstg[chunk*4096 + (size_t)kd*64 + vq4*16 + vi*4] = *(float4*)&Fl[kd*20 + vi*4];
    __syncthreads();
    float acc[4];
    #pragma unroll
    for (int i = 0; i < 4; ++i) acc[i] = Hl[kd*20 + vi*4 + i];
    #pragma unroll 8
    for (int j = 0; j < 64; ++j) {
      const float g = Gl[kd*68 + j];
      float4 f0 = *(const float4*)&Fl[j*20 + vi*4];
      acc[0]=fmaf(g,f0.x,acc[0]); acc[1]=fmaf(g,f0.y,acc[1]);
      acc[2]=fmaf(g,f0.z,acc[2]); acc[3]=fmaf(g,f0.w,acc[3]);
    }
    __syncthreads();
    #pragma unroll
    for (int i = 0; i < 4; ++i) Fl[kd*20 + vi*4 + i] = acc[i];
    __syncthreads();
  }
}

// ---------------- k3d: parallel outputs per chunk (needs Fst states).
__global__ __launch_bounds__(256) void pass3_out(
    const float* __restrict__ Q, const float* __restrict__ V,
    const float* __restrict__ SCL8, const float* __restrict__ AQK,
    const float* __restrict__ Pf, const float* __restrict__ Rf,
    const float* __restrict__ Ps, const float* __restrict__ Rs,
    const float* __restrict__ Fstf, const float* __restrict__ Fsts,
    const float* __restrict__ fap, const float* __restrict__ sap,
    float* __restrict__ OBASE, float* __restrict__ E2) {
  __shared__ float Qcl[64*68], AQKl[64*68], Pfl[64*68], Psl[64*68];
  __shared__ float Vl[64*36], Rfl[64*36], Rsl[64*36];
  __shared__ float F0l[64*36], S0l[64*36], Ufl[64*36], Usl[64*36];
  __shared__ float scal[256];
  __shared__ float fpw[65], spw[65];
  const int tid = threadIdx.x;
  const size_t chunk = blockIdx.x >> 1;
  const int vh = blockIdx.x & 1;
  const size_t tok0 = chunk * 64;
  const float fa = *fap, sa = *sap;
  if (tid == 0) {
    float f = 1.f, s = 1.f;
    for (int n = 0; n <= 64; ++n) { fpw[n] = f; spw[n] = s; f *= fa; s *= sa; }
  }
  STAGE68(Qcl,  Q   + tok0*64)
  STAGE68(AQKl, AQK + chunk*4096)
  STAGE68(Pfl,  Pf  + chunk*4096)
  STAGE68(Psl,  Ps  + chunk*4096)
  {
    const int r = tid >> 2, vq = tid & 3;
    const size_t off = chunk*4096 + (size_t)r*64 + vh*32 + vq*8;
    *(float4*)&Vl [r*36 + vq*8]     = ld4(&V   [tok0*64 + (size_t)r*64 + vh*32 + vq*8]);
    *(float4*)&Vl [r*36 + vq*8 + 4] = ld4(&V   [tok0*64 + (size_t)r*64 + vh*32 + vq*8 + 4]);
    *(float4*)&Rfl[r*36 + vq*8]     = ld4(&Rf  [off]);
    *(float4*)&Rfl[r*36 + vq*8 + 4] = ld4(&Rf  [off + 4]);
    *(float4*)&Rsl[r*36 + vq*8]     = ld4(&Rs  [off]);
    *(float4*)&Rsl[r*36 + vq*8 + 4] = ld4(&Rs  [off + 4]);
    *(float4*)&F0l[r*36 + vq*8]     = ld4(&Fstf[off]);
    *(float4*)&F0l[r*36 + vq*8 + 4] = ld4(&Fstf[off + 4]);
    *(float4*)&S0l[r*36 + vq*8]     = ld4(&Fsts[off]);
    *(float4*)&S0l[r*36 + vq*8 + 4] = ld4(&Fsts[off + 4]);
    scal[tid] = SCL8[(tok0 + r)*8 + vq];
  }
  __syncthreads();
  {
    const int j = tid >> 2, vq = tid & 3;
    float uf[8], us[8];
    #pragma unroll
    for (int i = 0; i < 8; ++i) { uf[i] = 0.f; us[i] = 0.f; }
    #pragma unroll 8
    for (int kd = 0; kd < 64; ++kd) {
      const float pfv = Pfl[j*68 + kd];
      const float psv = Psl[j*68 + kd];
      float4 f0 = *(const float4*)&F0l[kd*36 + vq*8];
      float4 f1 = *(const float4*)&F0l[kd*36 + vq*8 + 4];
      float4 s0 = *(const float4*)&S0l[kd*36 + vq*8];
      float4 s1 = *(const float4*)&S0l[kd*36 + vq*8 + 4];
      uf[0]=fmaf(pfv,f0.x,uf[0]); uf[1]=fmaf(pfv,f0.y,uf[1]);
      uf[2]=fmaf(pfv,f0.z,uf[2]); uf[3]=fmaf(pfv,f0.w,uf[3]);
      uf[4]=fmaf(pfv,f1.x,uf[4]); uf[5]=fmaf(pfv,f1.y,uf[5]);
      uf[6]=fmaf(pfv,f1.z,uf[6]); uf[7]=fmaf(pfv,f1.w,uf[7]);
      us[0]=fmaf(psv,s0.x,us[0]); us[1]=fmaf(psv,s0.y,us[1]);
      us[2]=fmaf(psv,s0.z,us[2]); us[3]=fmaf(psv,s0.w,us[3]);
      us[4]=fmaf(psv,s1.x,us[4]); us[5]=fmaf(psv,s1.y,us[5]);
      us[6]=fmaf(psv,s1.z,us[6]); us[7]=fmaf(psv,s1.w,us[7]);
    }
    #pragma unroll
    for (int i = 0; i < 8; ++i) {
      Ufl[j*36 + vq*8 + i] = Rfl[j*36 + vq*8 + i] - uf[i];
      Usl[j*36 + vq*8 + i] = Rsl[j*36 + vq*8 + i] - us[i];
    }
  }
  __syncthreads();
  {
    const int t = tid >> 2, vq = tid & 3;
    float af[8], as_[8];
    #pragma unroll
    for (int i = 0; i < 8; ++i) { af[i] = 0.f; as_[i] = 0.f; }
    #pragma unroll 8
    for (int kd = 0; kd < 64; ++kd) {
      const float q = Qcl[t*68 + kd];
      float4 f0 = *(const float4*)&F0l[kd*36 + vq*8];
      float4 f1 = *(const float4*)&F0l[kd*36 + vq*8 + 4];
      float4 s0 = *(const float4*)&S0l[kd*36 + vq*8];
      float4 s1 = *(const float4*)&S0l[kd*36 + vq*8 + 4];
      af[0]=fmaf(q,f0.x,af[0]); af[1]=fmaf(q,f0.y,af[1]);
      af[2]=fmaf(q,f0.z,af[2]); af[3]=fmaf(q,f0.w,af[3]);
      af[4]=fmaf(q,f1.x,af[4]); af[5]=fmaf(q,f1.y,af[5]);
      af[6]=fmaf(q,f1.z,af[6]); af[7]=fmaf(q,f1.w,af[7]);
      as_[0]=fmaf(q,s0.x,as_[0]); as_[1]=fmaf(q,s0.y,as_[1]);
      as_[2]=fmaf(q,s0.z,as_[2]); as_[3]=fmaf(q,s0.w,as_[3]);
      as_[4]=fmaf(q,s1.x,as_[4]); as_[5]=fmaf(q,s1.y,as_[5]);
      as_[6]=fmaf(q,s1.z,as_[6]); as_[7]=fmaf(q,s1.w,as_[7]);
    }
    float pq[8], pqs[8];
    #pragma unroll
    for (int i = 0; i < 8; ++i) { pq[i] = fpw[t]*af[i]; pqs[i] = spw[t]*as_[i]; }
    for (int j = 0; j < 64; ++j) {
      const float aq = AQKl[t*68 + j];
      const bool lt = (j < t);
      const int p = lt ? (t-1-j) : 0;
      const float wf = lt ? fpw[p]*aq : 0.f;
      const float ws = lt ? spw[p]*aq : 0.f;
      float4 u0 = *(const float4*)&Ufl[j*36 + vq*8];
      float4 u1 = *(const float4*)&Ufl[j*36 + vq*8 + 4];
      float4 w0 = *(const float4*)&Usl[j*36 + vq*8];
      float4 w1 = *(const float4*)&Usl[j*36 + vq*8 + 4];
      pq[0]=fmaf(wf,u0.x,pq[0]); pq[1]=fmaf(wf,u0.y,pq[1]);
      pq[2]=fmaf(wf,u0.z,pq[2]); pq[3]=fmaf(wf,u0.w,pq[3]);
      pq[4]=fmaf(wf,u1.x,pq[4]); pq[5]=fmaf(wf,u1.y,pq[5]);
      pq[6]=fmaf(wf,u1.z,pq[6]); pq[7]=fmaf(wf,u1.w,pq[7]);
      pqs[0]=fmaf(ws,w0.x,pqs[0]); pqs[1]=fmaf(ws,w0.y,pqs[1]);
      pqs[2]=fmaf(ws,w0.z,pqs[2]); pqs[3]=fmaf(ws,w0.w,pqs[3]);
      pqs[4]=fmaf(ws,w1.x,pqs[4]); pqs[5]=fmaf(ws,w1.y,pqs[5]);
      pqs[6]=fmaf(ws,w1.z,pqs[6]); pqs[7]=fmaf(ws,w1.w,pqs[7]);
    }
    const float qk = scal[t*4+0], p0 = scal[t*4+2], p1 = scal[t*4+3];
    float ob[8], ee[8];
    #pragma unroll
    for (int i = 0; i < 8; ++i) {
      const float uft = Ufl[t*36 + vq*8 + i];
      const float ust = Usl[t*36 + vq*8 + i];
      const float qfn = fmaf(fa, pq[i],  qk*uft);
      const float qsn = fmaf(sa, pqs[i], qk*ust);
      ob[i] = fmaf(p0, qfn, p1*qsn);
      const float pd = Vl[t*36 + vq*8 + i] - 0.5f*(pq[i] + pqs[i]);
      ee[i] = pd*pd;
    }
    const size_t o = (tok0 + t)*64 + vh*32 + vq*8;
    *(float4*)&OBASE[o]     = *(float4*)&ob[0];
    *(float4*)&OBASE[o + 4] = *(float4*)&ob[4];
    *(float4*)&E2[o]        = *(float4*)&ee[0];
    *(float4*)&E2[o + 4]    = *(float4*)&ee[4];
  }
}

// ---------------- k4: err reduce -> ns-gate coefficient c = 0.1*u_neu
__global__ __launch_bounds__(256) void err_kernel(
    const float* __restrict__ E, float* __restrict__ CNS) {
  int row = blockIdx.x*4 + (threadIdx.x >> 6);
  int l = threadIdx.x & 63;
  float s = wsum(E[(size_t)row*64 + l]);
  if (l == 0) {
    float z = s / (1.0f + 1e-6f);          // TEMP + 1e-6
    float sg = 1.f/(1.f+expf(-z));
    CNS[row] = (sg > 0.7f) ? 0.1f : 0.f;
  }
}

// ---------------- k5a: per-segment summaries A = prod(1-c), Bv = seg-recur(0)
__global__ __launch_bounds__(64) void nsseg(
    const float* __restrict__ CNS, const float* __restrict__ NU,
    float* __restrict__ ASEG, float* __restrict__ BSEG) {
  const int bseg = blockIdx.x;            // b*32 + seg
  const int v = threadIdx.x;
  const size_t t0 = (size_t)(bseg) * 64;  // token index (b*2048 + seg*64)
  float a = 1.f, bv = 0.f;
  for (int i = 0; i < 64; ++i) {
    float c  = CNS[t0 + i];
    float nu = NU[(t0 + i)*64 + v];
    bv = fmaf(1.f - c, bv, c*nu);
    a *= (1.f - c);
  }
  BSEG[(size_t)bseg*64 + v] = bv;
  if (v == 0) ASEG[bseg] = a;
}

// ---------------- k5b: serial prefix over 32 segments per batch (tiny)
__global__ __launch_bounds__(64) void nspre(
    const float* __restrict__ ASEG, const float* __restrict__ BSEG,
    float* __restrict__ NSST) {
  const int b = blockIdx.x, v = threadIdx.x;
  float ns = 0.f;
  for (int s = 0; s < 32; ++s) {
    const int bs = b*32 + s;
    NSST[(size_t)bs*64 + v] = ns;
    ns = fmaf(ASEG[bs], ns, BSEG[(size_t)bs*64 + v]);
  }
}

// ---------------- k5c: parallel replay + output
__global__ __launch_bounds__(64) void nsout2(
    const float* __restrict__ CNS, const float* __restrict__ NU,
    const float* __restrict__ OBASE, const float* __restrict__ PW,
    const float* __restrict__ NSST, float* __restrict__ OB) {
  const int bseg = blockIdx.x;
  const int v = threadIdx.x;
  const size_t t0 = (size_t)bseg * 64;
  float ns = NSST[(size_t)bseg*64 + v];
  for (int i = 0; i < 64; ++i) {
    float c  = CNS[t0 + i];
    float nu = NU[(t0 + i)*64 + v];
    ns = fmaf(1.f - c, ns, c*nu);
    OB[(t0 + i)*64 + v] = fmaf(PW[(t0 + i)*3 + 2], ns, OBASE[(t0 + i)*64 + v]);
  }
}

// ---------------- k6: fused RMSNorm + out = normed @ Wo^T
__global__ __launch_bounds__(256) void out_gemm(
    const float* __restrict__ OB, const float* __restrict__ Wo,
    const float* __restrict__ normw, float* __restrict__ out) {
  __shared__ float As[64*64];    // [k][m]
  __shared__ float Bs[64*128];   // [k][n]
  const int t  = threadIdx.x;
  const int m0 = blockIdx.y * 64;
  const int n0 = blockIdx.x * 128;
  {
    int r = t >> 2, q4 = t & 3;
    const float* src = OB + (size_t)(m0 + r)*64 + q4*16;
    float4 x0 = ld4(src), x1 = ld4(src+4), x2 = ld4(src+8), x3 = ld4(src+12);
    float ss = x0.x*x0.x+x0.y*x0.y+x0.z*x0.z+x0.w*x0.w
             + x1.x*x1.x+x1.y*x1.y+x1.z*x1.z+x1.w*x1.w
             + x2.x*x2.x+x2.y*x2.y+x2.z*x2.z+x2.w*x2.w
             + x3.x*x3.x+x3.y*x3.y+x3.z*x3.z+x3.w*x3.w;
    ss += __shfl_xor(ss, 1, 64);
    ss += __shfl_xor(ss, 2, 64);
    float rms = rsqrtf(ss * (1.f/64.f) + 1e-6f);
    const float* nw = normw + q4*16;
    float4 w0 = ld4(nw), w1 = ld4(nw+4), w2 = ld4(nw+8), w3 = ld4(nw+12);
    int kbase = q4*16;
    As[(kbase+ 0)*64+r]=x0.x*rms*w0.x; As[(kbase+ 1)*64+r]=x0.y*rms*w0.y;
    As[(kbase+ 2)*64+r]=x0.z*rms*w0.z; As[(kbase+ 3)*64+r]=x0.w*rms*w0.w;
    As[(kbase+ 4)*64+r]=x1.x*rms*w1.x; As[(kbase+ 5)*64+r]=x1.y*rms*w1.y;
    As[(kbase+ 6)*64+r]=x1.z*rms*w1.z; As[(kbase+ 7)*64+r]=x1.w*rms*w1.w;
    As[(kbase+ 8)*64+r]=x2.x*rms*w2.x; As[(kbase+ 9)*64+r]=x2.y*rms*w2.y;
    As[(kbase+10)*64+r]=x2.z*rms*w2.z; As[(kbase+11)*64+r]=x2.w*rms*w2.w;
    As[(kbase+12)*64+r]=x3.x*rms*w3.x; As[(kbase+13)*64+r]=x3.y*rms*w3.y;
    As[(kbase+14)*64+r]=x3.z*rms*w3.z; As[(kbase+15)*64+r]=x3.w*rms*w3.w;
  }
  {
    int rw = t >> 1, half = t & 1;
    const float* src = Wo + (size_t)(n0 + rw)*64 + half*32;
    #pragma unroll
    for (int j = 0; j < 8; ++j) {
      float4 w = ld4(src + j*4);
      int k = half*32 + j*4;
      Bs[(k+0)*128+rw] = w.x; Bs[(k+1)*128+rw] = w.y;
      Bs[(k+2)*128+rw] = w.z; Bs[(k+3)*128+rw] = w.w;
    }
  }
  __syncthreads();
  const int mi = t >> 5, ni = t & 31;
  float acc[8][4];
  #pragma unroll
  for (int i = 0; i < 8; ++i)
    #pragma unroll
    for (int j = 0; j < 4; ++j) acc[i][j] = 0.f;
  #pragma unroll 8
  for (int k = 0; k < 64; ++k) {
    float a[8], bv[4];
    float4 a0 = *(const float4*)&As[k*64 + mi*8];
    float4 a1 = *(const float4*)&As[k*64 + mi*8 + 4];
    float4 b0 = *(const float4*)&Bs[k*128 + ni*4];
    a[0]=a0.x; a[1]=a0.y; a[2]=a0.z; a[3]=a0.w;
    a[4]=a1.x; a[5]=a1.y; a[6]=a1.z; a[7]=a1.w;
    bv[0]=b0.x; bv[1]=b0.y; bv[2]=b0.z; bv[3]=b0.w;
    #pragma unroll
    for (int im = 0; im < 8; ++im)
      #pragma unroll
      for (int in = 0; in < 4; ++in)
        acc[im][in] = fmaf(a[im], bv[in], acc[im][in]);
  }
  #pragma unroll
  for (int im = 0; im < 8; ++im) {
    float4 o; o.x=acc[im][0]; o.y=acc[im][1]; o.z=acc[im][2]; o.w=acc[im][3];
    *(float4*)&out[(size_t)(m0 + mi*8 + im)*1024 + n0 + ni*4] = o;
  }
}

// ---------------- launcher ----------------
extern "C" void kernel_launch(void* const* d_in, const int* in_sizes, int n_in,
                              void* d_out, int out_size, void* d_ws, size_t ws_size,
                              hipStream_t stream) {
  const float* x     = (const float*)d_in[0];
  const float* Wk    = (const float*)d_in[1];
  const float* Wv    = (const float*)d_in[2];
  const float* Wq    = (const float*)d_in[3];
  const float* fap   = (const float*)d_in[4];
  const float* sap   = (const float*)d_in[5];
  const float* nm_w1 = (const float*)d_in[6];
  const float* nm_b1 = (const float*)d_in[7];
  const float* nm_w2 = (const float*)d_in[8];
  const float* nm_b2 = (const float*)d_in[9];
  const float* ir_w1 = (const float*)d_in[10];
  const float* ir_b1 = (const float*)d_in[11];
  const float* ir_w2 = (const float*)d_in[12];
  const float* ir_b2 = (const float*)d_in[13];
  const float* pw    = (const float*)d_in[14];
  const float* Wo    = (const float*)d_in[15];
  const float* normw = (const float*)d_in[16];
  float* out = (float*)d_out;
  float* ws  = (float*)d_ws;

  // workspace layout (floats)
  const size_t oW    = 0;                              // 320*1024
  const size_t oY    = oW + (size_t)320*1024;          // MM*320 (reused below)
  const size_t oOBASE = oY;                            // MM*64
  const size_t oE     = oY + (size_t)1*MM*64;          // MM*64
  const size_t oPfA   = oY + (size_t)2*MM*64;          // AKK -> P_f
  const size_t oAQK   = oY + (size_t)3*MM*64;          // AQK (kept for pass3)
  const size_t oPs    = oY + (size_t)4*MM*64;          // P_s
  const size_t oK    = oY + (size_t)MM*320;
  const size_t oV    = oK + (size_t)MM*64;
  const size_t oQ    = oV + (size_t)MM*64;
  const size_t oNU   = oQ + (size_t)MM*64;
  const size_t oPW   = oNU + (size_t)MM*64;
  const size_t oSCL  = oPW + (size_t)MM*3;
  const size_t oCNS  = oSCL + (size_t)MM*8;
  const size_t oOB   = oCNS + MM;
  const size_t oRf   = oOB  + (size_t)MM*64;
  const size_t oRs   = oRf  + (size_t)MM*64;
  const size_t oGf   = oRs  + (size_t)MM*64;
  const size_t oGs   = oGf  + (size_t)MM*64;
  const size_t oHf   = oGs  + (size_t)MM*64;
  const size_t oHs   = oHf  + (size_t)MM*64;
  const size_t oFstf = oHs  + (size_t)MM*64;
  const size_t oFsts = oFstf + (size_t)MM*64;
  const size_t oASEG = oFsts + (size_t)MM*64;          // 256
  const size_t oBSEG = oASEG + 256;                    // 16384
  const size_t oNSST = oBSEG + 16384;                  // 16384
  // split-K partial: YP1 overlays oRf.. (5*MM*64 = MM*320; Rf..Hf written
  // later by pass1+/pass1b, post reads YP1 before that). Proven safe (R16).
  const size_t oYP1 = oRf;

  pack_w<<<1280, 256, 0, stream>>>(Wk, Wv, Wq, ir_w1, pw, ws + oW);
  gemm1<<<dim3(128, 5, 2), 256, 0, stream>>>(x, ws + oW, ws + oY, ws + oYP1);
  post_kernel<<<1024, 256, 0, stream>>>(ws + oY, ws + oYP1,
                                        nm_w1, nm_b1, nm_w2, nm_b2,
                                        ir_b1, ir_w2, ir_b2, sap,
                                        ws + oK, ws + oV, ws + oQ, ws + oNU,
                                        ws + oPW, ws + oSCL);
  chunkdots<<<256, 256, 0, stream>>>(ws + oK, ws + oQ, ws + oPfA, ws + oAQK);
  pass1_solve<<<256, 256, 0, stream>>>(ws + oK, ws + oV, ws + oSCL, ws + oPfA,
                                       fap, sap,
                                       ws + oPfA, ws + oRf, ws + oPs, ws + oRs);
  pass1b_gh<<<512, 256, 0, stream>>>(ws + oK,
                                     ws + oPfA, ws + oRf, ws + oPs, ws + oRs,
                                     fap, sap,
                                     ws + oGf, ws + oHf, ws + oGs, ws + oHs);
  pass2_rec<<<64, 256, 0, stream>>>(ws + oGf, ws + oHf, ws + oGs, ws + oHs,
                                    ws + oFstf, ws + oFsts);
  pass3_out<<<512, 256, 0, stream>>>(ws + oQ, ws + oV, ws + oSCL, ws + oAQK,
                                     ws + oPfA, ws + oRf, ws + oPs, ws + oRs,
                                     ws + oFstf, ws + oFsts, fap, sap,
                                     ws + oOBASE, ws + oE);
  err_kernel<<<4096, 256, 0, stream>>>(ws + oE, ws + oCNS);
  nsseg<<<256, 64, 0, stream>>>(ws + oCNS, ws + oNU, ws + oASEG, ws + oBSEG);
  nspre<<<8, 64, 0, stream>>>(ws + oASEG, ws + oBSEG, ws + oNSST);
  nsout2<<<256, 64, 0, stream>>>(ws + oCNS, ws + oNU, ws + oOBASE, ws + oPW,
                                 ws + oNSST, ws + oOB);
  out_gemm<<<dim3(8, 256), 256, 0, stream>>>(ws + oOB, Wo, normw, out);
}